// Round 9
// baseline (478.052 us; speedup 1.0000x reference)
//
#include <hip/hip_runtime.h>
#include <hip/hip_bf16.h>
#include <hip/hip_fp16.h>
#include <math.h>

#define DPROJ 2320
#define CONVD 1280

typedef __attribute__((ext_vector_type(8))) short bf16x8;
typedef __attribute__((ext_vector_type(4))) float f32x4;

__device__ __forceinline__ float siluf(float x) { return x / (1.f + __expf(-x)); }
__device__ __forceinline__ float bfu(unsigned short s) { return __uint_as_float(((unsigned)s) << 16); }
__device__ __forceinline__ unsigned short f2bf(float f) {
    unsigned u = __float_as_uint(f);
    unsigned r = (u + 0x7FFFu + ((u >> 16) & 1u)) >> 16;
    return (unsigned short)r;
}
__device__ __forceinline__ unsigned short f2h(float f) {
    __half h = __float2half(f);
    return *(unsigned short*)&h;
}
__device__ __forceinline__ float h2f(unsigned short s) {
    __half h = *(__half*)&s;
    return __half2float(h);
}

// ---------------- fused gather + genefeat + wfold-zero ----------------

__global__ void gg_kernel(const int* __restrict__ chridx, const float* __restrict__ gid,
                          const float* __restrict__ path, const float* __restrict__ chrE,
                          const int* __restrict__ pidx, const float* __restrict__ pertE,
                          float* __restrict__ gf, float* __restrict__ cemb,
                          float* __restrict__ wf2, float* __restrict__ wb2) {
    int blk = blockIdx.x, tid = threadIdx.x;
    if (blk < 3072) {
        int idx = blk * 256 + tid;   // 2048*384
        int g = idx / 384, j = idx % 384;
        float v;
        if (j < 128)      v = gid[(size_t)g * 128 + j];
        else if (j < 256) v = path[(size_t)g * 128 + (j - 128)];
        else if (j < 320) v = chrE[(size_t)chridx[g] * 64 + (j - 256)];
        else return;
        gf[idx] = v;
    } else if (blk < 3076) {
        int idx = (blk - 3072) * 256 + tid;   // 1024
        int b = idx >> 7, k = idx & 127;
        cemb[idx] = pertE[(size_t)pidx[b] * 128 + k];
    } else {
        wf2[tid * 4 + 0] = 0.f; wf2[tid * 4 + 1] = 0.f;
        wf2[tid * 4 + 2] = 0.f; wf2[tid * 4 + 3] = 0.f;
        wb2[tid * 4 + 0] = 0.f; wb2[tid * 4 + 1] = 0.f;
        wb2[tid * 4 + 2] = 0.f; wb2[tid * 4 + 3] = 0.f;
    }
}

// wfold: split-m atomic partial sums. 128 blocks = dir(2) x dseg(4) x mseg(16)
__global__ void wfold_kernel(const float* __restrict__ headW,
                             const float* __restrict__ fOutW, const float* __restrict__ fNw,
                             const float* __restrict__ bOutW, const float* __restrict__ bNw,
                             float* __restrict__ wf2, float* __restrict__ wb2) {
    int blk = blockIdx.x;
    int dir = blk >> 6;
    int rem = blk & 63;
    int dseg = rem >> 4, mseg = rem & 15;
    int tid = threadIdx.x;
    int d = dseg * 256 + tid;
    const float* W = dir ? bOutW : fOutW;
    float s = 0.f;
#pragma unroll
    for (int m = mseg * 32; m < mseg * 32 + 32; ++m)
        s += headW[m] * W[(size_t)m * 1024 + d];
    const float* nw = dir ? bNw : fNw;
    atomicAdd(&(dir ? wb2 : wf2)[d], s * nw[d]);
}

// ---------------- fused bf16 conversions (weights + gf) ----------------

__global__ void tobf4_kernel(const float* __restrict__ inW, const float* __restrict__ fInW,
                             const float* __restrict__ bInW, const float* __restrict__ gf,
                             unsigned short* __restrict__ inW2, unsigned short* __restrict__ fInW2,
                             unsigned short* __restrict__ bInW2, unsigned short* __restrict__ gf2) {
    size_t idx = (size_t)blockIdx.x * 256 + threadIdx.x;
    const size_t A = 512UL * 384, B5 = 2432UL * 512;
    if (idx < A) {
        inW2[idx] = f2bf(inW[idx]);
    } else if (idx < A + B5) {
        size_t k = idx - A; int m = k / 512, kk = k % 512;
        fInW2[k] = f2bf(m < 2320 ? fInW[(size_t)m * 512 + kk] : 0.f);
    } else if (idx < A + 2 * B5) {
        size_t k = idx - A - B5; int m = k / 512, kk = k % 512;
        bInW2[k] = f2bf(m < 2320 ? bInW[(size_t)m * 512 + kk] : 0.f);
    } else {
        size_t k = idx - A - 2 * B5;   // 2048*384
        gf2[k] = f2bf(gf[k]);
    }
}

// ---------------- MFMA GEMM with fused epilogue modes ----------------
// C fp32 (nullable), Cbf bf16 (nullable), sz: for n<1024 write f2h(silu(v)) instead.

__global__ __launch_bounds__(256) void mfma_gemm_kernel(
    const unsigned short* __restrict__ A2, const unsigned short* __restrict__ W2,
    const float* __restrict__ bias, float* __restrict__ C,
    unsigned short* __restrict__ Cbf, unsigned short* __restrict__ sz,
    int N, int K2, int ldc) {
    __shared__ __align__(16) unsigned short Al[128 * 40];
    __shared__ __align__(16) unsigned short Bl[128 * 40];
    const int tid = threadIdx.x;
    const int bm = blockIdx.y * 128, bn = blockIdx.x * 128;
    const int lane = tid & 63, wave = tid >> 6;
    const int wm = (wave >> 1) * 64, wn = (wave & 1) * 64;
    f32x4 acc[4][4];
#pragma unroll
    for (int i = 0; i < 4; ++i)
#pragma unroll
        for (int j = 0; j < 4; ++j) acc[i][j] = (f32x4){0.f, 0.f, 0.f, 0.f};

    for (int k0 = 0; k0 < K2; k0 += 32) {
        __syncthreads();
#pragma unroll
        for (int s = 0; s < 2; ++s) {
            int ch = tid + 256 * s;
            int row = ch >> 2, q = ch & 3;
            uint4 va = *(const uint4*)&A2[(size_t)(bm + row) * K2 + k0 + q * 8];
            *(uint4*)&Al[row * 40 + q * 8] = va;
            uint4 vb = *(const uint4*)&W2[(size_t)(bn + row) * K2 + k0 + q * 8];
            *(uint4*)&Bl[row * 40 + q * 8] = vb;
        }
        __syncthreads();
        bf16x8 af[4], bfr[4];
#pragma unroll
        for (int i = 0; i < 4; ++i)
            af[i] = *(const bf16x8*)&Al[(wm + i * 16 + (lane & 15)) * 40 + (lane >> 4) * 8];
#pragma unroll
        for (int j = 0; j < 4; ++j)
            bfr[j] = *(const bf16x8*)&Bl[(wn + j * 16 + (lane & 15)) * 40 + (lane >> 4) * 8];
#pragma unroll
        for (int i = 0; i < 4; ++i)
#pragma unroll
            for (int j = 0; j < 4; ++j)
                acc[i][j] = __builtin_amdgcn_mfma_f32_16x16x32_bf16(af[i], bfr[j], acc[i][j], 0, 0, 0);
    }
#pragma unroll
    for (int i = 0; i < 4; ++i) {
        int m = bm + wm + i * 16 + (lane >> 4) * 4;
#pragma unroll
        for (int j = 0; j < 4; ++j) {
            int n = bn + wn + j * 16 + (lane & 15);
            if (n < N) {
                float bv = bias ? bias[n] : 0.f;
#pragma unroll
                for (int r = 0; r < 4; ++r) {
                    float v = acc[i][j][r] + bv;
                    if (sz && n < 1024)
                        sz[(size_t)(m + r) * 1024 + n] = f2h(siluf(v));
                    else if (Cbf)
                        Cbf[(size_t)(m + r) * ldc + n] = f2bf(v);
                    else
                        C[(size_t)(m + r) * ldc + n] = v;
                }
            }
        }
    }
}

// ---------------- generic tiled fp32 GEMM (small shapes only) ----------------

__global__ __launch_bounds__(256) void gemm_kernel(
    const float* __restrict__ A, const float* __restrict__ W,
    const float* __restrict__ bias, float* __restrict__ C,
    int M, int N, int K, int ldc, int act) {
    __shared__ __align__(16) float As[16][68];
    __shared__ __align__(16) float Ws[16][68];
    const int tid = threadIdx.x;
    const int tx = tid & 15, ty = tid >> 4;
    const int bm = blockIdx.y * 64, bn = blockIdx.x * 64;
    const int lr = tid >> 2;
    const int lk = (tid & 3) * 4;
    float acc[4][4];
#pragma unroll
    for (int i = 0; i < 4; ++i)
#pragma unroll
        for (int j = 0; j < 4; ++j) acc[i][j] = 0.f;

    for (int k0 = 0; k0 < K; k0 += 16) {
        const int am = bm + lr;
        const int wn = bn + lr;
        float4 av = make_float4(0.f, 0.f, 0.f, 0.f), wv = make_float4(0.f, 0.f, 0.f, 0.f);
        if (am < M) av = *(const float4*)&A[(size_t)am * K + k0 + lk];
        if (wn < N) wv = *(const float4*)&W[(size_t)wn * K + k0 + lk];
        __syncthreads();
        As[lk + 0][lr] = av.x; As[lk + 1][lr] = av.y; As[lk + 2][lr] = av.z; As[lk + 3][lr] = av.w;
        Ws[lk + 0][lr] = wv.x; Ws[lk + 1][lr] = wv.y; Ws[lk + 2][lr] = wv.z; Ws[lk + 3][lr] = wv.w;
        __syncthreads();
#pragma unroll
        for (int kk = 0; kk < 16; ++kk) {
            float4 a = *(const float4*)&As[kk][ty * 4];
            float4 w = *(const float4*)&Ws[kk][tx * 4];
            float aa[4] = {a.x, a.y, a.z, a.w}, ww[4] = {w.x, w.y, w.z, w.w};
#pragma unroll
            for (int i = 0; i < 4; ++i)
#pragma unroll
                for (int j = 0; j < 4; ++j) acc[i][j] += aa[i] * ww[j];
        }
    }
#pragma unroll
    for (int i = 0; i < 4; ++i) {
        const int m = bm + ty * 4 + i;
        if (m >= M) continue;
#pragma unroll
        for (int j = 0; j < 4; ++j) {
            const int n = bn + tx * 4 + j;
            if (n >= N) continue;
            float v = acc[i][j] + (bias ? bias[n] : 0.f);
            if (act == 1) v = 0.5f * v * (1.f + erff(v * 0.70710678118654752f));
            C[(size_t)m * ldc + n] = v;
        }
    }
}

// ---------------- cum kernel: dt softplus (transposed) + chunk-local cumsum + dtFp ----------------

__global__ void cum_kernel(const float* __restrict__ zxf, const float* __restrict__ zxb,
                           const float* __restrict__ zxc,
                           const float* __restrict__ fDtB, const float* __restrict__ bDtB,
                           const float* __restrict__ fAlog, const float* __restrict__ bAlog,
                           float* __restrict__ dtFsT, float* __restrict__ dtBsT,
                           float* __restrict__ dtFp,
                           float* __restrict__ cumF, float* __restrict__ cumB) {
    int blk = blockIdx.x, tid = threadIdx.x;
    if (blk == 4) {
        if (tid < 128) {
            int b = tid >> 4, h = tid & 15;
            float raw = zxc[(size_t)b * DPROJ + 2304 + h] + fDtB[h];
            dtFp[tid] = (raw > 20.f) ? raw : log1pf(expf(raw));
        }
        return;
    }
    int id = blk * 256 + tid;   // 1024
    int dir = id >> 9, k = id & 511, h = k >> 5, c = k & 31;
    const float* zx = dir ? zxb : zxf;
    float bias = (dir ? bDtB : fDtB)[h];
    float a = -expf((dir ? bAlog : fAlog)[h]);
    float* dtT = dir ? dtBsT : dtFsT;
    float* cum = dir ? cumB : cumF;
    float acc = 0.f;
    for (int s = 0; s < 64; ++s) {
        int j = c * 64 + s;
        int row = dir ? (2047 - j) : j;
        float raw = zx[(size_t)row * DPROJ + 2304 + h] + bias;
        float dt = (raw > 20.f) ? raw : log1pf(expf(raw));
        dtT[h * 2048 + j] = dt;
        acc += dt * a;
        cum[h * 2048 + j] = acc;
    }
}

// ---------------- causal depthwise conv (+SiLU): bf16 B/C + bf16 x side-copies only ----------------

__global__ void convFsh_kernel(const float* __restrict__ zxf, const float* __restrict__ cw,
                               const float* __restrict__ cb,
                               unsigned short* __restrict__ bc16, unsigned short* __restrict__ x16) {
    int idx = blockIdx.x * 256 + threadIdx.x;
    if (idx >= 2045 * 1280) return;
    int t4 = idx / 1280, c = idx % 1280;
    float4 w4 = *(const float4*)&cw[c * 4];
    float acc = cb[c];
    acc += zxf[(size_t)(t4 + 0) * DPROJ + 1024 + c] * w4.x;
    acc += zxf[(size_t)(t4 + 1) * DPROJ + 1024 + c] * w4.y;
    acc += zxf[(size_t)(t4 + 2) * DPROJ + 1024 + c] * w4.z;
    acc += zxf[(size_t)(t4 + 3) * DPROJ + 1024 + c] * w4.w;
    float r = siluf(acc);
    if (c >= 1024) bc16[(size_t)t4 * 256 + (c - 1024)] = f2bf(r);
    else           x16[(size_t)t4 * 1024 + c] = f2bf(r);
}

__global__ void convFpb_kernel(const float* __restrict__ zxf, const float* __restrict__ zxc,
                               const float* __restrict__ cw, const float* __restrict__ cb,
                               float* __restrict__ outp, unsigned short* __restrict__ bc16,
                               unsigned short* __restrict__ x16) {
    int idx = blockIdx.x * 256 + threadIdx.x;   // 8*4*1280
    int b = idx / 5120;
    int r = idx % 5120;
    int t = r / 1280, c = r % 1280;
    float4 w4 = *(const float4*)&cw[c * 4];
    float w[4] = {w4.x, w4.y, w4.z, w4.w};
    float acc = cb[c];
#pragma unroll
    for (int k = 0; k < 4; ++k) {
        int j = t - 3 + k;
        float x = 0.f;
        if (j == 0)      x = zxc[(size_t)b * DPROJ + 1024 + c];
        else if (j >= 1) x = zxf[(size_t)(j - 1) * DPROJ + 1024 + c];
        acc += x * w[k];
    }
    float rr = siluf(acc);
    outp[idx] = rr;   // fp32 kept: x0v, cbm rank-1 path
    if (c >= 1024) bc16[(size_t)(b * 4 + t) * 256 + (c - 1024)] = f2bf(rr);
    else           x16[(size_t)(b * 4 + t) * 1024 + c] = f2bf(rr);
}

__global__ void convBsh_kernel(const float* __restrict__ zxb, const float* __restrict__ cw,
                               const float* __restrict__ cb,
                               unsigned short* __restrict__ bc16, unsigned short* __restrict__ x16) {
    int idx = blockIdx.x * 256 + threadIdx.x;   // 2048*1280
    int s = idx / 1280, c = idx % 1280;
    float4 w4 = *(const float4*)&cw[c * 4];
    float w[4] = {w4.x, w4.y, w4.z, w4.w};
    float acc = cb[c];
#pragma unroll
    for (int k = 0; k < 4; ++k) {
        int j = s - 3 + k;
        if (j >= 0) acc += zxb[(size_t)(2047 - j) * DPROJ + 1024 + c] * w[k];
    }
    float r = siluf(acc);
    if (c >= 1024) bc16[(size_t)s * 256 + (c - 1024)] = f2bf(r);
    else           x16[(size_t)s * 1024 + c] = f2bf(r);
}

// ---------------- intra-chunk kernel (MFMA) ----------------

__global__ __launch_bounds__(256) void intra_kernel(
    const unsigned short* __restrict__ bcF, const unsigned short* __restrict__ bcFp,
    const unsigned short* __restrict__ bcB,
    const unsigned short* __restrict__ xF16, const unsigned short* __restrict__ xFp16,
    const unsigned short* __restrict__ xB16,
    const float* __restrict__ dtFsT, const float* __restrict__ dtBsT,
    const float* __restrict__ cumF, const float* __restrict__ cumB,
    unsigned short* __restrict__ YiF0, unsigned short* __restrict__ YiFs,
    unsigned short* __restrict__ YiB,
    unsigned short* __restrict__ UF0, unsigned short* __restrict__ UFs,
    unsigned short* __restrict__ UB) {
    __shared__ __align__(16) unsigned char smraw[63232];
    unsigned short* Bt = (unsigned short*)smraw;                    // 64 x 136  [s][n]
    unsigned short* Ct = (unsigned short*)(smraw + 17408);          // 64 x 136  [t][n]
    unsigned short* Sm = (unsigned short*)(smraw + 17408);          // 64 x 72   [t][s] (alias Ct)
    unsigned short* BT = (unsigned short*)(smraw + 34816);          // 128 x 72  [n][s]
    unsigned short* XT = (unsigned short*)(smraw + 53248);          // 64 x 72   [p][s]
    float* scum = (float*)(smraw + 62464);                          // 64
    float* sdt  = scum + 64;                                        // 64
    float* se   = scum + 128;                                       // 64

    const int iid = blockIdx.x;
    int dir, b = 0, h, c;
    unsigned short *Yout, *Uout;
    if (iid < 128)      { dir = 0; b = iid >> 4; h = iid & 15; c = 0;
                          Yout = YiF0 + (size_t)(b * 16 + h) * 4096; Uout = UF0 + (size_t)(b * 16 + h) * 8192; }
    else if (iid < 624) { int k = iid - 128; dir = 0; c = 1 + (k >> 4); h = k & 15;
                          Yout = YiFs + (size_t)(c * 16 + h) * 4096; Uout = UFs + (size_t)(c * 16 + h) * 8192; }
    else                { int k = iid - 624; dir = 1; c = k >> 4; h = k & 15;
                          Yout = YiB + (size_t)(c * 16 + h) * 4096;  Uout = UB + (size_t)(c * 16 + h) * 8192; }
    const float* dtAT = dir ? dtBsT : dtFsT;
    const float* cumA = dir ? cumB : cumF;

    const int tid = threadIdx.x;
    const int lane = tid & 63, wave = tid >> 6;
    const int quad = lane >> 4, l15 = lane & 15;

    {
        int r = tid >> 2, q = tid & 3;
        const unsigned short *bsrc, *xsrc;
        if (dir == 0) {
            int t = 64 * c + 1 + r;
            if (t < 4) { bsrc = bcFp + (size_t)(b * 4 + t) * 256; xsrc = xFp16 + (size_t)(b * 4 + t) * 1024; }
            else       { bsrc = bcF + (size_t)(t - 4) * 256;      xsrc = xF16 + (size_t)(t - 4) * 1024; }
        } else {
            int s = 64 * c + r;
            bsrc = bcB + (size_t)s * 256;
            xsrc = xB16 + (size_t)s * 1024;
        }
#pragma unroll
        for (int i = 0; i < 4; ++i) {
            int n0 = q * 32 + i * 8;
            uint4 v = *(const uint4*)&bsrc[n0];
            *(uint4*)&Bt[r * 136 + n0] = v;
            const unsigned short* pv = (const unsigned short*)&v;
#pragma unroll
            for (int jj = 0; jj < 8; ++jj) BT[(n0 + jj) * 72 + r] = pv[jj];
        }
#pragma unroll
        for (int i = 0; i < 4; ++i) {
            int n0 = q * 32 + i * 8;
            uint4 v = *(const uint4*)&bsrc[128 + n0];
            *(uint4*)&Ct[r * 136 + n0] = v;
        }
#pragma unroll
        for (int k = 0; k < 2; ++k) {
            uint4 v = *(const uint4*)&xsrc[h * 64 + q * 16 + k * 8];
            const unsigned short* pv = (const unsigned short*)&v;
#pragma unroll
            for (int jj = 0; jj < 8; ++jj) XT[(q * 16 + k * 8 + jj) * 72 + r] = pv[jj];
        }
        if (tid < 64) {
            int j = 64 * c + tid;
            scum[tid] = cumA[h * 2048 + j];
            sdt[tid] = dtAT[h * 2048 + j];
        }
    }
    __syncthreads();
    if (tid < 64) se[tid] = __expf(scum[63] - scum[tid]) * sdt[tid];

    // phase 1: G = C . B^T
    const int tm = (wave >> 1) * 32, sn = (wave & 1) * 32;
    f32x4 acc1[2][2];
#pragma unroll
    for (int i = 0; i < 2; ++i)
#pragma unroll
        for (int j = 0; j < 2; ++j) acc1[i][j] = (f32x4){0.f, 0.f, 0.f, 0.f};
#pragma unroll
    for (int ks = 0; ks < 4; ++ks) {
        bf16x8 af[2], bfr[2];
#pragma unroll
        for (int i = 0; i < 2; ++i)
            af[i] = *(const bf16x8*)&Ct[(tm + i * 16 + l15) * 136 + ks * 32 + quad * 8];
#pragma unroll
        for (int j = 0; j < 2; ++j)
            bfr[j] = *(const bf16x8*)&Bt[(sn + j * 16 + l15) * 136 + ks * 32 + quad * 8];
#pragma unroll
        for (int i = 0; i < 2; ++i)
#pragma unroll
            for (int j = 0; j < 2; ++j)
                acc1[i][j] = __builtin_amdgcn_mfma_f32_16x16x32_bf16(af[i], bfr[j], acc1[i][j], 0, 0, 0);
    }
    __syncthreads();

#pragma unroll
    for (int j = 0; j < 2; ++j) {
        int s = sn + j * 16 + l15;
        float cs = scum[s], ds = sdt[s];
#pragma unroll
        for (int i = 0; i < 2; ++i) {
#pragma unroll
            for (int r = 0; r < 4; ++r) {
                int t = tm + i * 16 + quad * 4 + r;
                float v = (s <= t) ? __expf(scum[t] - cs) * ds * acc1[i][j][r] : 0.f;
                Sm[t * 72 + s] = f2bf(v);
            }
        }
    }
    __syncthreads();

    // phase 2 (swapped): A = X^T rows p, B = Sm rows t -> D[p][t]
    const int pm = (wave >> 1) * 32, tn = (wave & 1) * 32;
    f32x4 acc2[2][2];
#pragma unroll
    for (int i = 0; i < 2; ++i)
#pragma unroll
        for (int j = 0; j < 2; ++j) acc2[i][j] = (f32x4){0.f, 0.f, 0.f, 0.f};
#pragma unroll
    for (int ks = 0; ks < 2; ++ks) {
        bf16x8 af[2], bfr[2];
#pragma unroll
        for (int i = 0; i < 2; ++i)
            af[i] = *(const bf16x8*)&XT[(pm + i * 16 + l15) * 72 + ks * 32 + quad * 8];
#pragma unroll
        for (int j = 0; j < 2; ++j)
            bfr[j] = *(const bf16x8*)&Sm[(tn + j * 16 + l15) * 72 + ks * 32 + quad * 8];
#pragma unroll
        for (int i = 0; i < 2; ++i)
#pragma unroll
            for (int j = 0; j < 2; ++j)
                acc2[i][j] = __builtin_amdgcn_mfma_f32_16x16x32_bf16(af[i], bfr[j], acc2[i][j], 0, 0, 0);
    }
#pragma unroll
    for (int i = 0; i < 2; ++i)
#pragma unroll
        for (int j = 0; j < 2; ++j) {
            int t = tn + j * 16 + l15;
            int p0 = pm + i * 16 + quad * 4;
            ushort4 o = make_ushort4(f2bf(acc2[i][j][0]), f2bf(acc2[i][j][1]),
                                     f2bf(acc2[i][j][2]), f2bf(acc2[i][j][3]));
            *(ushort4*)&Yout[t * 64 + p0] = o;
        }

    // phase 3: U = B^T . (e*X) -> write U[p][n]
    const int nm = wave * 32;
    f32x4 acc3[2][4];
#pragma unroll
    for (int i = 0; i < 2; ++i)
#pragma unroll
        for (int j = 0; j < 4; ++j) acc3[i][j] = (f32x4){0.f, 0.f, 0.f, 0.f};
#pragma unroll
    for (int ks = 0; ks < 2; ++ks) {
        float ev[8];
#pragma unroll
        for (int jj = 0; jj < 8; ++jj) ev[jj] = se[ks * 32 + quad * 8 + jj];
        bf16x8 bfx[4];
#pragma unroll
        for (int j = 0; j < 4; ++j) {
            bf16x8 xs = *(const bf16x8*)&XT[(j * 16 + l15) * 72 + ks * 32 + quad * 8];
#pragma unroll
            for (int jj = 0; jj < 8; ++jj)
                bfx[j][jj] = (short)f2bf(bfu((unsigned short)xs[jj]) * ev[jj]);
        }
        bf16x8 af[2];
#pragma unroll
        for (int i = 0; i < 2; ++i)
            af[i] = *(const bf16x8*)&BT[(nm + i * 16 + l15) * 72 + ks * 32 + quad * 8];
#pragma unroll
        for (int i = 0; i < 2; ++i)
#pragma unroll
            for (int j = 0; j < 4; ++j)
                acc3[i][j] = __builtin_amdgcn_mfma_f32_16x16x32_bf16(af[i], bfx[j], acc3[i][j], 0, 0, 0);
    }
#pragma unroll
    for (int i = 0; i < 2; ++i)
#pragma unroll
        for (int j = 0; j < 4; ++j) {
            int p = j * 16 + l15;
            int n0 = nm + i * 16 + quad * 4;
            ushort4 o = make_ushort4(f2bf(acc3[i][j][0]), f2bf(acc3[i][j][1]),
                                     f2bf(acc3[i][j][2]), f2bf(acc3[i][j][3]));
            *(ushort4*)&Uout[p * 128 + n0] = o;
        }
}

// ---------------- fused cb0 + M ----------------

__global__ void cbm_kernel(const float* __restrict__ convFp, const unsigned short* __restrict__ bcF,
                           const float* __restrict__ dtFp, const float* __restrict__ cumF,
                           const unsigned short* __restrict__ UF0,
                           float* __restrict__ cb0, unsigned short* __restrict__ Mb) {
    int blk = blockIdx.x, tid = threadIdx.x;   // 160
    if (blk < 32) {
        int idx = blk * 256 + tid;   // 8192
        int b = idx >> 10, r = idx & 1023, h = r >> 6, tl = r & 63;
        int t = tl + 1;
        const float* b0 = convFp + (size_t)(b * 4) * CONVD;
        float s = 0.f;
        if (t < 4) {
            const float* crow = convFp + (size_t)(b * 4 + t) * CONVD;
            for (int n = 0; n < 128; ++n) s += crow[1152 + n] * b0[1024 + n];
        } else {
            const unsigned short* cr = bcF + (size_t)(t - 4) * 256 + 128;
            for (int n = 0; n < 128; ++n) s += bfu(cr[n]) * b0[1024 + n];
        }
        cb0[(b * 16 + h) * 64 + tl] = s * dtFp[b * 16 + h];
    } else {
        int bh = blk - 32;   // 128
        int b = bh >> 4, h = bh & 15;
        float D0 = __expf(cumF[h * 2048 + 63]);
        float dt0 = dtFp[b * 16 + h];
        const float* row0 = convFp + (size_t)(b * 4) * CONVD;
        const unsigned short* u = UF0 + (size_t)(b * 16 + h) * 8192;
        unsigned short* m = Mb + (size_t)(b * 16 + h) * 8192;
        for (int e4 = tid; e4 < 2048; e4 += 256) {
            int e = e4 * 4, p = e >> 7, n0 = e & 127;
            float s = D0 * dt0 * row0[h * 64 + p];
            float4 B4 = *(const float4*)&row0[1024 + n0];
            ushort4 uv = *(const ushort4*)&u[e];
            ushort4 o = make_ushort4(f2bf(s * B4.x + bfu(uv.x)), f2bf(s * B4.y + bfu(uv.y)),
                                     f2bf(s * B4.z + bfu(uv.z)), f2bf(s * B4.w + bfu(uv.w)));
            *(ushort4*)&m[e] = o;
        }
    }
}

// ---------------- fused chunk-state scan + Yt GEMM (tpsi+yt) ----------------
// 32 blocks = (dir,h). State 64x128 in registers (32 f32/thread); per chunk:
// stash bf16(T) to LDS, GEMM Yt = C . T^T, update state with U (prefetched).

__global__ __launch_bounds__(256) void tyt_kernel(
    const unsigned short* __restrict__ UFs, const unsigned short* __restrict__ UB,
    const unsigned short* __restrict__ bcF, const unsigned short* __restrict__ bcB,
    const float* __restrict__ cumF, const float* __restrict__ cumB,
    unsigned short* __restrict__ YtF, unsigned short* __restrict__ YtB,
    float* __restrict__ psiF) {
    __shared__ __align__(16) unsigned short Tl[64 * 136];   // [p][n]
    const int blk = blockIdx.x;
    const int dir = blk >> 4, h = blk & 15;
    const unsigned short* U = dir ? UB : UFs;
    const float* cum = dir ? cumB : cumF;
    unsigned short* Yt = dir ? YtB : YtF;
    const int tid = threadIdx.x;
    const int lane = tid & 63, wave = tid >> 6;
    const int quad = lane >> 4, l15 = lane & 15;
    const int pm = (wave >> 1) * 32, tb = (wave & 1) * 32;

    if (dir == 0 && tid == 0) {
        float ps = 1.f;
        for (int c = 1; c < 32; ++c) {
            psiF[h * 32 + c] = ps;
            ps *= __expf(cumF[h * 2048 + c * 64 + 63]);
        }
    }

    f32x4 st[8];
#pragma unroll
    for (int q = 0; q < 8; ++q) st[q] = (f32x4){0.f, 0.f, 0.f, 0.f};
    const int c0 = dir ? 0 : 1;
    ushort4 u[8];
#pragma unroll
    for (int q = 0; q < 8; ++q)
        u[q] = *(const ushort4*)&U[((size_t)c0 * 16 + h) * 8192 + q * 1024 + 4 * tid];

    for (int c = c0; c < 32; ++c) {
        // stash T_c = st (pre-update) into LDS as bf16
#pragma unroll
        for (int q = 0; q < 8; ++q) {
            int e = q * 1024 + 4 * tid;
            int p = e >> 7, n = e & 127;
            ushort4 o = make_ushort4(f2bf(st[q][0]), f2bf(st[q][1]), f2bf(st[q][2]), f2bf(st[q][3]));
            *(ushort4*)&Tl[p * 136 + n] = o;
        }
        __syncthreads();
        // prefetch next U
        ushort4 un[8];
#pragma unroll
        for (int q = 0; q < 8; ++q) un[q] = make_ushort4(0, 0, 0, 0);
        if (c + 1 < 32)
#pragma unroll
            for (int q = 0; q < 8; ++q)
                un[q] = *(const ushort4*)&U[((size_t)(c + 1) * 16 + h) * 8192 + q * 1024 + 4 * tid];
        // GEMM: Yt[t][p] = sum_n C[t][n] * T[p][n]
        const unsigned short* Cbase = dir ? bcB + ((size_t)(64 * c)) * 256 + 128
                                          : bcF + ((size_t)(64 * c - 3)) * 256 + 128;
        f32x4 acc[2][2];
#pragma unroll
        for (int i = 0; i < 2; ++i)
#pragma unroll
            for (int j = 0; j < 2; ++j) acc[i][j] = (f32x4){0.f, 0.f, 0.f, 0.f};
#pragma unroll
        for (int ks = 0; ks < 4; ++ks) {
            bf16x8 af[2], bfr[2];
#pragma unroll
            for (int i = 0; i < 2; ++i)
                af[i] = *(const bf16x8*)&Tl[(pm + i * 16 + l15) * 136 + ks * 32 + quad * 8];
#pragma unroll
            for (int j = 0; j < 2; ++j)
                bfr[j] = *(const bf16x8*)&Cbase[(size_t)(tb + j * 16 + l15) * 256 + ks * 32 + quad * 8];
#pragma unroll
            for (int i = 0; i < 2; ++i)
#pragma unroll
                for (int j = 0; j < 2; ++j)
                    acc[i][j] = __builtin_amdgcn_mfma_f32_16x16x32_bf16(af[i], bfr[j], acc[i][j], 0, 0, 0);
        }
        unsigned short* Yc = Yt + (size_t)(c * 16 + h) * 4096;
#pragma unroll
        for (int i = 0; i < 2; ++i)
#pragma unroll
            for (int j = 0; j < 2; ++j) {
                int t = tb + j * 16 + l15;
                int p0 = pm + i * 16 + quad * 4;
                ushort4 o = make_ushort4(f2bf(acc[i][j][0]), f2bf(acc[i][j][1]),
                                         f2bf(acc[i][j][2]), f2bf(acc[i][j][3]));
                *(ushort4*)&Yc[t * 64 + p0] = o;
            }
        // state update
        float Dc = __expf(cum[h * 2048 + c * 64 + 63]);
#pragma unroll
        for (int q = 0; q < 8; ++q) {
            st[q][0] = Dc * st[q][0] + bfu(u[q].x);
            st[q][1] = Dc * st[q][1] + bfu(u[q].y);
            st[q][2] = Dc * st[q][2] + bfu(u[q].z);
            st[q][3] = Dc * st[q][3] + bfu(u[q].w);
            u[q] = un[q];
        }
        __syncthreads();
    }
}

// ---------------- gate kernel: 4 chunks/block, M fragments cached in regs ----------------

__global__ __launch_bounds__(256) void gate_kernel(
    const unsigned short* __restrict__ bcF,
    const unsigned short* __restrict__ Mb, const float* __restrict__ psiF,
    const unsigned short* __restrict__ YtF, const unsigned short* __restrict__ YtB,
    const unsigned short* __restrict__ xF16, const unsigned short* __restrict__ xFp16,
    const unsigned short* __restrict__ xB16,
    const unsigned short* __restrict__ szF, const unsigned short* __restrict__ szB,
    const float* __restrict__ convFp,
    const float* __restrict__ cumF, const float* __restrict__ cumB,
    const unsigned short* __restrict__ YiF0, const unsigned short* __restrict__ YiFs,
    const unsigned short* __restrict__ YiB,
    const float* __restrict__ cb0,
    const float* __restrict__ fD, const float* __restrict__ bD,
    const float* __restrict__ wf2, const float* __restrict__ wb2,
    float* __restrict__ aF, float* __restrict__ aB) {
    __shared__ __align__(16) float Ysm[64 * 68];

    const int iid = blockIdx.x;   // 1152: fwd 1024 (b,h,cg), bwd 128 (h,cg)
    int dir, b = 0, h, cg;
    if (iid < 1024) { dir = 0; b = iid >> 7; int r = iid & 127; h = r >> 3; cg = r & 7; }
    else            { int k = iid - 1024; dir = 1; h = k >> 3; cg = k & 7; }
    const int tid = threadIdx.x, tx = tid & 15, ty = tid >> 4;
    const int lane = tid & 63, wave = tid >> 6;
    const int quad = lane >> 4, l15 = lane & 15;

    const float Dh = (dir ? bD : fD)[h];
    const float* wvp = dir ? wb2 : wf2;
    float4 wreg = *(const float4*)&wvp[h * 64 + tx * 4];
    const float* cumA = dir ? cumB : cumF;

    const int pm = (wave >> 1) * 32, tb = (wave & 1) * 32;
    bf16x8 mfr[4][2];
    if (dir == 0) {
        const unsigned short* Mp = Mb + (size_t)(b * 16 + h) * 8192;
#pragma unroll
        for (int ks = 0; ks < 4; ++ks)
#pragma unroll
            for (int i = 0; i < 2; ++i)
                mfr[ks][i] = *(const bf16x8*)&Mp[(size_t)(pm + i * 16 + l15) * 128 + ks * 32 + quad * 8];
    }

    for (int cc = 0; cc < 4; ++cc) {
        const int c = cg * 4 + cc;
        const bool fwdG = (dir == 0 && c > 0);
        if (fwdG) {
            if (cc > 0) __syncthreads();   // prior epilogue done reading Ysm
            const unsigned short* Cbase = bcF + ((size_t)(64 * c - 3)) * 256 + 128;
            f32x4 acc[2][2];
#pragma unroll
            for (int i = 0; i < 2; ++i)
#pragma unroll
                for (int j = 0; j < 2; ++j) acc[i][j] = (f32x4){0.f, 0.f, 0.f, 0.f};
#pragma unroll
            for (int ks = 0; ks < 4; ++ks) {
                bf16x8 bfr[2];
#pragma unroll
                for (int j = 0; j < 2; ++j)
                    bfr[j] = *(const bf16x8*)&Cbase[(size_t)(tb + j * 16 + l15) * 256 + ks * 32 + quad * 8];
#pragma unroll
                for (int i = 0; i < 2; ++i)
#pragma unroll
                    for (int j = 0; j < 2; ++j)
                        acc[i][j] = __builtin_amdgcn_mfma_f32_16x16x32_bf16(mfr[ks][i], bfr[j], acc[i][j], 0, 0, 0);
            }
#pragma unroll
            for (int i = 0; i < 2; ++i)
#pragma unroll
                for (int j = 0; j < 2; ++j)
                    *(f32x4*)&Ysm[(tb + j * 16 + l15) * 68 + pm + i * 16 + quad * 4] = acc[i][j];
            __syncthreads();
        }

        const float psi = fwdG ? psiF[h * 32 + c] : 0.f;
        const unsigned short* Ytp = fwdG ? (YtF + (size_t)(c * 16 + h) * 4096)
                                         : (dir ? (YtB + (size_t)(c * 16 + h) * 4096) : nullptr);
        float4 x0v = make_float4(0.f, 0.f, 0.f, 0.f);
        float cbv[4] = {0.f, 0.f, 0.f, 0.f};
        if (dir == 0 && c == 0) {
            x0v = *(const float4*)&convFp[(size_t)(b * 4) * CONVD + h * 64 + tx * 4];
#pragma unroll
            for (int i = 0; i < 4; ++i) cbv[i] = cb0[(b * 16 + h) * 64 + (ty + 16 * i)];
        }

        float rawet[4];
        ushort4 yi4a[4], x4a[4], z4a[4], yt4a[4];
        float4 cm4a[4];
#pragma unroll
        for (int i = 0; i < 4; ++i) {
            int tl = ty + 16 * i;
            int j = 64 * c + tl;
            rawet[i] = cumA[h * 2048 + j];
            const unsigned short *Yi, *xp, *zp;
            if (dir == 0) {
                Yi = (c == 0) ? YiF0 + (size_t)(b * 16 + h) * 4096 : YiFs + (size_t)(c * 16 + h) * 4096;
                if (c == 0) {
                    int t = j + 1;
                    xp = (t < 4) ? xFp16 + (size_t)(b * 4 + t) * 1024 : xF16 + (size_t)(t - 4) * 1024;
                } else {
                    xp = xF16 + (size_t)(64 * c + tl - 3) * 1024;
                }
                zp = szF + (size_t)j * 1024;
            } else {
                Yi = YiB + (size_t)(c * 16 + h) * 4096;
                xp = xB16 + (size_t)j * 1024;
                zp = szB + (size_t)(2047 - j) * 1024;
            }
            yi4a[i] = *(const ushort4*)&Yi[tl * 64 + tx * 4];
            x4a[i] = *(const ushort4*)&xp[h * 64 + tx * 4];
            z4a[i] = *(const ushort4*)&zp[h * 64 + tx * 4];
            yt4a[i] = Ytp ? *(const ushort4*)&Ytp[tl * 64 + tx * 4] : make_ushort4(0, 0, 0, 0);
            cm4a[i] = fwdG ? *(const float4*)&Ysm[tl * 68 + tx * 4] : make_float4(0.f, 0.f, 0.f, 0.f);
        }

#pragma unroll
        for (int i = 0; i < 4; ++i) {
            int j = 64 * c + ty + 16 * i;
            float et = __expf(rawet[i]);
            float yv[4] = {bfu(yi4a[i].x), bfu(yi4a[i].y), bfu(yi4a[i].z), bfu(yi4a[i].w)};
            float xa[4] = {bfu(x4a[i].x), bfu(x4a[i].y), bfu(x4a[i].z), bfu(x4a[i].w)};
            float sza[4] = {h2f(z4a[i].x), h2f(z4a[i].y), h2f(z4a[i].z), h2f(z4a[i].w)};
            float ya[4] = {bfu(yt4a[i].x) + psi * cm4a[i].x, bfu(yt4a[i].y) + psi * cm4a[i].y,
                           bfu(yt4a[i].z) + psi * cm4a[i].z, bfu(yt4a[i].w) + psi * cm4a[i].w};
            float x0a[4] = {x0v.x, x0v.y, x0v.z, x0v.w};
            float wa[4] = {wreg.x, wreg.y, wreg.z, wreg.w};
            float a1 = 0.f, a2 = 0.f;
#pragma unroll
            for (int w = 0; w < 4; ++w) {
                float tot = yv[w] + et * (ya[w] + cbv[i] * x0a[w]) + Dh * xa[w];
                float g = tot * sza[w];
                a1 += g * wa[w];
                a2 += g * g;
            }
#pragma unroll
            for (int m = 1; m < 16; m <<= 1) {
                a1 += __shfl_xor(a1, m);
                a2 += __shfl_xor(a2, m);
            }
            if (tx == 0) {
                if (dir == 0) {
                    size_t o = ((size_t)(b * 2048 + j) * 16 + h) * 2;
                    aF[o] = a1; aF[o + 1] = a2;
                } else {
                    int g = 2047 - j;
                    size_t o = ((size_t)g * 16 + h) * 2;
                    aB[o] = a1; aB[o + 1] = a2;
                }
            }
        }
    }
}

// ---------------- final combine ----------------

__global__ void final_kernel(const float* __restrict__ aF, const float* __restrict__ aB,
                             const float* __restrict__ headB, float* __restrict__ out) {
    int idx = blockIdx.x * 256 + threadIdx.x;   // 16384
    int b = idx >> 11, g = idx & 2047;
    const float* pf = aF + ((size_t)(b * 2048 + g)) * 32;
    const float* pb = aB + (size_t)g * 32;
    float f1 = 0.f, f2 = 0.f, b1 = 0.f, b2 = 0.f;
#pragma unroll
    for (int h = 0; h < 16; ++h) {
        f1 += pf[2 * h]; f2 += pf[2 * h + 1];
        b1 += pb[2 * h]; b2 += pb[2 * h + 1];
    }
    out[idx] = f1 * rsqrtf(f2 * (1.f / 1024.f) + 1e-5f) +
               b1 * rsqrtf(b2 * (1.f / 1024.f) + 1e-5f) + headB[0];
}

// ---------------- launch ----------------

extern "C" void kernel_launch(void* const* d_in, const int* in_sizes, int n_in,
                              void* d_out, int out_size, void* d_ws, size_t ws_size,
                              hipStream_t stream) {
    const int*   pidx   = (const int*)  d_in[0];
    const int*   chridx = (const int*)  d_in[1];
    const float* locusF = (const float*)d_in[2];
    const float* pathF  = (const float*)d_in[3];
    const float* pertE  = (const float*)d_in[4];
    const float* gidE   = (const float*)d_in[5];
    const float* chrE   = (const float*)d_in[6];
    const float* locusW = (const float*)d_in[7];
    const float* locusB = (const float*)d_in[8];
    const float* condW  = (const float*)d_in[9];
    const float* condB  = (const float*)d_in[10];
    const float* inW    = (const float*)d_in[11];
    const float* inB    = (const float*)d_in[12];
    const float* headW  = (const float*)d_in[13];
    const float* headB  = (const float*)d_in[14];
    const float* fInW   = (const float*)d_in[15];
    const float* fCw    = (const float*)d_in[16];
    const float* fCb    = (const float*)d_in[17];
    const float* fDtB   = (const float*)d_in[18];
    const float* fAlog  = (const float*)d_in[19];
    const float* fDp    = (const float*)d_in[20];
    const float* fNw    = (const float*)d_in[21];
    const float* fOutW  = (const float*)d_in[22];
    const float* bInW   = (const float*)d_in[23];
    const float* bCw    = (const float*)d_in[24];
    const float* bCb    = (const float*)d_in[25];
    const float* bDtB   = (const float*)d_in[26];
    const float* bAlog  = (const float*)d_in[27];
    const float* bDp    = (const float*)d_in[28];
    const float* bNw    = (const float*)d_in[29];
    const float* bOutW  = (const float*)d_in[30];
    float* out = (float*)d_out;
    (void)in_sizes; (void)n_in; (void)out_size; (void)ws_size;

    char* base = (char*)d_ws;
    size_t off = 0;
    auto allocf = [&](size_t n) -> float* {
        char* r = base + off; off += ((n * 4 + 63) & ~(size_t)63); return (float*)r; };
    auto allocu = [&](size_t n) -> unsigned short* {
        char* r = base + off; off += ((n * 2 + 63) & ~(size_t)63); return (unsigned short*)r; };

    float* gf     = allocf(2048UL * 384);
    float* cond   = allocf(8UL * 384);
    float* cemb   = allocf(8UL * 128);
    float* uc     = allocf(8UL * 512);
    float* zxf    = allocf(2048UL * DPROJ);
    float* zxb    = allocf(2048UL * DPROJ);
    float* zxc    = allocf(8UL * DPROJ);
    float* convFp = allocf(8UL * 4 * CONVD);
    float* dtFsT  = allocf(16UL * 2048);
    float* dtFp   = allocf(128);
    float* dtBsT  = allocf(16UL * 2048);
    float* cumF   = allocf(16UL * 2048);
    float* cumB   = allocf(16UL * 2048);
    float* wf2    = allocf(1024);
    float* wb2    = allocf(1024);
    float* cb0    = allocf(8UL * 16 * 64);
    float* psiF   = allocf(16UL * 32);
    float* aF     = allocf(8UL * 2048 * 16 * 2);
    float* aB     = allocf(2048UL * 16 * 2);
    unsigned short* YiF0 = allocu(8UL * 16 * 4096);
    unsigned short* YiFs = allocu(32UL * 16 * 4096);
    unsigned short* YiB  = allocu(32UL * 16 * 4096);
    unsigned short* UF0  = allocu(8UL * 16 * 8192);
    unsigned short* UFs  = allocu(32UL * 16 * 8192);
    unsigned short* UB   = allocu(32UL * 16 * 8192);
    unsigned short* Mb   = allocu(8UL * 16 * 8192);
    unsigned short* bcF  = allocu(2045UL * 256);
    unsigned short* bcFp = allocu(32UL * 256);
    unsigned short* bcB  = allocu(2048UL * 256);
    unsigned short* YtF  = allocu(32UL * 16 * 4096);
    unsigned short* YtB  = allocu(32UL * 16 * 4096);
    unsigned short* xF16 = allocu(2045UL * 1024);
    unsigned short* xFp16= allocu(32UL * 1024);
    unsigned short* xB16 = allocu(2048UL * 1024);
    unsigned short* szF  = allocu(2048UL * 1024);
    unsigned short* szB  = allocu(2048UL * 1024);
    unsigned short* gf2   = allocu(2048UL * 384);
    unsigned short* inW2  = allocu(512UL * 384);
    unsigned short* ug2   = allocu(2048UL * 512);
    unsigned short* fInW2 = allocu(2432UL * 512);
    unsigned short* bInW2 = allocu(2432UL * 512);

    gg_kernel<<<3077, 256, 0, stream>>>(chridx, gidE, pathF, chrE, pidx, pertE, gf, cemb, wf2, wb2);
    wfold_kernel<<<128, 256, 0, stream>>>(headW, fOutW, fNw, bOutW, bNw, wf2, wb2);
    gemm_kernel<<<dim3(1, 32), 256, 0, stream>>>(locusF, locusW, locusB, gf + 320, 2048, 64, 64, 384, 1);
    gemm_kernel<<<dim3(6, 1), 256, 0, stream>>>(cemb, condW, condB, cond, 8, 384, 128, 384, 0);

    tobf4_kernel<<<13568, 256, 0, stream>>>(inW, fInW, bInW, gf, inW2, fInW2, bInW2, gf2);

    // ug2 = bf16(gf @ inW^T + inB), written directly by the GEMM epilogue
    mfma_gemm_kernel<<<dim3(4, 16), 256, 0, stream>>>(gf2, inW2, inB, nullptr, ug2, nullptr, 512, 384, 512);
    gemm_kernel<<<dim3(8, 1), 256, 0, stream>>>(cond, inW, inB, uc, 8, 512, 384, 512, 0);

    // zx = ug2 @ W^T; z-region (n<1024) emitted as fp16 silu directly
    mfma_gemm_kernel<<<dim3(19, 16), 256, 0, stream>>>(ug2, fInW2, nullptr, zxf, nullptr, szF, 2320, 512, DPROJ);
    mfma_gemm_kernel<<<dim3(19, 16), 256, 0, stream>>>(ug2, bInW2, nullptr, zxb, nullptr, szB, 2320, 512, DPROJ);
    gemm_kernel<<<dim3(37, 1), 256, 0, stream>>>(uc, fInW, nullptr, zxc, 8, DPROJ, 512, DPROJ, 0);

    cum_kernel<<<5, 256, 0, stream>>>(zxf, zxb, zxc, fDtB, bDtB, fAlog, bAlog,
                                      dtFsT, dtBsT, dtFp, cumF, cumB);
    convFsh_kernel<<<(2045 * 1280 + 255) / 256, 256, 0, stream>>>(zxf, fCw, fCb, bcF, xF16);
    convFpb_kernel<<<160, 256, 0, stream>>>(zxf, zxc, fCw, fCb, convFp, bcFp, xFp16);
    convBsh_kernel<<<10240, 256, 0, stream>>>(zxb, bCw, bCb, bcB, xB16);
    intra_kernel<<<1136, 256, 0, stream>>>(bcF, bcFp, bcB, xF16, xFp16, xB16,
                                           dtFsT, dtBsT, cumF, cumB,
                                           YiF0, YiFs, YiB, UF0, UFs, UB);
    cbm_kernel<<<160, 256, 0, stream>>>(convFp, bcF, dtFp, cumF, UF0, cb0, Mb);
    tyt_kernel<<<32, 256, 0, stream>>>(UFs, UB, bcF, bcB, cumF, cumB, YtF, YtB, psiF);
    gate_kernel<<<1152, 256, 0, stream>>>(bcF, Mb, psiF, YtF, YtB, xF16, xFp16, xB16,
                                          szF, szB, convFp, cumF, cumB,
                                          YiF0, YiFs, YiB, cb0, fDp, bDp, wf2, wb2, aF, aB);
    final_kernel<<<64, 256, 0, stream>>>(aF, aB, headB, out);
}

// Round 10
// 397.171 us; speedup vs baseline: 1.2036x; 1.2036x over previous
//
#include <hip/hip_runtime.h>
#include <hip/hip_bf16.h>
#include <hip/hip_fp16.h>
#include <math.h>

#define DPROJ 2320
#define CONVD 1280

typedef __attribute__((ext_vector_type(8))) short bf16x8;
typedef __attribute__((ext_vector_type(4))) float f32x4;

__device__ __forceinline__ float siluf(float x) { return x / (1.f + __expf(-x)); }
__device__ __forceinline__ float bfu(unsigned short s) { return __uint_as_float(((unsigned)s) << 16); }
__device__ __forceinline__ unsigned short f2bf(float f) {
    unsigned u = __float_as_uint(f);
    unsigned r = (u + 0x7FFFu + ((u >> 16) & 1u)) >> 16;
    return (unsigned short)r;
}
__device__ __forceinline__ unsigned short f2h(float f) {
    __half h = __float2half(f);
    return *(unsigned short*)&h;
}
__device__ __forceinline__ float h2f(unsigned short s) {
    __half h = *(__half*)&s;
    return __half2float(h);
}

// ---------------- fused gather + genefeat + wfold-zero ----------------

__global__ void gg_kernel(const int* __restrict__ chridx, const float* __restrict__ gid,
                          const float* __restrict__ path, const float* __restrict__ chrE,
                          const int* __restrict__ pidx, const float* __restrict__ pertE,
                          float* __restrict__ gf, float* __restrict__ cemb,
                          float* __restrict__ wf2, float* __restrict__ wb2) {
    int blk = blockIdx.x, tid = threadIdx.x;
    if (blk < 3072) {
        int idx = blk * 256 + tid;   // 2048*384
        int g = idx / 384, j = idx % 384;
        float v;
        if (j < 128)      v = gid[(size_t)g * 128 + j];
        else if (j < 256) v = path[(size_t)g * 128 + (j - 128)];
        else if (j < 320) v = chrE[(size_t)chridx[g] * 64 + (j - 256)];
        else return;
        gf[idx] = v;
    } else if (blk < 3076) {
        int idx = (blk - 3072) * 256 + tid;   // 1024
        int b = idx >> 7, k = idx & 127;
        cemb[idx] = pertE[(size_t)pidx[b] * 128 + k];
    } else {
        wf2[tid * 4 + 0] = 0.f; wf2[tid * 4 + 1] = 0.f;
        wf2[tid * 4 + 2] = 0.f; wf2[tid * 4 + 3] = 0.f;
        wb2[tid * 4 + 0] = 0.f; wb2[tid * 4 + 1] = 0.f;
        wb2[tid * 4 + 2] = 0.f; wb2[tid * 4 + 3] = 0.f;
    }
}

// wfold: split-m atomic partial sums. 128 blocks = dir(2) x dseg(4) x mseg(16)
__global__ void wfold_kernel(const float* __restrict__ headW,
                             const float* __restrict__ fOutW, const float* __restrict__ fNw,
                             const float* __restrict__ bOutW, const float* __restrict__ bNw,
                             float* __restrict__ wf2, float* __restrict__ wb2) {
    int blk = blockIdx.x;
    int dir = blk >> 6;
    int rem = blk & 63;
    int dseg = rem >> 4, mseg = rem & 15;
    int tid = threadIdx.x;
    int d = dseg * 256 + tid;
    const float* W = dir ? bOutW : fOutW;
    float s = 0.f;
#pragma unroll
    for (int m = mseg * 32; m < mseg * 32 + 32; ++m)
        s += headW[m] * W[(size_t)m * 1024 + d];
    const float* nw = dir ? bNw : fNw;
    atomicAdd(&(dir ? wb2 : wf2)[d], s * nw[d]);
}

// ---------------- fused bf16 conversions (weights + gf) ----------------

__global__ void tobf4_kernel(const float* __restrict__ inW, const float* __restrict__ fInW,
                             const float* __restrict__ bInW, const float* __restrict__ gf,
                             unsigned short* __restrict__ inW2, unsigned short* __restrict__ fInW2,
                             unsigned short* __restrict__ bInW2, unsigned short* __restrict__ gf2) {
    size_t idx = (size_t)blockIdx.x * 256 + threadIdx.x;
    const size_t A = 512UL * 384, B5 = 2432UL * 512;
    if (idx < A) {
        inW2[idx] = f2bf(inW[idx]);
    } else if (idx < A + B5) {
        size_t k = idx - A; int m = k / 512, kk = k % 512;
        fInW2[k] = f2bf(m < 2320 ? fInW[(size_t)m * 512 + kk] : 0.f);
    } else if (idx < A + 2 * B5) {
        size_t k = idx - A - B5; int m = k / 512, kk = k % 512;
        bInW2[k] = f2bf(m < 2320 ? bInW[(size_t)m * 512 + kk] : 0.f);
    } else {
        size_t k = idx - A - 2 * B5;   // 2048*384
        gf2[k] = f2bf(gf[k]);
    }
}

// ---------------- MFMA GEMM with fused epilogue modes ----------------
// C fp32 (nullable), Cbf bf16 (nullable), sz: for n<1024 write f2h(silu(v)) instead.

__global__ __launch_bounds__(256) void mfma_gemm_kernel(
    const unsigned short* __restrict__ A2, const unsigned short* __restrict__ W2,
    const float* __restrict__ bias, float* __restrict__ C,
    unsigned short* __restrict__ Cbf, unsigned short* __restrict__ sz,
    int N, int K2, int ldc) {
    __shared__ __align__(16) unsigned short Al[128 * 40];
    __shared__ __align__(16) unsigned short Bl[128 * 40];
    const int tid = threadIdx.x;
    const int bm = blockIdx.y * 128, bn = blockIdx.x * 128;
    const int lane = tid & 63, wave = tid >> 6;
    const int wm = (wave >> 1) * 64, wn = (wave & 1) * 64;
    f32x4 acc[4][4];
#pragma unroll
    for (int i = 0; i < 4; ++i)
#pragma unroll
        for (int j = 0; j < 4; ++j) acc[i][j] = (f32x4){0.f, 0.f, 0.f, 0.f};

    for (int k0 = 0; k0 < K2; k0 += 32) {
        __syncthreads();
#pragma unroll
        for (int s = 0; s < 2; ++s) {
            int ch = tid + 256 * s;
            int row = ch >> 2, q = ch & 3;
            uint4 va = *(const uint4*)&A2[(size_t)(bm + row) * K2 + k0 + q * 8];
            *(uint4*)&Al[row * 40 + q * 8] = va;
            uint4 vb = *(const uint4*)&W2[(size_t)(bn + row) * K2 + k0 + q * 8];
            *(uint4*)&Bl[row * 40 + q * 8] = vb;
        }
        __syncthreads();
        bf16x8 af[4], bfr[4];
#pragma unroll
        for (int i = 0; i < 4; ++i)
            af[i] = *(const bf16x8*)&Al[(wm + i * 16 + (lane & 15)) * 40 + (lane >> 4) * 8];
#pragma unroll
        for (int j = 0; j < 4; ++j)
            bfr[j] = *(const bf16x8*)&Bl[(wn + j * 16 + (lane & 15)) * 40 + (lane >> 4) * 8];
#pragma unroll
        for (int i = 0; i < 4; ++i)
#pragma unroll
            for (int j = 0; j < 4; ++j)
                acc[i][j] = __builtin_amdgcn_mfma_f32_16x16x32_bf16(af[i], bfr[j], acc[i][j], 0, 0, 0);
    }
#pragma unroll
    for (int i = 0; i < 4; ++i) {
        int m = bm + wm + i * 16 + (lane >> 4) * 4;
#pragma unroll
        for (int j = 0; j < 4; ++j) {
            int n = bn + wn + j * 16 + (lane & 15);
            if (n < N) {
                float bv = bias ? bias[n] : 0.f;
#pragma unroll
                for (int r = 0; r < 4; ++r) {
                    float v = acc[i][j][r] + bv;
                    if (sz && n < 1024)
                        sz[(size_t)(m + r) * 1024 + n] = f2h(siluf(v));
                    else if (Cbf)
                        Cbf[(size_t)(m + r) * ldc + n] = f2bf(v);
                    else
                        C[(size_t)(m + r) * ldc + n] = v;
                }
            }
        }
    }
}

// ---------------- generic tiled fp32 GEMM (small shapes only) ----------------

__global__ __launch_bounds__(256) void gemm_kernel(
    const float* __restrict__ A, const float* __restrict__ W,
    const float* __restrict__ bias, float* __restrict__ C,
    int M, int N, int K, int ldc, int act) {
    __shared__ __align__(16) float As[16][68];
    __shared__ __align__(16) float Ws[16][68];
    const int tid = threadIdx.x;
    const int tx = tid & 15, ty = tid >> 4;
    const int bm = blockIdx.y * 64, bn = blockIdx.x * 64;
    const int lr = tid >> 2;
    const int lk = (tid & 3) * 4;
    float acc[4][4];
#pragma unroll
    for (int i = 0; i < 4; ++i)
#pragma unroll
        for (int j = 0; j < 4; ++j) acc[i][j] = 0.f;

    for (int k0 = 0; k0 < K; k0 += 16) {
        const int am = bm + lr;
        const int wn = bn + lr;
        float4 av = make_float4(0.f, 0.f, 0.f, 0.f), wv = make_float4(0.f, 0.f, 0.f, 0.f);
        if (am < M) av = *(const float4*)&A[(size_t)am * K + k0 + lk];
        if (wn < N) wv = *(const float4*)&W[(size_t)wn * K + k0 + lk];
        __syncthreads();
        As[lk + 0][lr] = av.x; As[lk + 1][lr] = av.y; As[lk + 2][lr] = av.z; As[lk + 3][lr] = av.w;
        Ws[lk + 0][lr] = wv.x; Ws[lk + 1][lr] = wv.y; Ws[lk + 2][lr] = wv.z; Ws[lk + 3][lr] = wv.w;
        __syncthreads();
#pragma unroll
        for (int kk = 0; kk < 16; ++kk) {
            float4 a = *(const float4*)&As[kk][ty * 4];
            float4 w = *(const float4*)&Ws[kk][tx * 4];
            float aa[4] = {a.x, a.y, a.z, a.w}, ww[4] = {w.x, w.y, w.z, w.w};
#pragma unroll
            for (int i = 0; i < 4; ++i)
#pragma unroll
                for (int j = 0; j < 4; ++j) acc[i][j] += aa[i] * ww[j];
        }
    }
#pragma unroll
    for (int i = 0; i < 4; ++i) {
        const int m = bm + ty * 4 + i;
        if (m >= M) continue;
#pragma unroll
        for (int j = 0; j < 4; ++j) {
            const int n = bn + tx * 4 + j;
            if (n >= N) continue;
            float v = acc[i][j] + (bias ? bias[n] : 0.f);
            if (act == 1) v = 0.5f * v * (1.f + erff(v * 0.70710678118654752f));
            C[(size_t)m * ldc + n] = v;
        }
    }
}

// ---------------- dt precompute (parallel, transposed out) ----------------

__global__ void dt_kernel(const float* __restrict__ zxf, const float* __restrict__ zxb,
                          const float* __restrict__ zxc,
                          const float* __restrict__ fDtB, const float* __restrict__ bDtB,
                          float* __restrict__ dtFsT, float* __restrict__ dtBsT,
                          float* __restrict__ dtFp) {
    int idx = blockIdx.x * 256 + threadIdx.x;   // 65664
    if (idx < 32768) {
        int r = idx >> 4, hh = idx & 15;
        float raw = zxf[(size_t)r * DPROJ + 2304 + hh] + fDtB[hh];
        dtFsT[hh * 2048 + r] = (raw > 20.f) ? raw : log1pf(expf(raw));
    } else if (idx < 65536) {
        int k = idx - 32768;
        int r = k >> 4, hh = k & 15;
        float raw = zxb[(size_t)(2047 - r) * DPROJ + 2304 + hh] + bDtB[hh];
        dtBsT[hh * 2048 + r] = (raw > 20.f) ? raw : log1pf(expf(raw));
    } else if (idx < 65664) {
        int k = idx - 65536;
        int b = k >> 4, hh = k & 15;
        float raw = zxc[(size_t)b * DPROJ + 2304 + hh] + fDtB[hh];
        dtFp[k] = (raw > 20.f) ? raw : log1pf(expf(raw));
    }
}

// chunk-local inclusive cumsum of ldA = -dt*exp(A_log), transposed input
__global__ void cum_kernel(const float* __restrict__ dtFsT, const float* __restrict__ dtBsT,
                           const float* __restrict__ fAlog, const float* __restrict__ bAlog,
                           float* __restrict__ cumF, float* __restrict__ cumB) {
    int id = blockIdx.x * 256 + threadIdx.x;   // 1024
    int dir = id >> 9, k = id & 511, h = k >> 5, c = k & 31;
    const float* dtT = dir ? dtBsT : dtFsT;
    const float* Al = dir ? bAlog : fAlog;
    float* cum = dir ? cumB : cumF;
    float a = -expf(Al[h]);
    float acc = 0.f;
    for (int s4 = 0; s4 < 16; ++s4) {
        float4 v = *(const float4*)&dtT[h * 2048 + c * 64 + s4 * 4];
        float4 o;
        acc += v.x * a; o.x = acc;
        acc += v.y * a; o.y = acc;
        acc += v.z * a; o.z = acc;
        acc += v.w * a; o.w = acc;
        *(float4*)&cum[h * 2048 + c * 64 + s4 * 4] = o;
    }
}

// ---------------- causal depthwise conv (+SiLU): bf16 B/C + bf16 x side-copies only ----------------

__global__ void convFsh_kernel(const float* __restrict__ zxf, const float* __restrict__ cw,
                               const float* __restrict__ cb,
                               unsigned short* __restrict__ bc16, unsigned short* __restrict__ x16) {
    int idx = blockIdx.x * 256 + threadIdx.x;
    if (idx >= 2045 * 1280) return;
    int t4 = idx / 1280, c = idx % 1280;
    float4 w4 = *(const float4*)&cw[c * 4];
    float acc = cb[c];
    acc += zxf[(size_t)(t4 + 0) * DPROJ + 1024 + c] * w4.x;
    acc += zxf[(size_t)(t4 + 1) * DPROJ + 1024 + c] * w4.y;
    acc += zxf[(size_t)(t4 + 2) * DPROJ + 1024 + c] * w4.z;
    acc += zxf[(size_t)(t4 + 3) * DPROJ + 1024 + c] * w4.w;
    float r = siluf(acc);
    if (c >= 1024) bc16[(size_t)t4 * 256 + (c - 1024)] = f2bf(r);
    else           x16[(size_t)t4 * 1024 + c] = f2bf(r);
}

__global__ void convFpb_kernel(const float* __restrict__ zxf, const float* __restrict__ zxc,
                               const float* __restrict__ cw, const float* __restrict__ cb,
                               float* __restrict__ outp, unsigned short* __restrict__ bc16,
                               unsigned short* __restrict__ x16) {
    int idx = blockIdx.x * 256 + threadIdx.x;   // 8*4*1280
    int b = idx / 5120;
    int r = idx % 5120;
    int t = r / 1280, c = r % 1280;
    float4 w4 = *(const float4*)&cw[c * 4];
    float w[4] = {w4.x, w4.y, w4.z, w4.w};
    float acc = cb[c];
#pragma unroll
    for (int k = 0; k < 4; ++k) {
        int j = t - 3 + k;
        float x = 0.f;
        if (j == 0)      x = zxc[(size_t)b * DPROJ + 1024 + c];
        else if (j >= 1) x = zxf[(size_t)(j - 1) * DPROJ + 1024 + c];
        acc += x * w[k];
    }
    float rr = siluf(acc);
    outp[idx] = rr;   // fp32 kept: x0v, cbm rank-1 path
    if (c >= 1024) bc16[(size_t)(b * 4 + t) * 256 + (c - 1024)] = f2bf(rr);
    else           x16[(size_t)(b * 4 + t) * 1024 + c] = f2bf(rr);
}

__global__ void convBsh_kernel(const float* __restrict__ zxb, const float* __restrict__ cw,
                               const float* __restrict__ cb,
                               unsigned short* __restrict__ bc16, unsigned short* __restrict__ x16) {
    int idx = blockIdx.x * 256 + threadIdx.x;   // 2048*1280
    int s = idx / 1280, c = idx % 1280;
    float4 w4 = *(const float4*)&cw[c * 4];
    float w[4] = {w4.x, w4.y, w4.z, w4.w};
    float acc = cb[c];
#pragma unroll
    for (int k = 0; k < 4; ++k) {
        int j = s - 3 + k;
        if (j >= 0) acc += zxb[(size_t)(2047 - j) * DPROJ + 1024 + c] * w[k];
    }
    float r = siluf(acc);
    if (c >= 1024) bc16[(size_t)s * 256 + (c - 1024)] = f2bf(r);
    else           x16[(size_t)s * 1024 + c] = f2bf(r);
}

// ---------------- intra-chunk kernel (MFMA) ----------------

__global__ __launch_bounds__(256) void intra_kernel(
    const unsigned short* __restrict__ bcF, const unsigned short* __restrict__ bcFp,
    const unsigned short* __restrict__ bcB,
    const unsigned short* __restrict__ xF16, const unsigned short* __restrict__ xFp16,
    const unsigned short* __restrict__ xB16,
    const float* __restrict__ dtFsT, const float* __restrict__ dtBsT,
    const float* __restrict__ cumF, const float* __restrict__ cumB,
    unsigned short* __restrict__ YiF0, unsigned short* __restrict__ YiFs,
    unsigned short* __restrict__ YiB,
    unsigned short* __restrict__ UF0, unsigned short* __restrict__ UFs,
    unsigned short* __restrict__ UB) {
    __shared__ __align__(16) unsigned char smraw[63232];
    unsigned short* Bt = (unsigned short*)smraw;                    // 64 x 136  [s][n]
    unsigned short* Ct = (unsigned short*)(smraw + 17408);          // 64 x 136  [t][n]
    unsigned short* Sm = (unsigned short*)(smraw + 17408);          // 64 x 72   [t][s] (alias Ct)
    unsigned short* BT = (unsigned short*)(smraw + 34816);          // 128 x 72  [n][s]
    unsigned short* XT = (unsigned short*)(smraw + 53248);          // 64 x 72   [p][s]
    float* scum = (float*)(smraw + 62464);                          // 64
    float* sdt  = scum + 64;                                        // 64
    float* se   = scum + 128;                                       // 64

    const int iid = blockIdx.x;
    int dir, b = 0, h, c;
    unsigned short *Yout, *Uout;
    if (iid < 128)      { dir = 0; b = iid >> 4; h = iid & 15; c = 0;
                          Yout = YiF0 + (size_t)(b * 16 + h) * 4096; Uout = UF0 + (size_t)(b * 16 + h) * 8192; }
    else if (iid < 624) { int k = iid - 128; dir = 0; c = 1 + (k >> 4); h = k & 15;
                          Yout = YiFs + (size_t)(c * 16 + h) * 4096; Uout = UFs + (size_t)(c * 16 + h) * 8192; }
    else                { int k = iid - 624; dir = 1; c = k >> 4; h = k & 15;
                          Yout = YiB + (size_t)(c * 16 + h) * 4096;  Uout = UB + (size_t)(c * 16 + h) * 8192; }
    const float* dtAT = dir ? dtBsT : dtFsT;
    const float* cumA = dir ? cumB : cumF;

    const int tid = threadIdx.x;
    const int lane = tid & 63, wave = tid >> 6;
    const int quad = lane >> 4, l15 = lane & 15;

    {
        int r = tid >> 2, q = tid & 3;
        const unsigned short *bsrc, *xsrc;
        if (dir == 0) {
            int t = 64 * c + 1 + r;
            if (t < 4) { bsrc = bcFp + (size_t)(b * 4 + t) * 256; xsrc = xFp16 + (size_t)(b * 4 + t) * 1024; }
            else       { bsrc = bcF + (size_t)(t - 4) * 256;      xsrc = xF16 + (size_t)(t - 4) * 1024; }
        } else {
            int s = 64 * c + r;
            bsrc = bcB + (size_t)s * 256;
            xsrc = xB16 + (size_t)s * 1024;
        }
#pragma unroll
        for (int i = 0; i < 4; ++i) {
            int n0 = q * 32 + i * 8;
            uint4 v = *(const uint4*)&bsrc[n0];
            *(uint4*)&Bt[r * 136 + n0] = v;
            const unsigned short* pv = (const unsigned short*)&v;
#pragma unroll
            for (int jj = 0; jj < 8; ++jj) BT[(n0 + jj) * 72 + r] = pv[jj];
        }
#pragma unroll
        for (int i = 0; i < 4; ++i) {
            int n0 = q * 32 + i * 8;
            uint4 v = *(const uint4*)&bsrc[128 + n0];
            *(uint4*)&Ct[r * 136 + n0] = v;
        }
#pragma unroll
        for (int k = 0; k < 2; ++k) {
            uint4 v = *(const uint4*)&xsrc[h * 64 + q * 16 + k * 8];
            const unsigned short* pv = (const unsigned short*)&v;
#pragma unroll
            for (int jj = 0; jj < 8; ++jj) XT[(q * 16 + k * 8 + jj) * 72 + r] = pv[jj];
        }
        if (tid < 64) {
            int j = 64 * c + tid;
            scum[tid] = cumA[h * 2048 + j];
            sdt[tid] = dtAT[h * 2048 + j];
        }
    }
    __syncthreads();
    if (tid < 64) se[tid] = __expf(scum[63] - scum[tid]) * sdt[tid];

    // phase 1: G = C . B^T
    const int tm = (wave >> 1) * 32, sn = (wave & 1) * 32;
    f32x4 acc1[2][2];
#pragma unroll
    for (int i = 0; i < 2; ++i)
#pragma unroll
        for (int j = 0; j < 2; ++j) acc1[i][j] = (f32x4){0.f, 0.f, 0.f, 0.f};
#pragma unroll
    for (int ks = 0; ks < 4; ++ks) {
        bf16x8 af[2], bfr[2];
#pragma unroll
        for (int i = 0; i < 2; ++i)
            af[i] = *(const bf16x8*)&Ct[(tm + i * 16 + l15) * 136 + ks * 32 + quad * 8];
#pragma unroll
        for (int j = 0; j < 2; ++j)
            bfr[j] = *(const bf16x8*)&Bt[(sn + j * 16 + l15) * 136 + ks * 32 + quad * 8];
#pragma unroll
        for (int i = 0; i < 2; ++i)
#pragma unroll
            for (int j = 0; j < 2; ++j)
                acc1[i][j] = __builtin_amdgcn_mfma_f32_16x16x32_bf16(af[i], bfr[j], acc1[i][j], 0, 0, 0);
    }
    __syncthreads();

#pragma unroll
    for (int j = 0; j < 2; ++j) {
        int s = sn + j * 16 + l15;
        float cs = scum[s], ds = sdt[s];
#pragma unroll
        for (int i = 0; i < 2; ++i) {
#pragma unroll
            for (int r = 0; r < 4; ++r) {
                int t = tm + i * 16 + quad * 4 + r;
                float v = (s <= t) ? __expf(scum[t] - cs) * ds * acc1[i][j][r] : 0.f;
                Sm[t * 72 + s] = f2bf(v);
            }
        }
    }
    __syncthreads();

    // phase 2 (swapped): A = X^T rows p, B = Sm rows t -> D[p][t]
    const int pm = (wave >> 1) * 32, tn = (wave & 1) * 32;
    f32x4 acc2[2][2];
#pragma unroll
    for (int i = 0; i < 2; ++i)
#pragma unroll
        for (int j = 0; j < 2; ++j) acc2[i][j] = (f32x4){0.f, 0.f, 0.f, 0.f};
#pragma unroll
    for (int ks = 0; ks < 2; ++ks) {
        bf16x8 af[2], bfr[2];
#pragma unroll
        for (int i = 0; i < 2; ++i)
            af[i] = *(const bf16x8*)&XT[(pm + i * 16 + l15) * 72 + ks * 32 + quad * 8];
#pragma unroll
        for (int j = 0; j < 2; ++j)
            bfr[j] = *(const bf16x8*)&Sm[(tn + j * 16 + l15) * 72 + ks * 32 + quad * 8];
#pragma unroll
        for (int i = 0; i < 2; ++i)
#pragma unroll
            for (int j = 0; j < 2; ++j)
                acc2[i][j] = __builtin_amdgcn_mfma_f32_16x16x32_bf16(af[i], bfr[j], acc2[i][j], 0, 0, 0);
    }
#pragma unroll
    for (int i = 0; i < 2; ++i)
#pragma unroll
        for (int j = 0; j < 2; ++j) {
            int t = tn + j * 16 + l15;
            int p0 = pm + i * 16 + quad * 4;
            ushort4 o = make_ushort4(f2bf(acc2[i][j][0]), f2bf(acc2[i][j][1]),
                                     f2bf(acc2[i][j][2]), f2bf(acc2[i][j][3]));
            *(ushort4*)&Yout[t * 64 + p0] = o;
        }

    // phase 3: U = B^T . (e*X) -> write U[p][n]
    const int nm = wave * 32;
    f32x4 acc3[2][4];
#pragma unroll
    for (int i = 0; i < 2; ++i)
#pragma unroll
        for (int j = 0; j < 4; ++j) acc3[i][j] = (f32x4){0.f, 0.f, 0.f, 0.f};
#pragma unroll
    for (int ks = 0; ks < 2; ++ks) {
        float ev[8];
#pragma unroll
        for (int jj = 0; jj < 8; ++jj) ev[jj] = se[ks * 32 + quad * 8 + jj];
        bf16x8 bfx[4];
#pragma unroll
        for (int j = 0; j < 4; ++j) {
            bf16x8 xs = *(const bf16x8*)&XT[(j * 16 + l15) * 72 + ks * 32 + quad * 8];
#pragma unroll
            for (int jj = 0; jj < 8; ++jj)
                bfx[j][jj] = (short)f2bf(bfu((unsigned short)xs[jj]) * ev[jj]);
        }
        bf16x8 af[2];
#pragma unroll
        for (int i = 0; i < 2; ++i)
            af[i] = *(const bf16x8*)&BT[(nm + i * 16 + l15) * 72 + ks * 32 + quad * 8];
#pragma unroll
        for (int i = 0; i < 2; ++i)
#pragma unroll
            for (int j = 0; j < 4; ++j)
                acc3[i][j] = __builtin_amdgcn_mfma_f32_16x16x32_bf16(af[i], bfx[j], acc3[i][j], 0, 0, 0);
    }
#pragma unroll
    for (int i = 0; i < 2; ++i)
#pragma unroll
        for (int j = 0; j < 4; ++j) {
            int p = j * 16 + l15;
            int n0 = nm + i * 16 + quad * 4;
            ushort4 o = make_ushort4(f2bf(acc3[i][j][0]), f2bf(acc3[i][j][1]),
                                     f2bf(acc3[i][j][2]), f2bf(acc3[i][j][3]));
            *(ushort4*)&Uout[p * 128 + n0] = o;
        }
}

// ---------------- fused cb0 + M ----------------

__global__ void cbm_kernel(const float* __restrict__ convFp, const unsigned short* __restrict__ bcF,
                           const float* __restrict__ dtFp, const float* __restrict__ cumF,
                           const unsigned short* __restrict__ UF0,
                           float* __restrict__ cb0, unsigned short* __restrict__ Mb) {
    int blk = blockIdx.x, tid = threadIdx.x;   // 160
    if (blk < 32) {
        int idx = blk * 256 + tid;   // 8192
        int b = idx >> 10, r = idx & 1023, h = r >> 6, tl = r & 63;
        int t = tl + 1;
        const float* b0 = convFp + (size_t)(b * 4) * CONVD;
        float s = 0.f;
        if (t < 4) {
            const float* crow = convFp + (size_t)(b * 4 + t) * CONVD;
            for (int n = 0; n < 128; ++n) s += crow[1152 + n] * b0[1024 + n];
        } else {
            const unsigned short* cr = bcF + (size_t)(t - 4) * 256 + 128;
            for (int n = 0; n < 128; ++n) s += bfu(cr[n]) * b0[1024 + n];
        }
        cb0[(b * 16 + h) * 64 + tl] = s * dtFp[b * 16 + h];
    } else {
        int bh = blk - 32;   // 128
        int b = bh >> 4, h = bh & 15;
        float D0 = __expf(cumF[h * 2048 + 63]);
        float dt0 = dtFp[b * 16 + h];
        const float* row0 = convFp + (size_t)(b * 4) * CONVD;
        const unsigned short* u = UF0 + (size_t)(b * 16 + h) * 8192;
        unsigned short* m = Mb + (size_t)(b * 16 + h) * 8192;
        for (int e4 = tid; e4 < 2048; e4 += 256) {
            int e = e4 * 4, p = e >> 7, n0 = e & 127;
            float s = D0 * dt0 * row0[h * 64 + p];
            float4 B4 = *(const float4*)&row0[1024 + n0];
            ushort4 uv = *(const ushort4*)&u[e];
            ushort4 o = make_ushort4(f2bf(s * B4.x + bfu(uv.x)), f2bf(s * B4.y + bfu(uv.y)),
                                     f2bf(s * B4.z + bfu(uv.z)), f2bf(s * B4.w + bfu(uv.w)));
            *(ushort4*)&m[e] = o;
        }
    }
}

// ---------------- shared chunk-state scan: T_c, psi_c (256 blocks, prefetch) ----------------

__global__ void tpsi_kernel(const unsigned short* __restrict__ UFs, const unsigned short* __restrict__ UB,
                            const float* __restrict__ cumF, const float* __restrict__ cumB,
                            unsigned short* __restrict__ Tst, float* __restrict__ psiF) {
    int blk = blockIdx.x;   // 256: dir*128 + h*8 + q8
    int dir = blk >> 7, h = (blk >> 3) & 15, q8 = blk & 7;
    int tid = threadIdx.x;
    const unsigned short* U = dir ? UB : UFs;
    const float* cum = dir ? cumB : cumF;
    unsigned short* T = Tst + (size_t)(dir * 16 + h) * 32 * 8192;
    if (dir == 0 && q8 == 0 && tid == 0) {
        float ps = 1.f;
        for (int c = 1; c < 32; ++c) {
            psiF[h * 32 + c] = ps;
            ps *= __expf(cumF[h * 2048 + c * 64 + 63]);
        }
    }
    const size_t e = (size_t)q8 * 1024 + 4 * tid;
    float4 st = make_float4(0.f, 0.f, 0.f, 0.f);
    const int c0 = dir ? 0 : 1;
    ushort4 u = *(const ushort4*)&U[((size_t)c0 * 16 + h) * 8192 + e];
    for (int c = c0; c < 32; ++c) {
        ushort4 un = make_ushort4(0, 0, 0, 0);
        if (c + 1 < 32) un = *(const ushort4*)&U[((size_t)(c + 1) * 16 + h) * 8192 + e];
        float Dc = __expf(cum[h * 2048 + c * 64 + 63]);
        ushort4 o = make_ushort4(f2bf(st.x), f2bf(st.y), f2bf(st.z), f2bf(st.w));
        *(ushort4*)&T[(size_t)c * 8192 + e] = o;
        st.x = Dc * st.x + bfu(u.x);
        st.y = Dc * st.y + bfu(u.y);
        st.z = Dc * st.z + bfu(u.z);
        st.w = Dc * st.w + bfu(u.w);
        u = un;
    }
}

// ---------------- batch-shared Yt = C . T^T ----------------

__global__ __launch_bounds__(256) void yt_kernel(
    const unsigned short* __restrict__ bcF, const unsigned short* __restrict__ bcB,
    const unsigned short* __restrict__ Tst,
    unsigned short* __restrict__ YtF, unsigned short* __restrict__ YtB) {
    const int iid = blockIdx.x;   // 1008
    int dir, h, c;
    if (iid < 496) { dir = 0; c = 1 + (iid >> 4); h = iid & 15; }
    else           { int k = iid - 496; dir = 1; c = k >> 4; h = k & 15; }
    const unsigned short* Cbase = (dir == 0)
        ? bcF + ((size_t)(64 * c - 3)) * 256 + 128
        : bcB + ((size_t)(64 * c)) * 256 + 128;
    const unsigned short* Tp = Tst + ((size_t)(dir * 16 + h) * 32 + c) * 8192;
    unsigned short* Yt = (dir == 0 ? YtF : YtB) + (size_t)(c * 16 + h) * 4096;
    const int tid = threadIdx.x;
    const int lane = tid & 63, wave = tid >> 6;
    const int quad = lane >> 4, l15 = lane & 15;
    const int pm = (wave >> 1) * 32, tb = (wave & 1) * 32;
    f32x4 acc[2][2];
#pragma unroll
    for (int i = 0; i < 2; ++i)
#pragma unroll
        for (int j = 0; j < 2; ++j) acc[i][j] = (f32x4){0.f, 0.f, 0.f, 0.f};
#pragma unroll
    for (int ks = 0; ks < 4; ++ks) {
        bf16x8 af[2], bfr[2];
#pragma unroll
        for (int i = 0; i < 2; ++i)
            af[i] = *(const bf16x8*)&Tp[(size_t)(pm + i * 16 + l15) * 128 + ks * 32 + quad * 8];
#pragma unroll
        for (int j = 0; j < 2; ++j)
            bfr[j] = *(const bf16x8*)&Cbase[(size_t)(tb + j * 16 + l15) * 256 + ks * 32 + quad * 8];
#pragma unroll
        for (int i = 0; i < 2; ++i)
#pragma unroll
            for (int j = 0; j < 2; ++j)
                acc[i][j] = __builtin_amdgcn_mfma_f32_16x16x32_bf16(af[i], bfr[j], acc[i][j], 0, 0, 0);
    }
#pragma unroll
    for (int i = 0; i < 2; ++i)
#pragma unroll
        for (int j = 0; j < 2; ++j) {
            int t = tb + j * 16 + l15;
            int p0 = pm + i * 16 + quad * 4;
            ushort4 o = make_ushort4(f2bf(acc[i][j][0]), f2bf(acc[i][j][1]),
                                     f2bf(acc[i][j][2]), f2bf(acc[i][j][3]));
            *(ushort4*)&Yt[t * 64 + p0] = o;
        }
}

// ---------------- gate kernel: 4 chunks/block, M fragments cached in regs ----------------

__global__ __launch_bounds__(256) void gate_kernel(
    const unsigned short* __restrict__ bcF,
    const unsigned short* __restrict__ Mb, const float* __restrict__ psiF,
    const unsigned short* __restrict__ YtF, const unsigned short* __restrict__ YtB,
    const unsigned short* __restrict__ xF16, const unsigned short* __restrict__ xFp16,
    const unsigned short* __restrict__ xB16,
    const unsigned short* __restrict__ szF, const unsigned short* __restrict__ szB,
    const float* __restrict__ convFp,
    const float* __restrict__ cumF, const float* __restrict__ cumB,
    const unsigned short* __restrict__ YiF0, const unsigned short* __restrict__ YiFs,
    const unsigned short* __restrict__ YiB,
    const float* __restrict__ cb0,
    const float* __restrict__ fD, const float* __restrict__ bD,
    const float* __restrict__ wf2, const float* __restrict__ wb2,
    float* __restrict__ aF, float* __restrict__ aB) {
    __shared__ __align__(16) float Ysm[64 * 68];

    const int iid = blockIdx.x;   // 1152: fwd 1024 (b,h,cg), bwd 128 (h,cg)
    int dir, b = 0, h, cg;
    if (iid < 1024) { dir = 0; b = iid >> 7; int r = iid & 127; h = r >> 3; cg = r & 7; }
    else            { int k = iid - 1024; dir = 1; h = k >> 3; cg = k & 7; }
    const int tid = threadIdx.x, tx = tid & 15, ty = tid >> 4;
    const int lane = tid & 63, wave = tid >> 6;
    const int quad = lane >> 4, l15 = lane & 15;

    const float Dh = (dir ? bD : fD)[h];
    const float* wvp = dir ? wb2 : wf2;
    float4 wreg = *(const float4*)&wvp[h * 64 + tx * 4];
    const float* cumA = dir ? cumB : cumF;

    const int pm = (wave >> 1) * 32, tb = (wave & 1) * 32;
    bf16x8 mfr[4][2];
    if (dir == 0) {
        const unsigned short* Mp = Mb + (size_t)(b * 16 + h) * 8192;
#pragma unroll
        for (int ks = 0; ks < 4; ++ks)
#pragma unroll
            for (int i = 0; i < 2; ++i)
                mfr[ks][i] = *(const bf16x8*)&Mp[(size_t)(pm + i * 16 + l15) * 128 + ks * 32 + quad * 8];
    }

    for (int cc = 0; cc < 4; ++cc) {
        const int c = cg * 4 + cc;
        const bool fwdG = (dir == 0 && c > 0);
        if (fwdG) {
            if (cc > 0) __syncthreads();   // prior epilogue done reading Ysm
            const unsigned short* Cbase = bcF + ((size_t)(64 * c - 3)) * 256 + 128;
            f32x4 acc[2][2];
#pragma unroll
            for (int i = 0; i < 2; ++i)
#pragma unroll
                for (int j = 0; j < 2; ++j) acc[i][j] = (f32x4){0.f, 0.f, 0.f, 0.f};
#pragma unroll
            for (int ks = 0; ks < 4; ++ks) {
                bf16x8 bfr[2];
#pragma unroll
                for (int j = 0; j < 2; ++j)
                    bfr[j] = *(const bf16x8*)&Cbase[(size_t)(tb + j * 16 + l15) * 256 + ks * 32 + quad * 8];
#pragma unroll
                for (int i = 0; i < 2; ++i)
#pragma unroll
                    for (int j = 0; j < 2; ++j)
                        acc[i][j] = __builtin_amdgcn_mfma_f32_16x16x32_bf16(mfr[ks][i], bfr[j], acc[i][j], 0, 0, 0);
            }
#pragma unroll
            for (int i = 0; i < 2; ++i)
#pragma unroll
                for (int j = 0; j < 2; ++j)
                    *(f32x4*)&Ysm[(tb + j * 16 + l15) * 68 + pm + i * 16 + quad * 4] = acc[i][j];
            __syncthreads();
        }

        const float psi = fwdG ? psiF[h * 32 + c] : 0.f;
        const unsigned short* Ytp = fwdG ? (YtF + (size_t)(c * 16 + h) * 4096)
                                         : (dir ? (YtB + (size_t)(c * 16 + h) * 4096) : nullptr);
        float4 x0v = make_float4(0.f, 0.f, 0.f, 0.f);
        float cbv[4] = {0.f, 0.f, 0.f, 0.f};
        if (dir == 0 && c == 0) {
            x0v = *(const float4*)&convFp[(size_t)(b * 4) * CONVD + h * 64 + tx * 4];
#pragma unroll
            for (int i = 0; i < 4; ++i) cbv[i] = cb0[(b * 16 + h) * 64 + (ty + 16 * i)];
        }

        float rawet[4];
        ushort4 yi4a[4], x4a[4], z4a[4], yt4a[4];
        float4 cm4a[4];
#pragma unroll
        for (int i = 0; i < 4; ++i) {
            int tl = ty + 16 * i;
            int j = 64 * c + tl;
            rawet[i] = cumA[h * 2048 + j];
            const unsigned short *Yi, *xp, *zp;
            if (dir == 0) {
                Yi = (c == 0) ? YiF0 + (size_t)(b * 16 + h) * 4096 : YiFs + (size_t)(c * 16 + h) * 4096;
                if (c == 0) {
                    int t = j + 1;
                    xp = (t < 4) ? xFp16 + (size_t)(b * 4 + t) * 1024 : xF16 + (size_t)(t - 4) * 1024;
                } else {
                    xp = xF16 + (size_t)(64 * c + tl - 3) * 1024;
                }
                zp = szF + (size_t)j * 1024;
            } else {
                Yi = YiB + (size_t)(c * 16 + h) * 4096;
                xp = xB16 + (size_t)j * 1024;
                zp = szB + (size_t)(2047 - j) * 1024;
            }
            yi4a[i] = *(const ushort4*)&Yi[tl * 64 + tx * 4];
            x4a[i] = *(const ushort4*)&xp[h * 64 + tx * 4];
            z4a[i] = *(const ushort4*)&zp[h * 64 + tx * 4];
            yt4a[i] = Ytp ? *(const ushort4*)&Ytp[tl * 64 + tx * 4] : make_ushort4(0, 0, 0, 0);
            cm4a[i] = fwdG ? *(const float4*)&Ysm[tl * 68 + tx * 4] : make_float4(0.f, 0.f, 0.f, 0.f);
        }

#pragma unroll
        for (int i = 0; i < 4; ++i) {
            int j = 64 * c + ty + 16 * i;
            float et = __expf(rawet[i]);
            float yv[4] = {bfu(yi4a[i].x), bfu(yi4a[i].y), bfu(yi4a[i].z), bfu(yi4a[i].w)};
            float xa[4] = {bfu(x4a[i].x), bfu(x4a[i].y), bfu(x4a[i].z), bfu(x4a[i].w)};
            float sza[4] = {h2f(z4a[i].x), h2f(z4a[i].y), h2f(z4a[i].z), h2f(z4a[i].w)};
            float ya[4] = {bfu(yt4a[i].x) + psi * cm4a[i].x, bfu(yt4a[i].y) + psi * cm4a[i].y,
                           bfu(yt4a[i].z) + psi * cm4a[i].z, bfu(yt4a[i].w) + psi * cm4a[i].w};
            float x0a[4] = {x0v.x, x0v.y, x0v.z, x0v.w};
            float wa[4] = {wreg.x, wreg.y, wreg.z, wreg.w};
            float a1 = 0.f, a2 = 0.f;
#pragma unroll
            for (int w = 0; w < 4; ++w) {
                float tot = yv[w] + et * (ya[w] + cbv[i] * x0a[w]) + Dh * xa[w];
                float g = tot * sza[w];
                a1 += g * wa[w];
                a2 += g * g;
            }
#pragma unroll
            for (int m = 1; m < 16; m <<= 1) {
                a1 += __shfl_xor(a1, m);
                a2 += __shfl_xor(a2, m);
            }
            if (tx == 0) {
                if (dir == 0) {
                    size_t o = ((size_t)(b * 2048 + j) * 16 + h) * 2;
                    aF[o] = a1; aF[o + 1] = a2;
                } else {
                    int g = 2047 - j;
                    size_t o = ((size_t)g * 16 + h) * 2;
                    aB[o] = a1; aB[o + 1] = a2;
                }
            }
        }
    }
}

// ---------------- final combine ----------------

__global__ void final_kernel(const float* __restrict__ aF, const float* __restrict__ aB,
                             const float* __restrict__ headB, float* __restrict__ out) {
    int idx = blockIdx.x * 256 + threadIdx.x;   // 16384
    int b = idx >> 11, g = idx & 2047;
    const float* pf = aF + ((size_t)(b * 2048 + g)) * 32;
    const float* pb = aB + (size_t)g * 32;
    float f1 = 0.f, f2 = 0.f, b1 = 0.f, b2 = 0.f;
#pragma unroll
    for (int h = 0; h < 16; ++h) {
        f1 += pf[2 * h]; f2 += pf[2 * h + 1];
        b1 += pb[2 * h]; b2 += pb[2 * h + 1];
    }
    out[idx] = f1 * rsqrtf(f2 * (1.f / 1024.f) + 1e-5f) +
               b1 * rsqrtf(b2 * (1.f / 1024.f) + 1e-5f) + headB[0];
}

// ---------------- launch ----------------

extern "C" void kernel_launch(void* const* d_in, const int* in_sizes, int n_in,
                              void* d_out, int out_size, void* d_ws, size_t ws_size,
                              hipStream_t stream) {
    const int*   pidx   = (const int*)  d_in[0];
    const int*   chridx = (const int*)  d_in[1];
    const float* locusF = (const float*)d_in[2];
    const float* pathF  = (const float*)d_in[3];
    const float* pertE  = (const float*)d_in[4];
    const float* gidE   = (const float*)d_in[5];
    const float* chrE   = (const float*)d_in[6];
    const float* locusW = (const float*)d_in[7];
    const float* locusB = (const float*)d_in[8];
    const float* condW  = (const float*)d_in[9];
    const float* condB  = (const float*)d_in[10];
    const float* inW    = (const float*)d_in[11];
    const float* inB    = (const float*)d_in[12];
    const float* headW  = (const float*)d_in[13];
    const float* headB  = (const float*)d_in[14];
    const float* fInW   = (const float*)d_in[15];
    const float* fCw    = (const float*)d_in[16];
    const float* fCb    = (const float*)d_in[17];
    const float* fDtB   = (const float*)d_in[18];
    const float* fAlog  = (const float*)d_in[19];
    const float* fDp    = (const float*)d_in[20];
    const float* fNw    = (const float*)d_in[21];
    const float* fOutW  = (const float*)d_in[22];
    const float* bInW   = (const float*)d_in[23];
    const float* bCw    = (const float*)d_in[24];
    const float* bCb    = (const float*)d_in[25];
    const float* bDtB   = (const float*)d_in[26];
    const float* bAlog  = (const float*)d_in[27];
    const float* bDp    = (const float*)d_in[28];
    const float* bNw    = (const float*)d_in[29];
    const float* bOutW  = (const float*)d_in[30];
    float* out = (float*)d_out;
    (void)in_sizes; (void)n_in; (void)out_size; (void)ws_size;

    char* base = (char*)d_ws;
    size_t off = 0;
    auto allocf = [&](size_t n) -> float* {
        char* r = base + off; off += ((n * 4 + 63) & ~(size_t)63); return (float*)r; };
    auto allocu = [&](size_t n) -> unsigned short* {
        char* r = base + off; off += ((n * 2 + 63) & ~(size_t)63); return (unsigned short*)r; };

    float* gf     = allocf(2048UL * 384);
    float* cond   = allocf(8UL * 384);
    float* cemb   = allocf(8UL * 128);
    float* uc     = allocf(8UL * 512);
    float* zxf    = allocf(2048UL * DPROJ);
    float* zxb    = allocf(2048UL * DPROJ);
    float* zxc    = allocf(8UL * DPROJ);
    float* convFp = allocf(8UL * 4 * CONVD);
    float* dtFsT  = allocf(16UL * 2048);
    float* dtFp   = allocf(128);
    float* dtBsT  = allocf(16UL * 2048);
    float* cumF   = allocf(16UL * 2048);
    float* cumB   = allocf(16UL * 2048);
    float* wf2    = allocf(1024);
    float* wb2    = allocf(1024);
    float* cb0    = allocf(8UL * 16 * 64);
    float* psiF   = allocf(16UL * 32);
    float* aF     = allocf(8UL * 2048 * 16 * 2);
    float* aB     = allocf(2048UL * 16 * 2);
    unsigned short* YiF0 = allocu(8UL * 16 * 4096);
    unsigned short* YiFs = allocu(32UL * 16 * 4096);
    unsigned short* YiB  = allocu(32UL * 16 * 4096);
    unsigned short* UF0  = allocu(8UL * 16 * 8192);
    unsigned short* UFs  = allocu(32UL * 16 * 8192);
    unsigned short* UB   = allocu(32UL * 16 * 8192);
    unsigned short* Mb   = allocu(8UL * 16 * 8192);
    unsigned short* Tst  = allocu(2UL * 16 * 32 * 8192);
    unsigned short* bcF  = allocu(2045UL * 256);
    unsigned short* bcFp = allocu(32UL * 256);
    unsigned short* bcB  = allocu(2048UL * 256);
    unsigned short* YtF  = allocu(32UL * 16 * 4096);
    unsigned short* YtB  = allocu(32UL * 16 * 4096);
    unsigned short* xF16 = allocu(2045UL * 1024);
    unsigned short* xFp16= allocu(32UL * 1024);
    unsigned short* xB16 = allocu(2048UL * 1024);
    unsigned short* szF  = allocu(2048UL * 1024);
    unsigned short* szB  = allocu(2048UL * 1024);
    unsigned short* gf2   = allocu(2048UL * 384);
    unsigned short* inW2  = allocu(512UL * 384);
    unsigned short* ug2   = allocu(2048UL * 512);
    unsigned short* fInW2 = allocu(2432UL * 512);
    unsigned short* bInW2 = allocu(2432UL * 512);

    gg_kernel<<<3077, 256, 0, stream>>>(chridx, gidE, pathF, chrE, pidx, pertE, gf, cemb, wf2, wb2);
    wfold_kernel<<<128, 256, 0, stream>>>(headW, fOutW, fNw, bOutW, bNw, wf2, wb2);
    gemm_kernel<<<dim3(1, 32), 256, 0, stream>>>(locusF, locusW, locusB, gf + 320, 2048, 64, 64, 384, 1);
    gemm_kernel<<<dim3(6, 1), 256, 0, stream>>>(cemb, condW, condB, cond, 8, 384, 128, 384, 0);

    tobf4_kernel<<<13568, 256, 0, stream>>>(inW, fInW, bInW, gf, inW2, fInW2, bInW2, gf2);

    // ug2 = bf16(gf @ inW^T + inB), written directly by the GEMM epilogue
    mfma_gemm_kernel<<<dim3(4, 16), 256, 0, stream>>>(gf2, inW2, inB, nullptr, ug2, nullptr, 512, 384, 512);
    gemm_kernel<<<dim3(8, 1), 256, 0, stream>>>(cond, inW, inB, uc, 8, 512, 384, 512, 0);

    // zx = ug2 @ W^T; z-region (n<1024) emitted as fp16 silu directly
    mfma_gemm_kernel<<<dim3(19, 16), 256, 0, stream>>>(ug2, fInW2, nullptr, zxf, nullptr, szF, 2320, 512, DPROJ);
    mfma_gemm_kernel<<<dim3(19, 16), 256, 0, stream>>>(ug2, bInW2, nullptr, zxb, nullptr, szB, 2320, 512, DPROJ);
    gemm_kernel<<<dim3(37, 1), 256, 0, stream>>>(uc, fInW, nullptr, zxc, 8, DPROJ, 512, DPROJ, 0);

    dt_kernel<<<257, 256, 0, stream>>>(zxf, zxb, zxc, fDtB, bDtB, dtFsT, dtBsT, dtFp);
    cum_kernel<<<4, 256, 0, stream>>>(dtFsT, dtBsT, fAlog, bAlog, cumF, cumB);
    convFsh_kernel<<<(2045 * 1280 + 255) / 256, 256, 0, stream>>>(zxf, fCw, fCb, bcF, xF16);
    convFpb_kernel<<<160, 256, 0, stream>>>(zxf, zxc, fCw, fCb, convFp, bcFp, xFp16);
    convBsh_kernel<<<10240, 256, 0, stream>>>(zxb, bCw, bCb, bcB, xB16);
    intra_kernel<<<1136, 256, 0, stream>>>(bcF, bcFp, bcB, xF16, xFp16, xB16,
                                           dtFsT, dtBsT, cumF, cumB,
                                           YiF0, YiFs, YiB, UF0, UFs, UB);
    cbm_kernel<<<160, 256, 0, stream>>>(convFp, bcF, dtFp, cumF, UF0, cb0, Mb);
    tpsi_kernel<<<256, 256, 0, stream>>>(UFs, UB, cumF, cumB, Tst, psiF);
    yt_kernel<<<1008, 256, 0, stream>>>(bcF, bcB, Tst, YtF, YtB);
    gate_kernel<<<1152, 256, 0, stream>>>(bcF, Mb, psiF, YtF, YtB, xF16, xFp16, xB16,
                                          szF, szB, convFp, cumF, cumB,
                                          YiF0, YiFs, YiB, cb0, fDp, bDp, wf2, wb2, aF, aB);
    final_kernel<<<64, 256, 0, stream>>>(aF, aB, headB, out);
}

// Round 11
// 389.247 us; speedup vs baseline: 1.2281x; 1.0204x over previous
//
#include <hip/hip_runtime.h>
#include <hip/hip_bf16.h>
#include <hip/hip_fp16.h>
#include <math.h>

#define DPROJ 2320
#define CONVD 1280

typedef __attribute__((ext_vector_type(8))) short bf16x8;
typedef __attribute__((ext_vector_type(4))) float f32x4;

__device__ __forceinline__ float siluf(float x) { return x / (1.f + __expf(-x)); }
__device__ __forceinline__ float bfu(unsigned short s) { return __uint_as_float(((unsigned)s) << 16); }
__device__ __forceinline__ unsigned short f2bf(float f) {
    unsigned u = __float_as_uint(f);
    unsigned r = (u + 0x7FFFu + ((u >> 16) & 1u)) >> 16;
    return (unsigned short)r;
}
__device__ __forceinline__ unsigned short f2h(float f) {
    __half h = __float2half(f);
    return *(unsigned short*)&h;
}
__device__ __forceinline__ float h2f(unsigned short s) {
    __half h = *(__half*)&s;
    return __half2float(h);
}

// ---------------- fused gather + genefeat + wfold-zero ----------------

__global__ void gg_kernel(const int* __restrict__ chridx, const float* __restrict__ gid,
                          const float* __restrict__ path, const float* __restrict__ chrE,
                          const int* __restrict__ pidx, const float* __restrict__ pertE,
                          float* __restrict__ gf, float* __restrict__ cemb,
                          float* __restrict__ wf2, float* __restrict__ wb2) {
    int blk = blockIdx.x, tid = threadIdx.x;
    if (blk < 3072) {
        int idx = blk * 256 + tid;   // 2048*384
        int g = idx / 384, j = idx % 384;
        float v;
        if (j < 128)      v = gid[(size_t)g * 128 + j];
        else if (j < 256) v = path[(size_t)g * 128 + (j - 128)];
        else if (j < 320) v = chrE[(size_t)chridx[g] * 64 + (j - 256)];
        else return;
        gf[idx] = v;
    } else if (blk < 3076) {
        int idx = (blk - 3072) * 256 + tid;   // 1024
        int b = idx >> 7, k = idx & 127;
        cemb[idx] = pertE[(size_t)pidx[b] * 128 + k];
    } else {
        wf2[tid * 4 + 0] = 0.f; wf2[tid * 4 + 1] = 0.f;
        wf2[tid * 4 + 2] = 0.f; wf2[tid * 4 + 3] = 0.f;
        wb2[tid * 4 + 0] = 0.f; wb2[tid * 4 + 1] = 0.f;
        wb2[tid * 4 + 2] = 0.f; wb2[tid * 4 + 3] = 0.f;
    }
}

// wfold: split-m atomic partial sums. 128 blocks = dir(2) x dseg(4) x mseg(16)
__global__ void wfold_kernel(const float* __restrict__ headW,
                             const float* __restrict__ fOutW, const float* __restrict__ fNw,
                             const float* __restrict__ bOutW, const float* __restrict__ bNw,
                             float* __restrict__ wf2, float* __restrict__ wb2) {
    int blk = blockIdx.x;
    int dir = blk >> 6;
    int rem = blk & 63;
    int dseg = rem >> 4, mseg = rem & 15;
    int tid = threadIdx.x;
    int d = dseg * 256 + tid;
    const float* W = dir ? bOutW : fOutW;
    float s = 0.f;
#pragma unroll
    for (int m = mseg * 32; m < mseg * 32 + 32; ++m)
        s += headW[m] * W[(size_t)m * 1024 + d];
    const float* nw = dir ? bNw : fNw;
    atomicAdd(&(dir ? wb2 : wf2)[d], s * nw[d]);
}

// ---------------- fused bf16 conversions (weights + gf) ----------------

__global__ void tobf4_kernel(const float* __restrict__ inW, const float* __restrict__ fInW,
                             const float* __restrict__ bInW, const float* __restrict__ gf,
                             unsigned short* __restrict__ inW2, unsigned short* __restrict__ fInW2,
                             unsigned short* __restrict__ bInW2, unsigned short* __restrict__ gf2) {
    size_t idx = (size_t)blockIdx.x * 256 + threadIdx.x;
    const size_t A = 512UL * 384, B5 = 2432UL * 512;
    if (idx < A) {
        inW2[idx] = f2bf(inW[idx]);
    } else if (idx < A + B5) {
        size_t k = idx - A; int m = k / 512, kk = k % 512;
        fInW2[k] = f2bf(m < 2320 ? fInW[(size_t)m * 512 + kk] : 0.f);
    } else if (idx < A + 2 * B5) {
        size_t k = idx - A - B5; int m = k / 512, kk = k % 512;
        bInW2[k] = f2bf(m < 2320 ? bInW[(size_t)m * 512 + kk] : 0.f);
    } else {
        size_t k = idx - A - 2 * B5;   // 2048*384
        gf2[k] = f2bf(gf[k]);
    }
}

// ---------------- MFMA GEMM with fused scatter epilogue ----------------
// Modes: Cbf != null -> bf16 out (ldc). Otherwise scatter: n<1024 -> sz fp16 silu;
// 1024<=n<2304 -> xbc bf16 [m][1280]; n>=2304 -> dtr fp32 [m][16].

__global__ __launch_bounds__(256) void mfma_gemm_kernel(
    const unsigned short* __restrict__ A2, const unsigned short* __restrict__ W2,
    const float* __restrict__ bias,
    unsigned short* __restrict__ Cbf, unsigned short* __restrict__ sz,
    unsigned short* __restrict__ xbc, float* __restrict__ dtr,
    int N, int K2, int ldc) {
    __shared__ __align__(16) unsigned short Al[128 * 40];
    __shared__ __align__(16) unsigned short Bl[128 * 40];
    const int tid = threadIdx.x;
    const int bm = blockIdx.y * 128, bn = blockIdx.x * 128;
    const int lane = tid & 63, wave = tid >> 6;
    const int wm = (wave >> 1) * 64, wn = (wave & 1) * 64;
    f32x4 acc[4][4];
#pragma unroll
    for (int i = 0; i < 4; ++i)
#pragma unroll
        for (int j = 0; j < 4; ++j) acc[i][j] = (f32x4){0.f, 0.f, 0.f, 0.f};

    for (int k0 = 0; k0 < K2; k0 += 32) {
        __syncthreads();
#pragma unroll
        for (int s = 0; s < 2; ++s) {
            int ch = tid + 256 * s;
            int row = ch >> 2, q = ch & 3;
            uint4 va = *(const uint4*)&A2[(size_t)(bm + row) * K2 + k0 + q * 8];
            *(uint4*)&Al[row * 40 + q * 8] = va;
            uint4 vb = *(const uint4*)&W2[(size_t)(bn + row) * K2 + k0 + q * 8];
            *(uint4*)&Bl[row * 40 + q * 8] = vb;
        }
        __syncthreads();
        bf16x8 af[4], bfr[4];
#pragma unroll
        for (int i = 0; i < 4; ++i)
            af[i] = *(const bf16x8*)&Al[(wm + i * 16 + (lane & 15)) * 40 + (lane >> 4) * 8];
#pragma unroll
        for (int j = 0; j < 4; ++j)
            bfr[j] = *(const bf16x8*)&Bl[(wn + j * 16 + (lane & 15)) * 40 + (lane >> 4) * 8];
#pragma unroll
        for (int i = 0; i < 4; ++i)
#pragma unroll
            for (int j = 0; j < 4; ++j)
                acc[i][j] = __builtin_amdgcn_mfma_f32_16x16x32_bf16(af[i], bfr[j], acc[i][j], 0, 0, 0);
    }
#pragma unroll
    for (int i = 0; i < 4; ++i) {
        int m = bm + wm + i * 16 + (lane >> 4) * 4;
#pragma unroll
        for (int j = 0; j < 4; ++j) {
            int n = bn + wn + j * 16 + (lane & 15);
            if (n < N) {
                float bv = bias ? bias[n] : 0.f;
#pragma unroll
                for (int r = 0; r < 4; ++r) {
                    float v = acc[i][j][r] + bv;
                    if (Cbf) {
                        Cbf[(size_t)(m + r) * ldc + n] = f2bf(v);
                    } else if (n < 1024) {
                        sz[(size_t)(m + r) * 1024 + n] = f2h(siluf(v));
                    } else if (n < 2304) {
                        xbc[(size_t)(m + r) * 1280 + (n - 1024)] = f2bf(v);
                    } else {
                        dtr[(size_t)(m + r) * 16 + (n - 2304)] = v;
                    }
                }
            }
        }
    }
}

// ---------------- generic tiled fp32 GEMM (small shapes only) ----------------

__global__ __launch_bounds__(256) void gemm_kernel(
    const float* __restrict__ A, const float* __restrict__ W,
    const float* __restrict__ bias, float* __restrict__ C,
    int M, int N, int K, int ldc, int act) {
    __shared__ __align__(16) float As[16][68];
    __shared__ __align__(16) float Ws[16][68];
    const int tid = threadIdx.x;
    const int tx = tid & 15, ty = tid >> 4;
    const int bm = blockIdx.y * 64, bn = blockIdx.x * 64;
    const int lr = tid >> 2;
    const int lk = (tid & 3) * 4;
    float acc[4][4];
#pragma unroll
    for (int i = 0; i < 4; ++i)
#pragma unroll
        for (int j = 0; j < 4; ++j) acc[i][j] = 0.f;

    for (int k0 = 0; k0 < K; k0 += 16) {
        const int am = bm + lr;
        const int wn = bn + lr;
        float4 av = make_float4(0.f, 0.f, 0.f, 0.f), wv = make_float4(0.f, 0.f, 0.f, 0.f);
        if (am < M) av = *(const float4*)&A[(size_t)am * K + k0 + lk];
        if (wn < N) wv = *(const float4*)&W[(size_t)wn * K + k0 + lk];
        __syncthreads();
        As[lk + 0][lr] = av.x; As[lk + 1][lr] = av.y; As[lk + 2][lr] = av.z; As[lk + 3][lr] = av.w;
        Ws[lk + 0][lr] = wv.x; Ws[lk + 1][lr] = wv.y; Ws[lk + 2][lr] = wv.z; Ws[lk + 3][lr] = wv.w;
        __syncthreads();
#pragma unroll
        for (int kk = 0; kk < 16; ++kk) {
            float4 a = *(const float4*)&As[kk][ty * 4];
            float4 w = *(const float4*)&Ws[kk][tx * 4];
            float aa[4] = {a.x, a.y, a.z, a.w}, ww[4] = {w.x, w.y, w.z, w.w};
#pragma unroll
            for (int i = 0; i < 4; ++i)
#pragma unroll
                for (int j = 0; j < 4; ++j) acc[i][j] += aa[i] * ww[j];
        }
    }
#pragma unroll
    for (int i = 0; i < 4; ++i) {
        const int m = bm + ty * 4 + i;
        if (m >= M) continue;
#pragma unroll
        for (int j = 0; j < 4; ++j) {
            const int n = bn + tx * 4 + j;
            if (n >= N) continue;
            float v = acc[i][j] + (bias ? bias[n] : 0.f);
            if (act == 1) v = 0.5f * v * (1.f + erff(v * 0.70710678118654752f));
            C[(size_t)m * ldc + n] = v;
        }
    }
}

// ---------------- dt precompute (compact in, transposed out) ----------------

__global__ void dt_kernel(const float* __restrict__ dtrF, const float* __restrict__ dtrB,
                          const float* __restrict__ zxc,
                          const float* __restrict__ fDtB, const float* __restrict__ bDtB,
                          float* __restrict__ dtFsT, float* __restrict__ dtBsT,
                          float* __restrict__ dtFp) {
    int idx = blockIdx.x * 256 + threadIdx.x;   // 65664
    if (idx < 32768) {
        int r = idx >> 4, hh = idx & 15;
        float raw = dtrF[idx] + fDtB[hh];
        dtFsT[hh * 2048 + r] = (raw > 20.f) ? raw : log1pf(expf(raw));
    } else if (idx < 65536) {
        int k = idx - 32768;
        int r = k >> 4, hh = k & 15;
        float raw = dtrB[(size_t)(2047 - r) * 16 + hh] + bDtB[hh];
        dtBsT[hh * 2048 + r] = (raw > 20.f) ? raw : log1pf(expf(raw));
    } else if (idx < 65664) {
        int k = idx - 65536;
        int b = k >> 4, hh = k & 15;
        float raw = zxc[(size_t)b * DPROJ + 2304 + hh] + fDtB[hh];
        dtFp[k] = (raw > 20.f) ? raw : log1pf(expf(raw));
    }
}

// chunk-local inclusive cumsum of ldA = -dt*exp(A_log), transposed input
__global__ void cum_kernel(const float* __restrict__ dtFsT, const float* __restrict__ dtBsT,
                           const float* __restrict__ fAlog, const float* __restrict__ bAlog,
                           float* __restrict__ cumF, float* __restrict__ cumB) {
    int id = blockIdx.x * 256 + threadIdx.x;   // 1024
    int dir = id >> 9, k = id & 511, h = k >> 5, c = k & 31;
    const float* dtT = dir ? dtBsT : dtFsT;
    const float* Al = dir ? bAlog : fAlog;
    float* cum = dir ? cumB : cumF;
    float a = -expf(Al[h]);
    float acc = 0.f;
    for (int s4 = 0; s4 < 16; ++s4) {
        float4 v = *(const float4*)&dtT[h * 2048 + c * 64 + s4 * 4];
        float4 o;
        acc += v.x * a; o.x = acc;
        acc += v.y * a; o.y = acc;
        acc += v.z * a; o.z = acc;
        acc += v.w * a; o.w = acc;
        *(float4*)&cum[h * 2048 + c * 64 + s4 * 4] = o;
    }
}

// ---------------- fused causal depthwise conv (+SiLU), bf16 in/out ----------------
// blocks [0,10225): fwd shared; [10225,20465): bwd shared; [20465,20625): fwd per-batch.

__global__ void conv_kernel(const unsigned short* __restrict__ xbcF,
                            const unsigned short* __restrict__ xbcB,
                            const float* __restrict__ zxc,
                            const float* __restrict__ fCw, const float* __restrict__ fCb,
                            const float* __restrict__ bCw, const float* __restrict__ bCb,
                            unsigned short* __restrict__ bcF, unsigned short* __restrict__ xF16,
                            unsigned short* __restrict__ bcB, unsigned short* __restrict__ xB16,
                            float* __restrict__ convFp, unsigned short* __restrict__ bcFp,
                            unsigned short* __restrict__ xFp16) {
    int blk = blockIdx.x, tid = threadIdx.x;
    if (blk < 10225) {
        int idx = blk * 256 + tid;
        if (idx >= 2045 * 1280) return;
        int t4 = idx / 1280, c = idx % 1280;
        float4 w4 = *(const float4*)&fCw[c * 4];
        float acc = fCb[c];
        acc += bfu(xbcF[(size_t)(t4 + 0) * 1280 + c]) * w4.x;
        acc += bfu(xbcF[(size_t)(t4 + 1) * 1280 + c]) * w4.y;
        acc += bfu(xbcF[(size_t)(t4 + 2) * 1280 + c]) * w4.z;
        acc += bfu(xbcF[(size_t)(t4 + 3) * 1280 + c]) * w4.w;
        float r = siluf(acc);
        if (c >= 1024) bcF[(size_t)t4 * 256 + (c - 1024)] = f2bf(r);
        else           xF16[(size_t)t4 * 1024 + c] = f2bf(r);
    } else if (blk < 20465) {
        int idx = (blk - 10225) * 256 + tid;   // 2048*1280
        int s = idx / 1280, c = idx % 1280;
        float4 w4 = *(const float4*)&bCw[c * 4];
        float w[4] = {w4.x, w4.y, w4.z, w4.w};
        float acc = bCb[c];
#pragma unroll
        for (int k = 0; k < 4; ++k) {
            int j = s - 3 + k;
            if (j >= 0) acc += bfu(xbcB[(size_t)(2047 - j) * 1280 + c]) * w[k];
        }
        float r = siluf(acc);
        if (c >= 1024) bcB[(size_t)s * 256 + (c - 1024)] = f2bf(r);
        else           xB16[(size_t)s * 1024 + c] = f2bf(r);
    } else {
        int idx = (blk - 20465) * 256 + tid;   // 8*4*1280
        int b = idx / 5120;
        int r = idx % 5120;
        int t = r / 1280, c = r % 1280;
        float4 w4 = *(const float4*)&fCw[c * 4];
        float w[4] = {w4.x, w4.y, w4.z, w4.w};
        float acc = fCb[c];
#pragma unroll
        for (int k = 0; k < 4; ++k) {
            int j = t - 3 + k;
            float x = 0.f;
            if (j == 0)      x = zxc[(size_t)b * DPROJ + 1024 + c];
            else if (j >= 1) x = bfu(xbcF[(size_t)(j - 1) * 1280 + c]);
            acc += x * w[k];
        }
        float rr = siluf(acc);
        convFp[idx] = rr;   // fp32 kept: x0v, cbm rank-1 path
        if (c >= 1024) bcFp[(size_t)(b * 4 + t) * 256 + (c - 1024)] = f2bf(rr);
        else           xFp16[(size_t)(b * 4 + t) * 1024 + c] = f2bf(rr);
    }
}

// ---------------- intra-chunk kernel (MFMA) ----------------

__global__ __launch_bounds__(256) void intra_kernel(
    const unsigned short* __restrict__ bcF, const unsigned short* __restrict__ bcFp,
    const unsigned short* __restrict__ bcB,
    const unsigned short* __restrict__ xF16, const unsigned short* __restrict__ xFp16,
    const unsigned short* __restrict__ xB16,
    const float* __restrict__ dtFsT, const float* __restrict__ dtBsT,
    const float* __restrict__ cumF, const float* __restrict__ cumB,
    unsigned short* __restrict__ YiF0, unsigned short* __restrict__ YiFs,
    unsigned short* __restrict__ YiB,
    unsigned short* __restrict__ UF0, unsigned short* __restrict__ UFs,
    unsigned short* __restrict__ UB) {
    __shared__ __align__(16) unsigned char smraw[63232];
    unsigned short* Bt = (unsigned short*)smraw;                    // 64 x 136  [s][n]
    unsigned short* Ct = (unsigned short*)(smraw + 17408);          // 64 x 136  [t][n]
    unsigned short* Sm = (unsigned short*)(smraw + 17408);          // 64 x 72   [t][s] (alias Ct)
    unsigned short* BT = (unsigned short*)(smraw + 34816);          // 128 x 72  [n][s]
    unsigned short* XT = (unsigned short*)(smraw + 53248);          // 64 x 72   [p][s]
    float* scum = (float*)(smraw + 62464);                          // 64
    float* sdt  = scum + 64;                                        // 64
    float* se   = scum + 128;                                       // 64

    const int iid = blockIdx.x;
    int dir, b = 0, h, c;
    unsigned short *Yout, *Uout;
    if (iid < 128)      { dir = 0; b = iid >> 4; h = iid & 15; c = 0;
                          Yout = YiF0 + (size_t)(b * 16 + h) * 4096; Uout = UF0 + (size_t)(b * 16 + h) * 8192; }
    else if (iid < 624) { int k = iid - 128; dir = 0; c = 1 + (k >> 4); h = k & 15;
                          Yout = YiFs + (size_t)(c * 16 + h) * 4096; Uout = UFs + (size_t)(c * 16 + h) * 8192; }
    else                { int k = iid - 624; dir = 1; c = k >> 4; h = k & 15;
                          Yout = YiB + (size_t)(c * 16 + h) * 4096;  Uout = UB + (size_t)(c * 16 + h) * 8192; }
    const float* dtAT = dir ? dtBsT : dtFsT;
    const float* cumA = dir ? cumB : cumF;

    const int tid = threadIdx.x;
    const int lane = tid & 63, wave = tid >> 6;
    const int quad = lane >> 4, l15 = lane & 15;

    {
        int r = tid >> 2, q = tid & 3;
        const unsigned short *bsrc, *xsrc;
        if (dir == 0) {
            int t = 64 * c + 1 + r;
            if (t < 4) { bsrc = bcFp + (size_t)(b * 4 + t) * 256; xsrc = xFp16 + (size_t)(b * 4 + t) * 1024; }
            else       { bsrc = bcF + (size_t)(t - 4) * 256;      xsrc = xF16 + (size_t)(t - 4) * 1024; }
        } else {
            int s = 64 * c + r;
            bsrc = bcB + (size_t)s * 256;
            xsrc = xB16 + (size_t)s * 1024;
        }
#pragma unroll
        for (int i = 0; i < 4; ++i) {
            int n0 = q * 32 + i * 8;
            uint4 v = *(const uint4*)&bsrc[n0];
            *(uint4*)&Bt[r * 136 + n0] = v;
            const unsigned short* pv = (const unsigned short*)&v;
#pragma unroll
            for (int jj = 0; jj < 8; ++jj) BT[(n0 + jj) * 72 + r] = pv[jj];
        }
#pragma unroll
        for (int i = 0; i < 4; ++i) {
            int n0 = q * 32 + i * 8;
            uint4 v = *(const uint4*)&bsrc[128 + n0];
            *(uint4*)&Ct[r * 136 + n0] = v;
        }
#pragma unroll
        for (int k = 0; k < 2; ++k) {
            uint4 v = *(const uint4*)&xsrc[h * 64 + q * 16 + k * 8];
            const unsigned short* pv = (const unsigned short*)&v;
#pragma unroll
            for (int jj = 0; jj < 8; ++jj) XT[(q * 16 + k * 8 + jj) * 72 + r] = pv[jj];
        }
        if (tid < 64) {
            int j = 64 * c + tid;
            scum[tid] = cumA[h * 2048 + j];
            sdt[tid] = dtAT[h * 2048 + j];
        }
    }
    __syncthreads();
    if (tid < 64) se[tid] = __expf(scum[63] - scum[tid]) * sdt[tid];

    // phase 1: G = C . B^T
    const int tm = (wave >> 1) * 32, sn = (wave & 1) * 32;
    f32x4 acc1[2][2];
#pragma unroll
    for (int i = 0; i < 2; ++i)
#pragma unroll
        for (int j = 0; j < 2; ++j) acc1[i][j] = (f32x4){0.f, 0.f, 0.f, 0.f};
#pragma unroll
    for (int ks = 0; ks < 4; ++ks) {
        bf16x8 af[2], bfr[2];
#pragma unroll
        for (int i = 0; i < 2; ++i)
            af[i] = *(const bf16x8*)&Ct[(tm + i * 16 + l15) * 136 + ks * 32 + quad * 8];
#pragma unroll
        for (int j = 0; j < 2; ++j)
            bfr[j] = *(const bf16x8*)&Bt[(sn + j * 16 + l15) * 136 + ks * 32 + quad * 8];
#pragma unroll
        for (int i = 0; i < 2; ++i)
#pragma unroll
            for (int j = 0; j < 2; ++j)
                acc1[i][j] = __builtin_amdgcn_mfma_f32_16x16x32_bf16(af[i], bfr[j], acc1[i][j], 0, 0, 0);
    }
    __syncthreads();

#pragma unroll
    for (int j = 0; j < 2; ++j) {
        int s = sn + j * 16 + l15;
        float cs = scum[s], ds = sdt[s];
#pragma unroll
        for (int i = 0; i < 2; ++i) {
#pragma unroll
            for (int r = 0; r < 4; ++r) {
                int t = tm + i * 16 + quad * 4 + r;
                float v = (s <= t) ? __expf(scum[t] - cs) * ds * acc1[i][j][r] : 0.f;
                Sm[t * 72 + s] = f2bf(v);
            }
        }
    }
    __syncthreads();

    // phase 2 (swapped): A = X^T rows p, B = Sm rows t -> D[p][t]
    const int pm = (wave >> 1) * 32, tn = (wave & 1) * 32;
    f32x4 acc2[2][2];
#pragma unroll
    for (int i = 0; i < 2; ++i)
#pragma unroll
        for (int j = 0; j < 2; ++j) acc2[i][j] = (f32x4){0.f, 0.f, 0.f, 0.f};
#pragma unroll
    for (int ks = 0; ks < 2; ++ks) {
        bf16x8 af[2], bfr[2];
#pragma unroll
        for (int i = 0; i < 2; ++i)
            af[i] = *(const bf16x8*)&XT[(pm + i * 16 + l15) * 72 + ks * 32 + quad * 8];
#pragma unroll
        for (int j = 0; j < 2; ++j)
            bfr[j] = *(const bf16x8*)&Sm[(tn + j * 16 + l15) * 72 + ks * 32 + quad * 8];
#pragma unroll
        for (int i = 0; i < 2; ++i)
#pragma unroll
            for (int j = 0; j < 2; ++j)
                acc2[i][j] = __builtin_amdgcn_mfma_f32_16x16x32_bf16(af[i], bfr[j], acc2[i][j], 0, 0, 0);
    }
#pragma unroll
    for (int i = 0; i < 2; ++i)
#pragma unroll
        for (int j = 0; j < 2; ++j) {
            int t = tn + j * 16 + l15;
            int p0 = pm + i * 16 + quad * 4;
            ushort4 o = make_ushort4(f2bf(acc2[i][j][0]), f2bf(acc2[i][j][1]),
                                     f2bf(acc2[i][j][2]), f2bf(acc2[i][j][3]));
            *(ushort4*)&Yout[t * 64 + p0] = o;
        }

    // phase 3: U = B^T . (e*X) -> write U[p][n]
    const int nm = wave * 32;
    f32x4 acc3[2][4];
#pragma unroll
    for (int i = 0; i < 2; ++i)
#pragma unroll
        for (int j = 0; j < 4; ++j) acc3[i][j] = (f32x4){0.f, 0.f, 0.f, 0.f};
#pragma unroll
    for (int ks = 0; ks < 2; ++ks) {
        float ev[8];
#pragma unroll
        for (int jj = 0; jj < 8; ++jj) ev[jj] = se[ks * 32 + quad * 8 + jj];
        bf16x8 bfx[4];
#pragma unroll
        for (int j = 0; j < 4; ++j) {
            bf16x8 xs = *(const bf16x8*)&XT[(j * 16 + l15) * 72 + ks * 32 + quad * 8];
#pragma unroll
            for (int jj = 0; jj < 8; ++jj)
                bfx[j][jj] = (short)f2bf(bfu((unsigned short)xs[jj]) * ev[jj]);
        }
        bf16x8 af[2];
#pragma unroll
        for (int i = 0; i < 2; ++i)
            af[i] = *(const bf16x8*)&BT[(nm + i * 16 + l15) * 72 + ks * 32 + quad * 8];
#pragma unroll
        for (int i = 0; i < 2; ++i)
#pragma unroll
            for (int j = 0; j < 4; ++j)
                acc3[i][j] = __builtin_amdgcn_mfma_f32_16x16x32_bf16(af[i], bfx[j], acc3[i][j], 0, 0, 0);
    }
#pragma unroll
    for (int i = 0; i < 2; ++i)
#pragma unroll
        for (int j = 0; j < 4; ++j) {
            int p = j * 16 + l15;
            int n0 = nm + i * 16 + quad * 4;
            ushort4 o = make_ushort4(f2bf(acc3[i][j][0]), f2bf(acc3[i][j][1]),
                                     f2bf(acc3[i][j][2]), f2bf(acc3[i][j][3]));
            *(ushort4*)&Uout[p * 128 + n0] = o;
        }
}

// ---------------- fused cb0 + M ----------------

__global__ void cbm_kernel(const float* __restrict__ convFp, const unsigned short* __restrict__ bcF,
                           const float* __restrict__ dtFp, const float* __restrict__ cumF,
                           const unsigned short* __restrict__ UF0,
                           float* __restrict__ cb0, unsigned short* __restrict__ Mb) {
    int blk = blockIdx.x, tid = threadIdx.x;   // 160
    if (blk < 32) {
        int idx = blk * 256 + tid;   // 8192
        int b = idx >> 10, r = idx & 1023, h = r >> 6, tl = r & 63;
        int t = tl + 1;
        const float* b0 = convFp + (size_t)(b * 4) * CONVD;
        float s = 0.f;
        if (t < 4) {
            const float* crow = convFp + (size_t)(b * 4 + t) * CONVD;
            for (int n = 0; n < 128; ++n) s += crow[1152 + n] * b0[1024 + n];
        } else {
            const unsigned short* cr = bcF + (size_t)(t - 4) * 256 + 128;
            for (int n = 0; n < 128; ++n) s += bfu(cr[n]) * b0[1024 + n];
        }
        cb0[(b * 16 + h) * 64 + tl] = s * dtFp[b * 16 + h];
    } else {
        int bh = blk - 32;   // 128
        int b = bh >> 4, h = bh & 15;
        float D0 = __expf(cumF[h * 2048 + 63]);
        float dt0 = dtFp[b * 16 + h];
        const float* row0 = convFp + (size_t)(b * 4) * CONVD;
        const unsigned short* u = UF0 + (size_t)(b * 16 + h) * 8192;
        unsigned short* m = Mb + (size_t)(b * 16 + h) * 8192;
        for (int e4 = tid; e4 < 2048; e4 += 256) {
            int e = e4 * 4, p = e >> 7, n0 = e & 127;
            float s = D0 * dt0 * row0[h * 64 + p];
            float4 B4 = *(const float4*)&row0[1024 + n0];
            ushort4 uv = *(const ushort4*)&u[e];
            ushort4 o = make_ushort4(f2bf(s * B4.x + bfu(uv.x)), f2bf(s * B4.y + bfu(uv.y)),
                                     f2bf(s * B4.z + bfu(uv.z)), f2bf(s * B4.w + bfu(uv.w)));
            *(ushort4*)&m[e] = o;
        }
    }
}

// ---------------- shared chunk-state scan: T_c, psi_c (256 blocks, prefetch) ----------------

__global__ void tpsi_kernel(const unsigned short* __restrict__ UFs, const unsigned short* __restrict__ UB,
                            const float* __restrict__ cumF, const float* __restrict__ cumB,
                            unsigned short* __restrict__ Tst, float* __restrict__ psiF) {
    int blk = blockIdx.x;   // 256: dir*128 + h*8 + q8
    int dir = blk >> 7, h = (blk >> 3) & 15, q8 = blk & 7;
    int tid = threadIdx.x;
    const unsigned short* U = dir ? UB : UFs;
    const float* cum = dir ? cumB : cumF;
    unsigned short* T = Tst + (size_t)(dir * 16 + h) * 32 * 8192;
    if (dir == 0 && q8 == 0 && tid == 0) {
        float ps = 1.f;
        for (int c = 1; c < 32; ++c) {
            psiF[h * 32 + c] = ps;
            ps *= __expf(cumF[h * 2048 + c * 64 + 63]);
        }
    }
    const size_t e = (size_t)q8 * 1024 + 4 * tid;
    float4 st = make_float4(0.f, 0.f, 0.f, 0.f);
    const int c0 = dir ? 0 : 1;
    ushort4 u = *(const ushort4*)&U[((size_t)c0 * 16 + h) * 8192 + e];
    for (int c = c0; c < 32; ++c) {
        ushort4 un = make_ushort4(0, 0, 0, 0);
        if (c + 1 < 32) un = *(const ushort4*)&U[((size_t)(c + 1) * 16 + h) * 8192 + e];
        float Dc = __expf(cum[h * 2048 + c * 64 + 63]);
        ushort4 o = make_ushort4(f2bf(st.x), f2bf(st.y), f2bf(st.z), f2bf(st.w));
        *(ushort4*)&T[(size_t)c * 8192 + e] = o;
        st.x = Dc * st.x + bfu(u.x);
        st.y = Dc * st.y + bfu(u.y);
        st.z = Dc * st.z + bfu(u.z);
        st.w = Dc * st.w + bfu(u.w);
        u = un;
    }
}

// ---------------- batch-shared Yt = C . T^T ----------------

__global__ __launch_bounds__(256) void yt_kernel(
    const unsigned short* __restrict__ bcF, const unsigned short* __restrict__ bcB,
    const unsigned short* __restrict__ Tst,
    unsigned short* __restrict__ YtF, unsigned short* __restrict__ YtB) {
    const int iid = blockIdx.x;   // 1008
    int dir, h, c;
    if (iid < 496) { dir = 0; c = 1 + (iid >> 4); h = iid & 15; }
    else           { int k = iid - 496; dir = 1; c = k >> 4; h = k & 15; }
    const unsigned short* Cbase = (dir == 0)
        ? bcF + ((size_t)(64 * c - 3)) * 256 + 128
        : bcB + ((size_t)(64 * c)) * 256 + 128;
    const unsigned short* Tp = Tst + ((size_t)(dir * 16 + h) * 32 + c) * 8192;
    unsigned short* Yt = (dir == 0 ? YtF : YtB) + (size_t)(c * 16 + h) * 4096;
    const int tid = threadIdx.x;
    const int lane = tid & 63, wave = tid >> 6;
    const int quad = lane >> 4, l15 = lane & 15;
    const int pm = (wave >> 1) * 32, tb = (wave & 1) * 32;
    f32x4 acc[2][2];
#pragma unroll
    for (int i = 0; i < 2; ++i)
#pragma unroll
        for (int j = 0; j < 2; ++j) acc[i][j] = (f32x4){0.f, 0.f, 0.f, 0.f};
#pragma unroll
    for (int ks = 0; ks < 4; ++ks) {
        bf16x8 af[2], bfr[2];
#pragma unroll
        for (int i = 0; i < 2; ++i)
            af[i] = *(const bf16x8*)&Tp[(size_t)(pm + i * 16 + l15) * 128 + ks * 32 + quad * 8];
#pragma unroll
        for (int j = 0; j < 2; ++j)
            bfr[j] = *(const bf16x8*)&Cbase[(size_t)(tb + j * 16 + l15) * 256 + ks * 32 + quad * 8];
#pragma unroll
        for (int i = 0; i < 2; ++i)
#pragma unroll
            for (int j = 0; j < 2; ++j)
                acc[i][j] = __builtin_amdgcn_mfma_f32_16x16x32_bf16(af[i], bfr[j], acc[i][j], 0, 0, 0);
    }
#pragma unroll
    for (int i = 0; i < 2; ++i)
#pragma unroll
        for (int j = 0; j < 2; ++j) {
            int t = tb + j * 16 + l15;
            int p0 = pm + i * 16 + quad * 4;
            ushort4 o = make_ushort4(f2bf(acc[i][j][0]), f2bf(acc[i][j][1]),
                                     f2bf(acc[i][j][2]), f2bf(acc[i][j][3]));
            *(ushort4*)&Yt[t * 64 + p0] = o;
        }
}

// ---------------- gate kernel: 4 chunks/block, M fragments cached in regs ----------------

__global__ __launch_bounds__(256) void gate_kernel(
    const unsigned short* __restrict__ bcF,
    const unsigned short* __restrict__ Mb, const float* __restrict__ psiF,
    const unsigned short* __restrict__ YtF, const unsigned short* __restrict__ YtB,
    const unsigned short* __restrict__ xF16, const unsigned short* __restrict__ xFp16,
    const unsigned short* __restrict__ xB16,
    const unsigned short* __restrict__ szF, const unsigned short* __restrict__ szB,
    const float* __restrict__ convFp,
    const float* __restrict__ cumF, const float* __restrict__ cumB,
    const unsigned short* __restrict__ YiF0, const unsigned short* __restrict__ YiFs,
    const unsigned short* __restrict__ YiB,
    const float* __restrict__ cb0,
    const float* __restrict__ fD, const float* __restrict__ bD,
    const float* __restrict__ wf2, const float* __restrict__ wb2,
    float* __restrict__ aF, float* __restrict__ aB) {
    __shared__ __align__(16) float Ysm[64 * 68];

    const int iid = blockIdx.x;   // 1152: fwd 1024 (b,h,cg), bwd 128 (h,cg)
    int dir, b = 0, h, cg;
    if (iid < 1024) { dir = 0; b = iid >> 7; int r = iid & 127; h = r >> 3; cg = r & 7; }
    else            { int k = iid - 1024; dir = 1; h = k >> 3; cg = k & 7; }
    const int tid = threadIdx.x, tx = tid & 15, ty = tid >> 4;
    const int lane = tid & 63, wave = tid >> 6;
    const int quad = lane >> 4, l15 = lane & 15;

    const float Dh = (dir ? bD : fD)[h];
    const float* wvp = dir ? wb2 : wf2;
    float4 wreg = *(const float4*)&wvp[h * 64 + tx * 4];
    const float* cumA = dir ? cumB : cumF;

    const int pm = (wave >> 1) * 32, tb = (wave & 1) * 32;
    bf16x8 mfr[4][2];
    if (dir == 0) {
        const unsigned short* Mp = Mb + (size_t)(b * 16 + h) * 8192;
#pragma unroll
        for (int ks = 0; ks < 4; ++ks)
#pragma unroll
            for (int i = 0; i < 2; ++i)
                mfr[ks][i] = *(const bf16x8*)&Mp[(size_t)(pm + i * 16 + l15) * 128 + ks * 32 + quad * 8];
    }

    for (int cc = 0; cc < 4; ++cc) {
        const int c = cg * 4 + cc;
        const bool fwdG = (dir == 0 && c > 0);
        if (fwdG) {
            if (cc > 0) __syncthreads();   // prior epilogue done reading Ysm
            const unsigned short* Cbase = bcF + ((size_t)(64 * c - 3)) * 256 + 128;
            f32x4 acc[2][2];
#pragma unroll
            for (int i = 0; i < 2; ++i)
#pragma unroll
                for (int j = 0; j < 2; ++j) acc[i][j] = (f32x4){0.f, 0.f, 0.f, 0.f};
#pragma unroll
            for (int ks = 0; ks < 4; ++ks) {
                bf16x8 bfr[2];
#pragma unroll
                for (int j = 0; j < 2; ++j)
                    bfr[j] = *(const bf16x8*)&Cbase[(size_t)(tb + j * 16 + l15) * 256 + ks * 32 + quad * 8];
#pragma unroll
                for (int i = 0; i < 2; ++i)
#pragma unroll
                    for (int j = 0; j < 2; ++j)
                        acc[i][j] = __builtin_amdgcn_mfma_f32_16x16x32_bf16(mfr[ks][i], bfr[j], acc[i][j], 0, 0, 0);
            }
#pragma unroll
            for (int i = 0; i < 2; ++i)
#pragma unroll
                for (int j = 0; j < 2; ++j)
                    *(f32x4*)&Ysm[(tb + j * 16 + l15) * 68 + pm + i * 16 + quad * 4] = acc[i][j];
            __syncthreads();
        }

        const float psi = fwdG ? psiF[h * 32 + c] : 0.f;
        const unsigned short* Ytp = fwdG ? (YtF + (size_t)(c * 16 + h) * 4096)
                                         : (dir ? (YtB + (size_t)(c * 16 + h) * 4096) : nullptr);
        float4 x0v = make_float4(0.f, 0.f, 0.f, 0.f);
        float cbv[4] = {0.f, 0.f, 0.f, 0.f};
        if (dir == 0 && c == 0) {
            x0v = *(const float4*)&convFp[(size_t)(b * 4) * CONVD + h * 64 + tx * 4];
#pragma unroll
            for (int i = 0; i < 4; ++i) cbv[i] = cb0[(b * 16 + h) * 64 + (ty + 16 * i)];
        }

        float rawet[4];
        ushort4 yi4a[4], x4a[4], z4a[4], yt4a[4];
        float4 cm4a[4];
#pragma unroll
        for (int i = 0; i < 4; ++i) {
            int tl = ty + 16 * i;
            int j = 64 * c + tl;
            rawet[i] = cumA[h * 2048 + j];
            const unsigned short *Yi, *xp, *zp;
            if (dir == 0) {
                Yi = (c == 0) ? YiF0 + (size_t)(b * 16 + h) * 4096 : YiFs + (size_t)(c * 16 + h) * 4096;
                if (c == 0) {
                    int t = j + 1;
                    xp = (t < 4) ? xFp16 + (size_t)(b * 4 + t) * 1024 : xF16 + (size_t)(t - 4) * 1024;
                } else {
                    xp = xF16 + (size_t)(64 * c + tl - 3) * 1024;
                }
                zp = szF + (size_t)j * 1024;
            } else {
                Yi = YiB + (size_t)(c * 16 + h) * 4096;
                xp = xB16 + (size_t)j * 1024;
                zp = szB + (size_t)(2047 - j) * 1024;
            }
            yi4a[i] = *(const ushort4*)&Yi[tl * 64 + tx * 4];
            x4a[i] = *(const ushort4*)&xp[h * 64 + tx * 4];
            z4a[i] = *(const ushort4*)&zp[h * 64 + tx * 4];
            yt4a[i] = Ytp ? *(const ushort4*)&Ytp[tl * 64 + tx * 4] : make_ushort4(0, 0, 0, 0);
            cm4a[i] = fwdG ? *(const float4*)&Ysm[tl * 68 + tx * 4] : make_float4(0.f, 0.f, 0.f, 0.f);
        }

#pragma unroll
        for (int i = 0; i < 4; ++i) {
            int j = 64 * c + ty + 16 * i;
            float et = __expf(rawet[i]);
            float yv[4] = {bfu(yi4a[i].x), bfu(yi4a[i].y), bfu(yi4a[i].z), bfu(yi4a[i].w)};
            float xa[4] = {bfu(x4a[i].x), bfu(x4a[i].y), bfu(x4a[i].z), bfu(x4a[i].w)};
            float sza[4] = {h2f(z4a[i].x), h2f(z4a[i].y), h2f(z4a[i].z), h2f(z4a[i].w)};
            float ya[4] = {bfu(yt4a[i].x) + psi * cm4a[i].x, bfu(yt4a[i].y) + psi * cm4a[i].y,
                           bfu(yt4a[i].z) + psi * cm4a[i].z, bfu(yt4a[i].w) + psi * cm4a[i].w};
            float x0a[4] = {x0v.x, x0v.y, x0v.z, x0v.w};
            float wa[4] = {wreg.x, wreg.y, wreg.z, wreg.w};
            float a1 = 0.f, a2 = 0.f;
#pragma unroll
            for (int w = 0; w < 4; ++w) {
                float tot = yv[w] + et * (ya[w] + cbv[i] * x0a[w]) + Dh * xa[w];
                float g = tot * sza[w];
                a1 += g * wa[w];
                a2 += g * g;
            }
#pragma unroll
            for (int m = 1; m < 16; m <<= 1) {
                a1 += __shfl_xor(a1, m);
                a2 += __shfl_xor(a2, m);
            }
            if (tx == 0) {
                if (dir == 0) {
                    size_t o = ((size_t)(b * 2048 + j) * 16 + h) * 2;
                    aF[o] = a1; aF[o + 1] = a2;
                } else {
                    int g = 2047 - j;
                    size_t o = ((size_t)g * 16 + h) * 2;
                    aB[o] = a1; aB[o + 1] = a2;
                }
            }
        }
    }
}

// ---------------- final combine ----------------

__global__ void final_kernel(const float* __restrict__ aF, const float* __restrict__ aB,
                             const float* __restrict__ headB, float* __restrict__ out) {
    int idx = blockIdx.x * 256 + threadIdx.x;   // 16384
    int b = idx >> 11, g = idx & 2047;
    const float* pf = aF + ((size_t)(b * 2048 + g)) * 32;
    const float* pb = aB + (size_t)g * 32;
    float f1 = 0.f, f2 = 0.f, b1 = 0.f, b2 = 0.f;
#pragma unroll
    for (int h = 0; h < 16; ++h) {
        f1 += pf[2 * h]; f2 += pf[2 * h + 1];
        b1 += pb[2 * h]; b2 += pb[2 * h + 1];
    }
    out[idx] = f1 * rsqrtf(f2 * (1.f / 1024.f) + 1e-5f) +
               b1 * rsqrtf(b2 * (1.f / 1024.f) + 1e-5f) + headB[0];
}

// ---------------- launch ----------------

extern "C" void kernel_launch(void* const* d_in, const int* in_sizes, int n_in,
                              void* d_out, int out_size, void* d_ws, size_t ws_size,
                              hipStream_t stream) {
    const int*   pidx   = (const int*)  d_in[0];
    const int*   chridx = (const int*)  d_in[1];
    const float* locusF = (const float*)d_in[2];
    const float* pathF  = (const float*)d_in[3];
    const float* pertE  = (const float*)d_in[4];
    const float* gidE   = (const float*)d_in[5];
    const float* chrE   = (const float*)d_in[6];
    const float* locusW = (const float*)d_in[7];
    const float* locusB = (const float*)d_in[8];
    const float* condW  = (const float*)d_in[9];
    const float* condB  = (const float*)d_in[10];
    const float* inW    = (const float*)d_in[11];
    const float* inB    = (const float*)d_in[12];
    const float* headW  = (const float*)d_in[13];
    const float* headB  = (const float*)d_in[14];
    const float* fInW   = (const float*)d_in[15];
    const float* fCw    = (const float*)d_in[16];
    const float* fCb    = (const float*)d_in[17];
    const float* fDtB   = (const float*)d_in[18];
    const float* fAlog  = (const float*)d_in[19];
    const float* fDp    = (const float*)d_in[20];
    const float* fNw    = (const float*)d_in[21];
    const float* fOutW  = (const float*)d_in[22];
    const float* bInW   = (const float*)d_in[23];
    const float* bCw    = (const float*)d_in[24];
    const float* bCb    = (const float*)d_in[25];
    const float* bDtB   = (const float*)d_in[26];
    const float* bAlog  = (const float*)d_in[27];
    const float* bDp    = (const float*)d_in[28];
    const float* bNw    = (const float*)d_in[29];
    const float* bOutW  = (const float*)d_in[30];
    float* out = (float*)d_out;
    (void)in_sizes; (void)n_in; (void)out_size; (void)ws_size;

    char* base = (char*)d_ws;
    size_t off = 0;
    auto allocf = [&](size_t n) -> float* {
        char* r = base + off; off += ((n * 4 + 63) & ~(size_t)63); return (float*)r; };
    auto allocu = [&](size_t n) -> unsigned short* {
        char* r = base + off; off += ((n * 2 + 63) & ~(size_t)63); return (unsigned short*)r; };

    float* gf     = allocf(2048UL * 384);
    float* cond   = allocf(8UL * 384);
    float* cemb   = allocf(8UL * 128);
    float* uc     = allocf(8UL * 512);
    float* zxc    = allocf(8UL * DPROJ);
    float* convFp = allocf(8UL * 4 * CONVD);
    float* dtrF   = allocf(2048UL * 16);
    float* dtrB   = allocf(2048UL * 16);
    float* dtFsT  = allocf(16UL * 2048);
    float* dtFp   = allocf(128);
    float* dtBsT  = allocf(16UL * 2048);
    float* cumF   = allocf(16UL * 2048);
    float* cumB   = allocf(16UL * 2048);
    float* wf2    = allocf(1024);
    float* wb2    = allocf(1024);
    float* cb0    = allocf(8UL * 16 * 64);
    float* psiF   = allocf(16UL * 32);
    float* aF     = allocf(8UL * 2048 * 16 * 2);
    float* aB     = allocf(2048UL * 16 * 2);
    unsigned short* xbcF = allocu(2048UL * 1280);
    unsigned short* xbcB = allocu(2048UL * 1280);
    unsigned short* YiF0 = allocu(8UL * 16 * 4096);
    unsigned short* YiFs = allocu(32UL * 16 * 4096);
    unsigned short* YiB  = allocu(32UL * 16 * 4096);
    unsigned short* UF0  = allocu(8UL * 16 * 8192);
    unsigned short* UFs  = allocu(32UL * 16 * 8192);
    unsigned short* UB   = allocu(32UL * 16 * 8192);
    unsigned short* Mb   = allocu(8UL * 16 * 8192);
    unsigned short* Tst  = allocu(2UL * 16 * 32 * 8192);
    unsigned short* bcF  = allocu(2045UL * 256);
    unsigned short* bcFp = allocu(32UL * 256);
    unsigned short* bcB  = allocu(2048UL * 256);
    unsigned short* YtF  = allocu(32UL * 16 * 4096);
    unsigned short* YtB  = allocu(32UL * 16 * 4096);
    unsigned short* xF16 = allocu(2045UL * 1024);
    unsigned short* xFp16= allocu(32UL * 1024);
    unsigned short* xB16 = allocu(2048UL * 1024);
    unsigned short* szF  = allocu(2048UL * 1024);
    unsigned short* szB  = allocu(2048UL * 1024);
    unsigned short* gf2   = allocu(2048UL * 384);
    unsigned short* inW2  = allocu(512UL * 384);
    unsigned short* ug2   = allocu(2048UL * 512);
    unsigned short* fInW2 = allocu(2432UL * 512);
    unsigned short* bInW2 = allocu(2432UL * 512);

    gg_kernel<<<3077, 256, 0, stream>>>(chridx, gidE, pathF, chrE, pidx, pertE, gf, cemb, wf2, wb2);
    wfold_kernel<<<128, 256, 0, stream>>>(headW, fOutW, fNw, bOutW, bNw, wf2, wb2);
    gemm_kernel<<<dim3(1, 32), 256, 0, stream>>>(locusF, locusW, locusB, gf + 320, 2048, 64, 64, 384, 1);
    gemm_kernel<<<dim3(6, 1), 256, 0, stream>>>(cemb, condW, condB, cond, 8, 384, 128, 384, 0);

    tobf4_kernel<<<13568, 256, 0, stream>>>(inW, fInW, bInW, gf, inW2, fInW2, bInW2, gf2);

    // ug2 = bf16(gf @ inW^T + inB)
    mfma_gemm_kernel<<<dim3(4, 16), 256, 0, stream>>>(gf2, inW2, inB, ug2, nullptr, nullptr, nullptr, 512, 384, 512);
    gemm_kernel<<<dim3(8, 1), 256, 0, stream>>>(cond, inW, inB, uc, 8, 512, 384, 512, 0);

    // zx = ug2 @ W^T with scatter epilogue: z->fp16 silu, xBC->bf16, dt->compact fp32
    mfma_gemm_kernel<<<dim3(19, 16), 256, 0, stream>>>(ug2, fInW2, nullptr, nullptr, szF, xbcF, dtrF, 2320, 512, 0);
    mfma_gemm_kernel<<<dim3(19, 16), 256, 0, stream>>>(ug2, bInW2, nullptr, nullptr, szB, xbcB, dtrB, 2320, 512, 0);
    gemm_kernel<<<dim3(37, 1), 256, 0, stream>>>(uc, fInW, nullptr, zxc, 8, DPROJ, 512, DPROJ, 0);

    dt_kernel<<<257, 256, 0, stream>>>(dtrF, dtrB, zxc, fDtB, bDtB, dtFsT, dtBsT, dtFp);
    cum_kernel<<<4, 256, 0, stream>>>(dtFsT, dtBsT, fAlog, bAlog, cumF, cumB);
    conv_kernel<<<20625, 256, 0, stream>>>(xbcF, xbcB, zxc, fCw, fCb, bCw, bCb,
                                           bcF, xF16, bcB, xB16, convFp, bcFp, xFp16);
    intra_kernel<<<1136, 256, 0, stream>>>(bcF, bcFp, bcB, xF16, xFp16, xB16,
                                           dtFsT, dtBsT, cumF, cumB,
                                           YiF0, YiFs, YiB, UF0, UFs, UB);
    cbm_kernel<<<160, 256, 0, stream>>>(convFp, bcF, dtFp, cumF, UF0, cb0, Mb);
    tpsi_kernel<<<256, 256, 0, stream>>>(UFs, UB, cumF, cumB, Tst, psiF);
    yt_kernel<<<1008, 256, 0, stream>>>(bcF, bcB, Tst, YtF, YtB);
    gate_kernel<<<1152, 256, 0, stream>>>(bcF, Mb, psiF, YtF, YtB, xF16, xFp16, xB16,
                                          szF, szB, convFp, cumF, cumB,
                                          YiF0, YiFs, YiB, cb0, fDp, bDp, wf2, wb2, aF, aB);
    final_kernel<<<64, 256, 0, stream>>>(aF, aB, headB, out);
}

// Round 12
// 372.941 us; speedup vs baseline: 1.2818x; 1.0437x over previous
//
#include <hip/hip_runtime.h>
#include <hip/hip_bf16.h>
#include <hip/hip_fp16.h>
#include <math.h>

#define DPROJ 2320
#define CONVD 1280

typedef __attribute__((ext_vector_type(8))) short bf16x8;
typedef __attribute__((ext_vector_type(4))) float f32x4;

__device__ __forceinline__ float siluf(float x) { return x / (1.f + __expf(-x)); }
__device__ __forceinline__ float bfu(unsigned short s) { return __uint_as_float(((unsigned)s) << 16); }
__device__ __forceinline__ unsigned short f2bf(float f) {
    unsigned u = __float_as_uint(f);
    unsigned r = (u + 0x7FFFu + ((u >> 16) & 1u)) >> 16;
    return (unsigned short)r;
}
__device__ __forceinline__ unsigned short f2h(float f) {
    __half h = __float2half(f);
    return *(unsigned short*)&h;
}
__device__ __forceinline__ float h2f(unsigned short s) {
    __half h = *(__half*)&s;
    return __half2float(h);
}

// ---------------- fused gather + genefeat + wfold-zero ----------------

__global__ void gg_kernel(const int* __restrict__ chridx, const float* __restrict__ gid,
                          const float* __restrict__ path, const float* __restrict__ chrE,
                          const int* __restrict__ pidx, const float* __restrict__ pertE,
                          float* __restrict__ gf, float* __restrict__ cemb,
                          float* __restrict__ wf2, float* __restrict__ wb2) {
    int blk = blockIdx.x, tid = threadIdx.x;
    if (blk < 3072) {
        int idx = blk * 256 + tid;   // 2048*384
        int g = idx / 384, j = idx % 384;
        float v;
        if (j < 128)      v = gid[(size_t)g * 128 + j];
        else if (j < 256) v = path[(size_t)g * 128 + (j - 128)];
        else if (j < 320) v = chrE[(size_t)chridx[g] * 64 + (j - 256)];
        else return;
        gf[idx] = v;
    } else if (blk < 3076) {
        int idx = (blk - 3072) * 256 + tid;   // 1024
        int b = idx >> 7, k = idx & 127;
        cemb[idx] = pertE[(size_t)pidx[b] * 128 + k];
    } else {
        wf2[tid * 4 + 0] = 0.f; wf2[tid * 4 + 1] = 0.f;
        wf2[tid * 4 + 2] = 0.f; wf2[tid * 4 + 3] = 0.f;
        wb2[tid * 4 + 0] = 0.f; wb2[tid * 4 + 1] = 0.f;
        wb2[tid * 4 + 2] = 0.f; wb2[tid * 4 + 3] = 0.f;
    }
}

// wfold: split-m atomic partial sums. 128 blocks = dir(2) x dseg(4) x mseg(16)
__global__ void wfold_kernel(const float* __restrict__ headW,
                             const float* __restrict__ fOutW, const float* __restrict__ fNw,
                             const float* __restrict__ bOutW, const float* __restrict__ bNw,
                             float* __restrict__ wf2, float* __restrict__ wb2) {
    int blk = blockIdx.x;
    int dir = blk >> 6;
    int rem = blk & 63;
    int dseg = rem >> 4, mseg = rem & 15;
    int tid = threadIdx.x;
    int d = dseg * 256 + tid;
    const float* W = dir ? bOutW : fOutW;
    float s = 0.f;
#pragma unroll
    for (int m = mseg * 32; m < mseg * 32 + 32; ++m)
        s += headW[m] * W[(size_t)m * 1024 + d];
    const float* nw = dir ? bNw : fNw;
    atomicAdd(&(dir ? wb2 : wf2)[d], s * nw[d]);
}

// ---------------- fused bf16 conversions (weights + gf) ----------------

__global__ void tobf4_kernel(const float* __restrict__ inW, const float* __restrict__ fInW,
                             const float* __restrict__ bInW, const float* __restrict__ gf,
                             unsigned short* __restrict__ inW2, unsigned short* __restrict__ fInW2,
                             unsigned short* __restrict__ bInW2, unsigned short* __restrict__ gf2) {
    size_t idx = (size_t)blockIdx.x * 256 + threadIdx.x;
    const size_t A = 512UL * 384, B5 = 2432UL * 512;
    if (idx < A) {
        inW2[idx] = f2bf(inW[idx]);
    } else if (idx < A + B5) {
        size_t k = idx - A; int m = k / 512, kk = k % 512;
        fInW2[k] = f2bf(m < 2320 ? fInW[(size_t)m * 512 + kk] : 0.f);
    } else if (idx < A + 2 * B5) {
        size_t k = idx - A - B5; int m = k / 512, kk = k % 512;
        bInW2[k] = f2bf(m < 2320 ? bInW[(size_t)m * 512 + kk] : 0.f);
    } else {
        size_t k = idx - A - 2 * B5;   // 2048*384
        gf2[k] = f2bf(gf[k]);
    }
}

// ---------------- MFMA GEMM (bf16 out) for the ug projection ----------------

__global__ __launch_bounds__(256) void mfma_gemm_kernel(
    const unsigned short* __restrict__ A2, const unsigned short* __restrict__ W2,
    const float* __restrict__ bias, unsigned short* __restrict__ Cbf,
    int N, int K2, int ldc) {
    __shared__ __align__(16) unsigned short Al[128 * 40];
    __shared__ __align__(16) unsigned short Bl[128 * 40];
    const int tid = threadIdx.x;
    const int bm = blockIdx.y * 128, bn = blockIdx.x * 128;
    const int lane = tid & 63, wave = tid >> 6;
    const int wm = (wave >> 1) * 64, wn = (wave & 1) * 64;
    f32x4 acc[4][4];
#pragma unroll
    for (int i = 0; i < 4; ++i)
#pragma unroll
        for (int j = 0; j < 4; ++j) acc[i][j] = (f32x4){0.f, 0.f, 0.f, 0.f};

    for (int k0 = 0; k0 < K2; k0 += 32) {
        __syncthreads();
#pragma unroll
        for (int s = 0; s < 2; ++s) {
            int ch = tid + 256 * s;
            int row = ch >> 2, q = ch & 3;
            uint4 va = *(const uint4*)&A2[(size_t)(bm + row) * K2 + k0 + q * 8];
            *(uint4*)&Al[row * 40 + q * 8] = va;
            uint4 vb = *(const uint4*)&W2[(size_t)(bn + row) * K2 + k0 + q * 8];
            *(uint4*)&Bl[row * 40 + q * 8] = vb;
        }
        __syncthreads();
        bf16x8 af[4], bfr[4];
#pragma unroll
        for (int i = 0; i < 4; ++i)
            af[i] = *(const bf16x8*)&Al[(wm + i * 16 + (lane & 15)) * 40 + (lane >> 4) * 8];
#pragma unroll
        for (int j = 0; j < 4; ++j)
            bfr[j] = *(const bf16x8*)&Bl[(wn + j * 16 + (lane & 15)) * 40 + (lane >> 4) * 8];
#pragma unroll
        for (int i = 0; i < 4; ++i)
#pragma unroll
            for (int j = 0; j < 4; ++j)
                acc[i][j] = __builtin_amdgcn_mfma_f32_16x16x32_bf16(af[i], bfr[j], acc[i][j], 0, 0, 0);
    }
#pragma unroll
    for (int i = 0; i < 4; ++i) {
        int m = bm + wm + i * 16 + (lane >> 4) * 4;
#pragma unroll
        for (int j = 0; j < 4; ++j) {
            int n = bn + wn + j * 16 + (lane & 15);
            if (n < N) {
                float bv = bias ? bias[n] : 0.f;
#pragma unroll
                for (int r = 0; r < 4; ++r)
                    Cbf[(size_t)(m + r) * ldc + n] = f2bf(acc[i][j][r] + bv);
            }
        }
    }
}

// ---------------- merged fwd+bwd zx GEMM with scatter epilogue ----------------
// grid (38,16): bx<19 fwd, else bwd. Scatter: n<1024 -> sz fp16 silu;
// 1024<=n<2304 -> xbc bf16 [m][1280]; n>=2304 -> dtr fp32 [m][16].

__global__ __launch_bounds__(256) void zx_gemm_kernel(
    const unsigned short* __restrict__ A2,
    const unsigned short* __restrict__ fInW2, const unsigned short* __restrict__ bInW2,
    unsigned short* __restrict__ szF, unsigned short* __restrict__ xbcF, float* __restrict__ dtrF,
    unsigned short* __restrict__ szB, unsigned short* __restrict__ xbcB, float* __restrict__ dtrB) {
    __shared__ __align__(16) unsigned short Al[128 * 40];
    __shared__ __align__(16) unsigned short Bl[128 * 40];
    const int tid = threadIdx.x;
    const int bxx = blockIdx.x;
    const int d = (bxx >= 19);
    const int bn = (d ? bxx - 19 : bxx) * 128, bm = blockIdx.y * 128;
    const unsigned short* W2 = d ? bInW2 : fInW2;
    unsigned short* sz = d ? szB : szF;
    unsigned short* xbc = d ? xbcB : xbcF;
    float* dtr = d ? dtrB : dtrF;
    const int lane = tid & 63, wave = tid >> 6;
    const int wm = (wave >> 1) * 64, wn = (wave & 1) * 64;
    const int K2 = 512, N = 2320;
    f32x4 acc[4][4];
#pragma unroll
    for (int i = 0; i < 4; ++i)
#pragma unroll
        for (int j = 0; j < 4; ++j) acc[i][j] = (f32x4){0.f, 0.f, 0.f, 0.f};

    for (int k0 = 0; k0 < K2; k0 += 32) {
        __syncthreads();
#pragma unroll
        for (int s = 0; s < 2; ++s) {
            int ch = tid + 256 * s;
            int row = ch >> 2, q = ch & 3;
            uint4 va = *(const uint4*)&A2[(size_t)(bm + row) * K2 + k0 + q * 8];
            *(uint4*)&Al[row * 40 + q * 8] = va;
            uint4 vb = *(const uint4*)&W2[(size_t)(bn + row) * K2 + k0 + q * 8];
            *(uint4*)&Bl[row * 40 + q * 8] = vb;
        }
        __syncthreads();
        bf16x8 af[4], bfr[4];
#pragma unroll
        for (int i = 0; i < 4; ++i)
            af[i] = *(const bf16x8*)&Al[(wm + i * 16 + (lane & 15)) * 40 + (lane >> 4) * 8];
#pragma unroll
        for (int j = 0; j < 4; ++j)
            bfr[j] = *(const bf16x8*)&Bl[(wn + j * 16 + (lane & 15)) * 40 + (lane >> 4) * 8];
#pragma unroll
        for (int i = 0; i < 4; ++i)
#pragma unroll
            for (int j = 0; j < 4; ++j)
                acc[i][j] = __builtin_amdgcn_mfma_f32_16x16x32_bf16(af[i], bfr[j], acc[i][j], 0, 0, 0);
    }
#pragma unroll
    for (int i = 0; i < 4; ++i) {
        int m = bm + wm + i * 16 + (lane >> 4) * 4;
#pragma unroll
        for (int j = 0; j < 4; ++j) {
            int n = bn + wn + j * 16 + (lane & 15);
            if (n < N) {
#pragma unroll
                for (int r = 0; r < 4; ++r) {
                    float v = acc[i][j][r];
                    if (n < 1024)
                        sz[(size_t)(m + r) * 1024 + n] = f2h(siluf(v));
                    else if (n < 2304)
                        xbc[(size_t)(m + r) * 1280 + (n - 1024)] = f2bf(v);
                    else
                        dtr[(size_t)(m + r) * 16 + (n - 2304)] = v;
                }
            }
        }
    }
}

// ---------------- generic tiled fp32 GEMM (small shapes only) ----------------

__global__ __launch_bounds__(256) void gemm_kernel(
    const float* __restrict__ A, const float* __restrict__ W,
    const float* __restrict__ bias, float* __restrict__ C,
    int M, int N, int K, int ldc, int act) {
    __shared__ __align__(16) float As[16][68];
    __shared__ __align__(16) float Ws[16][68];
    const int tid = threadIdx.x;
    const int tx = tid & 15, ty = tid >> 4;
    const int bm = blockIdx.y * 64, bn = blockIdx.x * 64;
    const int lr = tid >> 2;
    const int lk = (tid & 3) * 4;
    float acc[4][4];
#pragma unroll
    for (int i = 0; i < 4; ++i)
#pragma unroll
        for (int j = 0; j < 4; ++j) acc[i][j] = 0.f;

    for (int k0 = 0; k0 < K; k0 += 16) {
        const int am = bm + lr;
        const int wn = bn + lr;
        float4 av = make_float4(0.f, 0.f, 0.f, 0.f), wv = make_float4(0.f, 0.f, 0.f, 0.f);
        if (am < M) av = *(const float4*)&A[(size_t)am * K + k0 + lk];
        if (wn < N) wv = *(const float4*)&W[(size_t)wn * K + k0 + lk];
        __syncthreads();
        As[lk + 0][lr] = av.x; As[lk + 1][lr] = av.y; As[lk + 2][lr] = av.z; As[lk + 3][lr] = av.w;
        Ws[lk + 0][lr] = wv.x; Ws[lk + 1][lr] = wv.y; Ws[lk + 2][lr] = wv.z; Ws[lk + 3][lr] = wv.w;
        __syncthreads();
#pragma unroll
        for (int kk = 0; kk < 16; ++kk) {
            float4 a = *(const float4*)&As[kk][ty * 4];
            float4 w = *(const float4*)&Ws[kk][tx * 4];
            float aa[4] = {a.x, a.y, a.z, a.w}, ww[4] = {w.x, w.y, w.z, w.w};
#pragma unroll
            for (int i = 0; i < 4; ++i)
#pragma unroll
                for (int j = 0; j < 4; ++j) acc[i][j] += aa[i] * ww[j];
        }
    }
#pragma unroll
    for (int i = 0; i < 4; ++i) {
        const int m = bm + ty * 4 + i;
        if (m >= M) continue;
#pragma unroll
        for (int j = 0; j < 4; ++j) {
            const int n = bn + tx * 4 + j;
            if (n >= N) continue;
            float v = acc[i][j] + (bias ? bias[n] : 0.f);
            if (act == 1) v = 0.5f * v * (1.f + erff(v * 0.70710678118654752f));
            C[(size_t)m * ldc + n] = v;
        }
    }
}

// ---------------- dt precompute (compact in, transposed out) ----------------

__global__ void dt_kernel(const float* __restrict__ dtrF, const float* __restrict__ dtrB,
                          const float* __restrict__ zxc,
                          const float* __restrict__ fDtB, const float* __restrict__ bDtB,
                          float* __restrict__ dtFsT, float* __restrict__ dtBsT,
                          float* __restrict__ dtFp) {
    int idx = blockIdx.x * 256 + threadIdx.x;   // 65664
    if (idx < 32768) {
        int r = idx >> 4, hh = idx & 15;
        float raw = dtrF[idx] + fDtB[hh];
        dtFsT[hh * 2048 + r] = (raw > 20.f) ? raw : log1pf(expf(raw));
    } else if (idx < 65536) {
        int k = idx - 32768;
        int r = k >> 4, hh = k & 15;
        float raw = dtrB[(size_t)(2047 - r) * 16 + hh] + bDtB[hh];
        dtBsT[hh * 2048 + r] = (raw > 20.f) ? raw : log1pf(expf(raw));
    } else if (idx < 65664) {
        int k = idx - 65536;
        int b = k >> 4, hh = k & 15;
        float raw = zxc[(size_t)b * DPROJ + 2304 + hh] + fDtB[hh];
        dtFp[k] = (raw > 20.f) ? raw : log1pf(expf(raw));
    }
}

// chunk-local inclusive cumsum of ldA = -dt*exp(A_log), transposed input
__global__ void cum_kernel(const float* __restrict__ dtFsT, const float* __restrict__ dtBsT,
                           const float* __restrict__ fAlog, const float* __restrict__ bAlog,
                           float* __restrict__ cumF, float* __restrict__ cumB) {
    int id = blockIdx.x * 256 + threadIdx.x;   // 1024
    int dir = id >> 9, k = id & 511, h = k >> 5, c = k & 31;
    const float* dtT = dir ? dtBsT : dtFsT;
    const float* Al = dir ? bAlog : fAlog;
    float* cum = dir ? cumB : cumF;
    float a = -expf(Al[h]);
    float acc = 0.f;
    for (int s4 = 0; s4 < 16; ++s4) {
        float4 v = *(const float4*)&dtT[h * 2048 + c * 64 + s4 * 4];
        float4 o;
        acc += v.x * a; o.x = acc;
        acc += v.y * a; o.y = acc;
        acc += v.z * a; o.z = acc;
        acc += v.w * a; o.w = acc;
        *(float4*)&cum[h * 2048 + c * 64 + s4 * 4] = o;
    }
}

// ---------------- fused causal depthwise conv (+SiLU), bf16 in/out ----------------

__global__ void conv_kernel(const unsigned short* __restrict__ xbcF,
                            const unsigned short* __restrict__ xbcB,
                            const float* __restrict__ zxc,
                            const float* __restrict__ fCw, const float* __restrict__ fCb,
                            const float* __restrict__ bCw, const float* __restrict__ bCb,
                            unsigned short* __restrict__ bcF, unsigned short* __restrict__ xF16,
                            unsigned short* __restrict__ bcB, unsigned short* __restrict__ xB16,
                            float* __restrict__ convFp, unsigned short* __restrict__ bcFp,
                            unsigned short* __restrict__ xFp16) {
    int blk = blockIdx.x, tid = threadIdx.x;
    if (blk < 10225) {
        int idx = blk * 256 + tid;
        if (idx >= 2045 * 1280) return;
        int t4 = idx / 1280, c = idx % 1280;
        float4 w4 = *(const float4*)&fCw[c * 4];
        float acc = fCb[c];
        acc += bfu(xbcF[(size_t)(t4 + 0) * 1280 + c]) * w4.x;
        acc += bfu(xbcF[(size_t)(t4 + 1) * 1280 + c]) * w4.y;
        acc += bfu(xbcF[(size_t)(t4 + 2) * 1280 + c]) * w4.z;
        acc += bfu(xbcF[(size_t)(t4 + 3) * 1280 + c]) * w4.w;
        float r = siluf(acc);
        if (c >= 1024) bcF[(size_t)t4 * 256 + (c - 1024)] = f2bf(r);
        else           xF16[(size_t)t4 * 1024 + c] = f2bf(r);
    } else if (blk < 20465) {
        int idx = (blk - 10225) * 256 + tid;   // 2048*1280
        int s = idx / 1280, c = idx % 1280;
        float4 w4 = *(const float4*)&bCw[c * 4];
        float w[4] = {w4.x, w4.y, w4.z, w4.w};
        float acc = bCb[c];
#pragma unroll
        for (int k = 0; k < 4; ++k) {
            int j = s - 3 + k;
            if (j >= 0) acc += bfu(xbcB[(size_t)(2047 - j) * 1280 + c]) * w[k];
        }
        float r = siluf(acc);
        if (c >= 1024) bcB[(size_t)s * 256 + (c - 1024)] = f2bf(r);
        else           xB16[(size_t)s * 1024 + c] = f2bf(r);
    } else {
        int idx = (blk - 20465) * 256 + tid;   // 8*4*1280
        int b = idx / 5120;
        int r = idx % 5120;
        int t = r / 1280, c = r % 1280;
        float4 w4 = *(const float4*)&fCw[c * 4];
        float w[4] = {w4.x, w4.y, w4.z, w4.w};
        float acc = fCb[c];
#pragma unroll
        for (int k = 0; k < 4; ++k) {
            int j = t - 3 + k;
            float x = 0.f;
            if (j == 0)      x = zxc[(size_t)b * DPROJ + 1024 + c];
            else if (j >= 1) x = bfu(xbcF[(size_t)(j - 1) * 1280 + c]);
            acc += x * w[k];
        }
        float rr = siluf(acc);
        convFp[idx] = rr;   // fp32 kept: x0v, cbm rank-1 path
        if (c >= 1024) bcFp[(size_t)(b * 4 + t) * 256 + (c - 1024)] = f2bf(rr);
        else           xFp16[(size_t)(b * 4 + t) * 1024 + c] = f2bf(rr);
    }
}

// ---------------- intra-chunk kernel (MFMA) ----------------

__global__ __launch_bounds__(256) void intra_kernel(
    const unsigned short* __restrict__ bcF, const unsigned short* __restrict__ bcFp,
    const unsigned short* __restrict__ bcB,
    const unsigned short* __restrict__ xF16, const unsigned short* __restrict__ xFp16,
    const unsigned short* __restrict__ xB16,
    const float* __restrict__ dtFsT, const float* __restrict__ dtBsT,
    const float* __restrict__ cumF, const float* __restrict__ cumB,
    unsigned short* __restrict__ YiF0, unsigned short* __restrict__ YiFs,
    unsigned short* __restrict__ YiB,
    unsigned short* __restrict__ UF0, unsigned short* __restrict__ UFs,
    unsigned short* __restrict__ UB) {
    __shared__ __align__(16) unsigned char smraw[63232];
    unsigned short* Bt = (unsigned short*)smraw;                    // 64 x 136  [s][n]
    unsigned short* Ct = (unsigned short*)(smraw + 17408);          // 64 x 136  [t][n]
    unsigned short* Sm = (unsigned short*)(smraw + 17408);          // 64 x 72   [t][s] (alias Ct)
    unsigned short* BT = (unsigned short*)(smraw + 34816);          // 128 x 72  [n][s]
    unsigned short* XT = (unsigned short*)(smraw + 53248);          // 64 x 72   [p][s]
    float* scum = (float*)(smraw + 62464);                          // 64
    float* sdt  = scum + 64;                                        // 64
    float* se   = scum + 128;                                       // 64

    const int iid = blockIdx.x;
    int dir, b = 0, h, c;
    unsigned short *Yout, *Uout;
    if (iid < 128)      { dir = 0; b = iid >> 4; h = iid & 15; c = 0;
                          Yout = YiF0 + (size_t)(b * 16 + h) * 4096; Uout = UF0 + (size_t)(b * 16 + h) * 8192; }
    else if (iid < 624) { int k = iid - 128; dir = 0; c = 1 + (k >> 4); h = k & 15;
                          Yout = YiFs + (size_t)(c * 16 + h) * 4096; Uout = UFs + (size_t)(c * 16 + h) * 8192; }
    else                { int k = iid - 624; dir = 1; c = k >> 4; h = k & 15;
                          Yout = YiB + (size_t)(c * 16 + h) * 4096;  Uout = UB + (size_t)(c * 16 + h) * 8192; }
    const float* dtAT = dir ? dtBsT : dtFsT;
    const float* cumA = dir ? cumB : cumF;

    const int tid = threadIdx.x;
    const int lane = tid & 63, wave = tid >> 6;
    const int quad = lane >> 4, l15 = lane & 15;

    {
        int r = tid >> 2, q = tid & 3;
        const unsigned short *bsrc, *xsrc;
        if (dir == 0) {
            int t = 64 * c + 1 + r;
            if (t < 4) { bsrc = bcFp + (size_t)(b * 4 + t) * 256; xsrc = xFp16 + (size_t)(b * 4 + t) * 1024; }
            else       { bsrc = bcF + (size_t)(t - 4) * 256;      xsrc = xF16 + (size_t)(t - 4) * 1024; }
        } else {
            int s = 64 * c + r;
            bsrc = bcB + (size_t)s * 256;
            xsrc = xB16 + (size_t)s * 1024;
        }
#pragma unroll
        for (int i = 0; i < 4; ++i) {
            int n0 = q * 32 + i * 8;
            uint4 v = *(const uint4*)&bsrc[n0];
            *(uint4*)&Bt[r * 136 + n0] = v;
            const unsigned short* pv = (const unsigned short*)&v;
#pragma unroll
            for (int jj = 0; jj < 8; ++jj) BT[(n0 + jj) * 72 + r] = pv[jj];
        }
#pragma unroll
        for (int i = 0; i < 4; ++i) {
            int n0 = q * 32 + i * 8;
            uint4 v = *(const uint4*)&bsrc[128 + n0];
            *(uint4*)&Ct[r * 136 + n0] = v;
        }
#pragma unroll
        for (int k = 0; k < 2; ++k) {
            uint4 v = *(const uint4*)&xsrc[h * 64 + q * 16 + k * 8];
            const unsigned short* pv = (const unsigned short*)&v;
#pragma unroll
            for (int jj = 0; jj < 8; ++jj) XT[(q * 16 + k * 8 + jj) * 72 + r] = pv[jj];
        }
        if (tid < 64) {
            int j = 64 * c + tid;
            scum[tid] = cumA[h * 2048 + j];
            sdt[tid] = dtAT[h * 2048 + j];
        }
    }
    __syncthreads();
    if (tid < 64) se[tid] = __expf(scum[63] - scum[tid]) * sdt[tid];

    // phase 1: G = C . B^T
    const int tm = (wave >> 1) * 32, sn = (wave & 1) * 32;
    f32x4 acc1[2][2];
#pragma unroll
    for (int i = 0; i < 2; ++i)
#pragma unroll
        for (int j = 0; j < 2; ++j) acc1[i][j] = (f32x4){0.f, 0.f, 0.f, 0.f};
#pragma unroll
    for (int ks = 0; ks < 4; ++ks) {
        bf16x8 af[2], bfr[2];
#pragma unroll
        for (int i = 0; i < 2; ++i)
            af[i] = *(const bf16x8*)&Ct[(tm + i * 16 + l15) * 136 + ks * 32 + quad * 8];
#pragma unroll
        for (int j = 0; j < 2; ++j)
            bfr[j] = *(const bf16x8*)&Bt[(sn + j * 16 + l15) * 136 + ks * 32 + quad * 8];
#pragma unroll
        for (int i = 0; i < 2; ++i)
#pragma unroll
            for (int j = 0; j < 2; ++j)
                acc1[i][j] = __builtin_amdgcn_mfma_f32_16x16x32_bf16(af[i], bfr[j], acc1[i][j], 0, 0, 0);
    }
    __syncthreads();

#pragma unroll
    for (int j = 0; j < 2; ++j) {
        int s = sn + j * 16 + l15;
        float cs = scum[s], ds = sdt[s];
#pragma unroll
        for (int i = 0; i < 2; ++i) {
#pragma unroll
            for (int r = 0; r < 4; ++r) {
                int t = tm + i * 16 + quad * 4 + r;
                float v = (s <= t) ? __expf(scum[t] - cs) * ds * acc1[i][j][r] : 0.f;
                Sm[t * 72 + s] = f2bf(v);
            }
        }
    }
    __syncthreads();

    // phase 2 (swapped): A = X^T rows p, B = Sm rows t -> D[p][t]
    const int pm = (wave >> 1) * 32, tn = (wave & 1) * 32;
    f32x4 acc2[2][2];
#pragma unroll
    for (int i = 0; i < 2; ++i)
#pragma unroll
        for (int j = 0; j < 2; ++j) acc2[i][j] = (f32x4){0.f, 0.f, 0.f, 0.f};
#pragma unroll
    for (int ks = 0; ks < 2; ++ks) {
        bf16x8 af[2], bfr[2];
#pragma unroll
        for (int i = 0; i < 2; ++i)
            af[i] = *(const bf16x8*)&XT[(pm + i * 16 + l15) * 72 + ks * 32 + quad * 8];
#pragma unroll
        for (int j = 0; j < 2; ++j)
            bfr[j] = *(const bf16x8*)&Sm[(tn + j * 16 + l15) * 72 + ks * 32 + quad * 8];
#pragma unroll
        for (int i = 0; i < 2; ++i)
#pragma unroll
            for (int j = 0; j < 2; ++j)
                acc2[i][j] = __builtin_amdgcn_mfma_f32_16x16x32_bf16(af[i], bfr[j], acc2[i][j], 0, 0, 0);
    }
#pragma unroll
    for (int i = 0; i < 2; ++i)
#pragma unroll
        for (int j = 0; j < 2; ++j) {
            int t = tn + j * 16 + l15;
            int p0 = pm + i * 16 + quad * 4;
            ushort4 o = make_ushort4(f2bf(acc2[i][j][0]), f2bf(acc2[i][j][1]),
                                     f2bf(acc2[i][j][2]), f2bf(acc2[i][j][3]));
            *(ushort4*)&Yout[t * 64 + p0] = o;
        }

    // phase 3: U = B^T . (e*X) -> write U[p][n]
    const int nm = wave * 32;
    f32x4 acc3[2][4];
#pragma unroll
    for (int i = 0; i < 2; ++i)
#pragma unroll
        for (int j = 0; j < 4; ++j) acc3[i][j] = (f32x4){0.f, 0.f, 0.f, 0.f};
#pragma unroll
    for (int ks = 0; ks < 2; ++ks) {
        float ev[8];
#pragma unroll
        for (int jj = 0; jj < 8; ++jj) ev[jj] = se[ks * 32 + quad * 8 + jj];
        bf16x8 bfx[4];
#pragma unroll
        for (int j = 0; j < 4; ++j) {
            bf16x8 xs = *(const bf16x8*)&XT[(j * 16 + l15) * 72 + ks * 32 + quad * 8];
#pragma unroll
            for (int jj = 0; jj < 8; ++jj)
                bfx[j][jj] = (short)f2bf(bfu((unsigned short)xs[jj]) * ev[jj]);
        }
        bf16x8 af[2];
#pragma unroll
        for (int i = 0; i < 2; ++i)
            af[i] = *(const bf16x8*)&BT[(nm + i * 16 + l15) * 72 + ks * 32 + quad * 8];
#pragma unroll
        for (int i = 0; i < 2; ++i)
#pragma unroll
            for (int j = 0; j < 4; ++j)
                acc3[i][j] = __builtin_amdgcn_mfma_f32_16x16x32_bf16(af[i], bfx[j], acc3[i][j], 0, 0, 0);
    }
#pragma unroll
    for (int i = 0; i < 2; ++i)
#pragma unroll
        for (int j = 0; j < 4; ++j) {
            int p = j * 16 + l15;
            int n0 = nm + i * 16 + quad * 4;
            ushort4 o = make_ushort4(f2bf(acc3[i][j][0]), f2bf(acc3[i][j][1]),
                                     f2bf(acc3[i][j][2]), f2bf(acc3[i][j][3]));
            *(ushort4*)&Uout[p * 128 + n0] = o;
        }
}

// ---------------- merged cb0 + M + tpsi ----------------

__global__ void mid_kernel(const float* __restrict__ convFp, const unsigned short* __restrict__ bcF,
                           const float* __restrict__ dtFp, const float* __restrict__ cumF,
                           const float* __restrict__ cumB,
                           const unsigned short* __restrict__ UF0,
                           const unsigned short* __restrict__ UFs, const unsigned short* __restrict__ UB,
                           float* __restrict__ cb0, unsigned short* __restrict__ Mb,
                           unsigned short* __restrict__ Tst, float* __restrict__ psiF) {
    int blk = blockIdx.x, tid = threadIdx.x;   // 416
    if (blk < 32) {
        int idx = blk * 256 + tid;   // 8192
        int b = idx >> 10, r = idx & 1023, h = r >> 6, tl = r & 63;
        int t = tl + 1;
        const float* b0 = convFp + (size_t)(b * 4) * CONVD;
        float s = 0.f;
        if (t < 4) {
            const float* crow = convFp + (size_t)(b * 4 + t) * CONVD;
            for (int n = 0; n < 128; ++n) s += crow[1152 + n] * b0[1024 + n];
        } else {
            const unsigned short* cr = bcF + (size_t)(t - 4) * 256 + 128;
            for (int n = 0; n < 128; ++n) s += bfu(cr[n]) * b0[1024 + n];
        }
        cb0[(b * 16 + h) * 64 + tl] = s * dtFp[b * 16 + h];
    } else if (blk < 160) {
        int bh = blk - 32;   // 128
        int b = bh >> 4, h = bh & 15;
        float D0 = __expf(cumF[h * 2048 + 63]);
        float dt0 = dtFp[b * 16 + h];
        const float* row0 = convFp + (size_t)(b * 4) * CONVD;
        const unsigned short* u = UF0 + (size_t)(b * 16 + h) * 8192;
        unsigned short* m = Mb + (size_t)(b * 16 + h) * 8192;
        for (int e4 = tid; e4 < 2048; e4 += 256) {
            int e = e4 * 4, p = e >> 7, n0 = e & 127;
            float s = D0 * dt0 * row0[h * 64 + p];
            float4 B4 = *(const float4*)&row0[1024 + n0];
            ushort4 uv = *(const ushort4*)&u[e];
            ushort4 o = make_ushort4(f2bf(s * B4.x + bfu(uv.x)), f2bf(s * B4.y + bfu(uv.y)),
                                     f2bf(s * B4.z + bfu(uv.z)), f2bf(s * B4.w + bfu(uv.w)));
            *(ushort4*)&m[e] = o;
        }
    } else {
        int blk2 = blk - 160;   // 256: dir*128 + h*8 + q8
        int dir = blk2 >> 7, h = (blk2 >> 3) & 15, q8 = blk2 & 7;
        const unsigned short* U = dir ? UB : UFs;
        const float* cum = dir ? cumB : cumF;
        unsigned short* T = Tst + (size_t)(dir * 16 + h) * 32 * 8192;
        if (dir == 0 && q8 == 0 && tid == 0) {
            float ps = 1.f;
            for (int c = 1; c < 32; ++c) {
                psiF[h * 32 + c] = ps;
                ps *= __expf(cumF[h * 2048 + c * 64 + 63]);
            }
        }
        const size_t e = (size_t)q8 * 1024 + 4 * tid;
        float4 st = make_float4(0.f, 0.f, 0.f, 0.f);
        const int c0 = dir ? 0 : 1;
        ushort4 u = *(const ushort4*)&U[((size_t)c0 * 16 + h) * 8192 + e];
        for (int c = c0; c < 32; ++c) {
            ushort4 un = make_ushort4(0, 0, 0, 0);
            if (c + 1 < 32) un = *(const ushort4*)&U[((size_t)(c + 1) * 16 + h) * 8192 + e];
            float Dc = __expf(cum[h * 2048 + c * 64 + 63]);
            ushort4 o = make_ushort4(f2bf(st.x), f2bf(st.y), f2bf(st.z), f2bf(st.w));
            *(ushort4*)&T[(size_t)c * 8192 + e] = o;
            st.x = Dc * st.x + bfu(u.x);
            st.y = Dc * st.y + bfu(u.y);
            st.z = Dc * st.z + bfu(u.z);
            st.w = Dc * st.w + bfu(u.w);
            u = un;
        }
    }
}

// ---------------- batch-shared Ys = Yi + et*(C . T^T) ----------------

__global__ __launch_bounds__(256) void yt_kernel(
    const unsigned short* __restrict__ bcF, const unsigned short* __restrict__ bcB,
    const unsigned short* __restrict__ Tst,
    const unsigned short* __restrict__ YiFs, const unsigned short* __restrict__ YiB,
    const float* __restrict__ cumF, const float* __restrict__ cumB,
    unsigned short* __restrict__ YsF, unsigned short* __restrict__ YsB) {
    const int iid = blockIdx.x;   // 1008
    int dir, h, c;
    if (iid < 496) { dir = 0; c = 1 + (iid >> 4); h = iid & 15; }
    else           { int k = iid - 496; dir = 1; c = k >> 4; h = k & 15; }
    const unsigned short* Cbase = (dir == 0)
        ? bcF + ((size_t)(64 * c - 3)) * 256 + 128
        : bcB + ((size_t)(64 * c)) * 256 + 128;
    const unsigned short* Tp = Tst + ((size_t)(dir * 16 + h) * 32 + c) * 8192;
    const unsigned short* Yi = (dir == 0 ? YiFs : YiB) + (size_t)(c * 16 + h) * 4096;
    const float* cum = dir ? cumB : cumF;
    unsigned short* Ys = (dir == 0 ? YsF : YsB) + (size_t)(c * 16 + h) * 4096;
    const int tid = threadIdx.x;
    const int lane = tid & 63, wave = tid >> 6;
    const int quad = lane >> 4, l15 = lane & 15;
    const int pm = (wave >> 1) * 32, tb = (wave & 1) * 32;
    f32x4 acc[2][2];
#pragma unroll
    for (int i = 0; i < 2; ++i)
#pragma unroll
        for (int j = 0; j < 2; ++j) acc[i][j] = (f32x4){0.f, 0.f, 0.f, 0.f};
#pragma unroll
    for (int ks = 0; ks < 4; ++ks) {
        bf16x8 af[2], bfr[2];
#pragma unroll
        for (int i = 0; i < 2; ++i)
            af[i] = *(const bf16x8*)&Tp[(size_t)(pm + i * 16 + l15) * 128 + ks * 32 + quad * 8];
#pragma unroll
        for (int j = 0; j < 2; ++j)
            bfr[j] = *(const bf16x8*)&Cbase[(size_t)(tb + j * 16 + l15) * 256 + ks * 32 + quad * 8];
#pragma unroll
        for (int i = 0; i < 2; ++i)
#pragma unroll
            for (int j = 0; j < 2; ++j)
                acc[i][j] = __builtin_amdgcn_mfma_f32_16x16x32_bf16(af[i], bfr[j], acc[i][j], 0, 0, 0);
    }
#pragma unroll
    for (int i = 0; i < 2; ++i)
#pragma unroll
        for (int j = 0; j < 2; ++j) {
            int t = tb + j * 16 + l15;
            int p0 = pm + i * 16 + quad * 4;
            float et = __expf(cum[h * 2048 + 64 * c + t]);
            ushort4 yi = *(const ushort4*)&Yi[t * 64 + p0];
            ushort4 o = make_ushort4(f2bf(bfu(yi.x) + et * acc[i][j][0]),
                                     f2bf(bfu(yi.y) + et * acc[i][j][1]),
                                     f2bf(bfu(yi.z) + et * acc[i][j][2]),
                                     f2bf(bfu(yi.w) + et * acc[i][j][3]));
            *(ushort4*)&Ys[t * 64 + p0] = o;
        }
}

// ---------------- gate kernel: 4 chunks/block, M fragments cached in regs ----------------

__global__ __launch_bounds__(256) void gate_kernel(
    const unsigned short* __restrict__ bcF,
    const unsigned short* __restrict__ Mb, const float* __restrict__ psiF,
    const unsigned short* __restrict__ YsF, const unsigned short* __restrict__ YsB,
    const unsigned short* __restrict__ xF16, const unsigned short* __restrict__ xFp16,
    const unsigned short* __restrict__ xB16,
    const unsigned short* __restrict__ szF, const unsigned short* __restrict__ szB,
    const float* __restrict__ convFp,
    const float* __restrict__ cumF,
    const unsigned short* __restrict__ YiF0,
    const float* __restrict__ cb0,
    const float* __restrict__ fD, const float* __restrict__ bD,
    const float* __restrict__ wf2, const float* __restrict__ wb2,
    float* __restrict__ aF, float* __restrict__ aB) {
    __shared__ __align__(16) float Ysm[64 * 68];

    const int iid = blockIdx.x;   // 1152: fwd 1024 (b,h,cg), bwd 128 (h,cg)
    int dir, b = 0, h, cg;
    if (iid < 1024) { dir = 0; b = iid >> 7; int r = iid & 127; h = r >> 3; cg = r & 7; }
    else            { int k = iid - 1024; dir = 1; h = k >> 3; cg = k & 7; }
    const int tid = threadIdx.x, tx = tid & 15, ty = tid >> 4;
    const int lane = tid & 63, wave = tid >> 6;
    const int quad = lane >> 4, l15 = lane & 15;

    const float Dh = (dir ? bD : fD)[h];
    const float* wvp = dir ? wb2 : wf2;
    float4 wreg = *(const float4*)&wvp[h * 64 + tx * 4];

    const int pm = (wave >> 1) * 32, tb = (wave & 1) * 32;
    bf16x8 mfr[4][2];
    if (dir == 0) {
        const unsigned short* Mp = Mb + (size_t)(b * 16 + h) * 8192;
#pragma unroll
        for (int ks = 0; ks < 4; ++ks)
#pragma unroll
            for (int i = 0; i < 2; ++i)
                mfr[ks][i] = *(const bf16x8*)&Mp[(size_t)(pm + i * 16 + l15) * 128 + ks * 32 + quad * 8];
    }

    for (int cc = 0; cc < 4; ++cc) {
        const int c = cg * 4 + cc;
        const bool fwdG = (dir == 0 && c > 0);
        if (fwdG) {
            if (cc > 0) __syncthreads();   // prior epilogue done reading Ysm
            const unsigned short* Cbase = bcF + ((size_t)(64 * c - 3)) * 256 + 128;
            f32x4 acc[2][2];
#pragma unroll
            for (int i = 0; i < 2; ++i)
#pragma unroll
                for (int j = 0; j < 2; ++j) acc[i][j] = (f32x4){0.f, 0.f, 0.f, 0.f};
#pragma unroll
            for (int ks = 0; ks < 4; ++ks) {
                bf16x8 bfr[2];
#pragma unroll
                for (int j = 0; j < 2; ++j)
                    bfr[j] = *(const bf16x8*)&Cbase[(size_t)(tb + j * 16 + l15) * 256 + ks * 32 + quad * 8];
#pragma unroll
                for (int i = 0; i < 2; ++i)
#pragma unroll
                    for (int j = 0; j < 2; ++j)
                        acc[i][j] = __builtin_amdgcn_mfma_f32_16x16x32_bf16(mfr[ks][i], bfr[j], acc[i][j], 0, 0, 0);
            }
#pragma unroll
            for (int i = 0; i < 2; ++i)
#pragma unroll
                for (int j = 0; j < 2; ++j)
                    *(f32x4*)&Ysm[(tb + j * 16 + l15) * 68 + pm + i * 16 + quad * 4] = acc[i][j];
            __syncthreads();
        }

        const float psi = fwdG ? psiF[h * 32 + c] : 0.f;
        float4 x0v = make_float4(0.f, 0.f, 0.f, 0.f);
        float cbv[4] = {0.f, 0.f, 0.f, 0.f};
        if (dir == 0 && c == 0) {
            x0v = *(const float4*)&convFp[(size_t)(b * 4) * CONVD + h * 64 + tx * 4];
#pragma unroll
            for (int i = 0; i < 4; ++i) cbv[i] = cb0[(b * 16 + h) * 64 + (ty + 16 * i)];
        }

        float rawet[4];
        ushort4 y4a[4], x4a[4], z4a[4];
        float4 cm4a[4];
#pragma unroll
        for (int i = 0; i < 4; ++i) {
            int tl = ty + 16 * i;
            int j = 64 * c + tl;
            rawet[i] = (dir == 0) ? cumF[h * 2048 + j] : 0.f;
            const unsigned short *Yp, *xp, *zp;
            if (dir == 0) {
                Yp = (c == 0) ? YiF0 + (size_t)(b * 16 + h) * 4096 : YsF + (size_t)(c * 16 + h) * 4096;
                if (c == 0) {
                    int t = j + 1;
                    xp = (t < 4) ? xFp16 + (size_t)(b * 4 + t) * 1024 : xF16 + (size_t)(t - 4) * 1024;
                } else {
                    xp = xF16 + (size_t)(64 * c + tl - 3) * 1024;
                }
                zp = szF + (size_t)j * 1024;
            } else {
                Yp = YsB + (size_t)(c * 16 + h) * 4096;
                xp = xB16 + (size_t)j * 1024;
                zp = szB + (size_t)(2047 - j) * 1024;
            }
            y4a[i] = *(const ushort4*)&Yp[tl * 64 + tx * 4];
            x4a[i] = *(const ushort4*)&xp[h * 64 + tx * 4];
            z4a[i] = *(const ushort4*)&zp[h * 64 + tx * 4];
            if (fwdG)                    cm4a[i] = *(const float4*)&Ysm[tl * 68 + tx * 4];
            else if (dir == 0 && c == 0) cm4a[i] = x0v;
            else                         cm4a[i] = make_float4(0.f, 0.f, 0.f, 0.f);
        }

#pragma unroll
        for (int i = 0; i < 4; ++i) {
            int j = 64 * c + ty + 16 * i;
            float k1 = 0.f;
            if (dir == 0) {
                float et = __expf(rawet[i]);
                k1 = (c == 0) ? et * cbv[i] : et * psi;
            }
            float yv[4] = {bfu(y4a[i].x), bfu(y4a[i].y), bfu(y4a[i].z), bfu(y4a[i].w)};
            float xa[4] = {bfu(x4a[i].x), bfu(x4a[i].y), bfu(x4a[i].z), bfu(x4a[i].w)};
            float sza[4] = {h2f(z4a[i].x), h2f(z4a[i].y), h2f(z4a[i].z), h2f(z4a[i].w)};
            float cma[4] = {cm4a[i].x, cm4a[i].y, cm4a[i].z, cm4a[i].w};
            float wa[4] = {wreg.x, wreg.y, wreg.z, wreg.w};
            float a1 = 0.f, a2 = 0.f;
#pragma unroll
            for (int w = 0; w < 4; ++w) {
                float tot = yv[w] + k1 * cma[w] + Dh * xa[w];
                float g = tot * sza[w];
                a1 += g * wa[w];
                a2 += g * g;
            }
#pragma unroll
            for (int m = 1; m < 16; m <<= 1) {
                a1 += __shfl_xor(a1, m);
                a2 += __shfl_xor(a2, m);
            }
            if (tx == 0) {
                if (dir == 0) {
                    size_t o = ((size_t)(b * 2048 + j) * 16 + h) * 2;
                    aF[o] = a1; aF[o + 1] = a2;
                } else {
                    int g = 2047 - j;
                    size_t o = ((size_t)g * 16 + h) * 2;
                    aB[o] = a1; aB[o + 1] = a2;
                }
            }
        }
    }
}

// ---------------- final combine ----------------

__global__ void final_kernel(const float* __restrict__ aF, const float* __restrict__ aB,
                             const float* __restrict__ headB, float* __restrict__ out) {
    int idx = blockIdx.x * 256 + threadIdx.x;   // 16384
    int b = idx >> 11, g = idx & 2047;
    const float* pf = aF + ((size_t)(b * 2048 + g)) * 32;
    const float* pb = aB + (size_t)g * 32;
    float f1 = 0.f, f2 = 0.f, b1 = 0.f, b2 = 0.f;
#pragma unroll
    for (int h = 0; h < 16; ++h) {
        f1 += pf[2 * h]; f2 += pf[2 * h + 1];
        b1 += pb[2 * h]; b2 += pb[2 * h + 1];
    }
    out[idx] = f1 * rsqrtf(f2 * (1.f / 1024.f) + 1e-5f) +
               b1 * rsqrtf(b2 * (1.f / 1024.f) + 1e-5f) + headB[0];
}

// ---------------- launch ----------------

extern "C" void kernel_launch(void* const* d_in, const int* in_sizes, int n_in,
                              void* d_out, int out_size, void* d_ws, size_t ws_size,
                              hipStream_t stream) {
    const int*   pidx   = (const int*)  d_in[0];
    const int*   chridx = (const int*)  d_in[1];
    const float* locusF = (const float*)d_in[2];
    const float* pathF  = (const float*)d_in[3];
    const float* pertE  = (const float*)d_in[4];
    const float* gidE   = (const float*)d_in[5];
    const float* chrE   = (const float*)d_in[6];
    const float* locusW = (const float*)d_in[7];
    const float* locusB = (const float*)d_in[8];
    const float* condW  = (const float*)d_in[9];
    const float* condB  = (const float*)d_in[10];
    const float* inW    = (const float*)d_in[11];
    const float* inB    = (const float*)d_in[12];
    const float* headW  = (const float*)d_in[13];
    const float* headB  = (const float*)d_in[14];
    const float* fInW   = (const float*)d_in[15];
    const float* fCw    = (const float*)d_in[16];
    const float* fCb    = (const float*)d_in[17];
    const float* fDtB   = (const float*)d_in[18];
    const float* fAlog  = (const float*)d_in[19];
    const float* fDp    = (const float*)d_in[20];
    const float* fNw    = (const float*)d_in[21];
    const float* fOutW  = (const float*)d_in[22];
    const float* bInW   = (const float*)d_in[23];
    const float* bCw    = (const float*)d_in[24];
    const float* bCb    = (const float*)d_in[25];
    const float* bDtB   = (const float*)d_in[26];
    const float* bAlog  = (const float*)d_in[27];
    const float* bDp    = (const float*)d_in[28];
    const float* bNw    = (const float*)d_in[29];
    const float* bOutW  = (const float*)d_in[30];
    float* out = (float*)d_out;
    (void)in_sizes; (void)n_in; (void)out_size; (void)ws_size;

    char* base = (char*)d_ws;
    size_t off = 0;
    auto allocf = [&](size_t n) -> float* {
        char* r = base + off; off += ((n * 4 + 63) & ~(size_t)63); return (float*)r; };
    auto allocu = [&](size_t n) -> unsigned short* {
        char* r = base + off; off += ((n * 2 + 63) & ~(size_t)63); return (unsigned short*)r; };

    float* gf     = allocf(2048UL * 384);
    float* cond   = allocf(8UL * 384);
    float* cemb   = allocf(8UL * 128);
    float* uc     = allocf(8UL * 512);
    float* zxc    = allocf(8UL * DPROJ);
    float* convFp = allocf(8UL * 4 * CONVD);
    float* dtrF   = allocf(2048UL * 16);
    float* dtrB   = allocf(2048UL * 16);
    float* dtFsT  = allocf(16UL * 2048);
    float* dtFp   = allocf(128);
    float* dtBsT  = allocf(16UL * 2048);
    float* cumF   = allocf(16UL * 2048);
    float* cumB   = allocf(16UL * 2048);
    float* wf2    = allocf(1024);
    float* wb2    = allocf(1024);
    float* cb0    = allocf(8UL * 16 * 64);
    float* psiF   = allocf(16UL * 32);
    float* aF     = allocf(8UL * 2048 * 16 * 2);
    float* aB     = allocf(2048UL * 16 * 2);
    unsigned short* xbcF = allocu(2048UL * 1280);
    unsigned short* xbcB = allocu(2048UL * 1280);
    unsigned short* YiF0 = allocu(8UL * 16 * 4096);
    unsigned short* YiFs = allocu(32UL * 16 * 4096);
    unsigned short* YiB  = allocu(32UL * 16 * 4096);
    unsigned short* UF0  = allocu(8UL * 16 * 8192);
    unsigned short* UFs  = allocu(32UL * 16 * 8192);
    unsigned short* UB   = allocu(32UL * 16 * 8192);
    unsigned short* Mb   = allocu(8UL * 16 * 8192);
    unsigned short* Tst  = allocu(2UL * 16 * 32 * 8192);
    unsigned short* bcF  = allocu(2045UL * 256);
    unsigned short* bcFp = allocu(32UL * 256);
    unsigned short* bcB  = allocu(2048UL * 256);
    unsigned short* YsF  = allocu(32UL * 16 * 4096);
    unsigned short* YsB  = allocu(32UL * 16 * 4096);
    unsigned short* xF16 = allocu(2045UL * 1024);
    unsigned short* xFp16= allocu(32UL * 1024);
    unsigned short* xB16 = allocu(2048UL * 1024);
    unsigned short* szF  = allocu(2048UL * 1024);
    unsigned short* szB  = allocu(2048UL * 1024);
    unsigned short* gf2   = allocu(2048UL * 384);
    unsigned short* inW2  = allocu(512UL * 384);
    unsigned short* ug2   = allocu(2048UL * 512);
    unsigned short* fInW2 = allocu(2432UL * 512);
    unsigned short* bInW2 = allocu(2432UL * 512);

    gg_kernel<<<3077, 256, 0, stream>>>(chridx, gidE, pathF, chrE, pidx, pertE, gf, cemb, wf2, wb2);
    wfold_kernel<<<128, 256, 0, stream>>>(headW, fOutW, fNw, bOutW, bNw, wf2, wb2);
    gemm_kernel<<<dim3(1, 32), 256, 0, stream>>>(locusF, locusW, locusB, gf + 320, 2048, 64, 64, 384, 1);
    gemm_kernel<<<dim3(6, 1), 256, 0, stream>>>(cemb, condW, condB, cond, 8, 384, 128, 384, 0);

    tobf4_kernel<<<13568, 256, 0, stream>>>(inW, fInW, bInW, gf, inW2, fInW2, bInW2, gf2);

    // ug2 = bf16(gf @ inW^T + inB)
    mfma_gemm_kernel<<<dim3(4, 16), 256, 0, stream>>>(gf2, inW2, inB, ug2, 512, 384, 512);
    gemm_kernel<<<dim3(8, 1), 256, 0, stream>>>(cond, inW, inB, uc, 8, 512, 384, 512, 0);

    // merged fwd+bwd zx GEMM with scatter epilogue
    zx_gemm_kernel<<<dim3(38, 16), 256, 0, stream>>>(ug2, fInW2, bInW2,
                                                     szF, xbcF, dtrF, szB, xbcB, dtrB);
    gemm_kernel<<<dim3(37, 1), 256, 0, stream>>>(uc, fInW, nullptr, zxc, 8, DPROJ, 512, DPROJ, 0);

    dt_kernel<<<257, 256, 0, stream>>>(dtrF, dtrB, zxc, fDtB, bDtB, dtFsT, dtBsT, dtFp);
    cum_kernel<<<4, 256, 0, stream>>>(dtFsT, dtBsT, fAlog, bAlog, cumF, cumB);
    conv_kernel<<<20625, 256, 0, stream>>>(xbcF, xbcB, zxc, fCw, fCb, bCw, bCb,
                                           bcF, xF16, bcB, xB16, convFp, bcFp, xFp16);
    intra_kernel<<<1136, 256, 0, stream>>>(bcF, bcFp, bcB, xF16, xFp16, xB16,
                                           dtFsT, dtBsT, cumF, cumB,
                                           YiF0, YiFs, YiB, UF0, UFs, UB);
    mid_kernel<<<416, 256, 0, stream>>>(convFp, bcF, dtFp, cumF, cumB, UF0, UFs, UB,
                                        cb0, Mb, Tst, psiF);
    yt_kernel<<<1008, 256, 0, stream>>>(bcF, bcB, Tst, YiFs, YiB, cumF, cumB, YsF, YsB);
    gate_kernel<<<1152, 256, 0, stream>>>(bcF, Mb, psiF, YsF, YsB, xF16, xFp16, xB16,
                                          szF, szB, convFp, cumF,
                                          YiF0, cb0, fDp, bDp, wf2, wb2, aF, aB);
    final_kernel<<<64, 256, 0, stream>>>(aF, aB, headB, out);
}

// Round 13
// 366.363 us; speedup vs baseline: 1.3049x; 1.0180x over previous
//
#include <hip/hip_runtime.h>
#include <hip/hip_bf16.h>
#include <hip/hip_fp16.h>
#include <math.h>

#define DPROJ 2320
#define CONVD 1280

typedef __attribute__((ext_vector_type(8))) short bf16x8;
typedef __attribute__((ext_vector_type(4))) float f32x4;

__device__ __forceinline__ float siluf(float x) { return x / (1.f + __expf(-x)); }
__device__ __forceinline__ float bfu(unsigned short s) { return __uint_as_float(((unsigned)s) << 16); }
__device__ __forceinline__ unsigned short f2bf(float f) {
    unsigned u = __float_as_uint(f);
    unsigned r = (u + 0x7FFFu + ((u >> 16) & 1u)) >> 16;
    return (unsigned short)r;
}
__device__ __forceinline__ unsigned short f2h(float f) {
    __half h = __float2half(f);
    return *(unsigned short*)&h;
}
__device__ __forceinline__ float h2f(unsigned short s) {
    __half h = *(__half*)&s;
    return __half2float(h);
}

// ---------------- fused gather + genefeat + wfold-zero ----------------

__global__ void gg_kernel(const int* __restrict__ chridx, const float* __restrict__ gid,
                          const float* __restrict__ path, const float* __restrict__ chrE,
                          const int* __restrict__ pidx, const float* __restrict__ pertE,
                          float* __restrict__ gf, float* __restrict__ cemb,
                          float* __restrict__ wf2, float* __restrict__ wb2) {
    int blk = blockIdx.x, tid = threadIdx.x;
    if (blk < 3072) {
        int idx = blk * 256 + tid;   // 2048*384
        int g = idx / 384, j = idx % 384;
        float v;
        if (j < 128)      v = gid[(size_t)g * 128 + j];
        else if (j < 256) v = path[(size_t)g * 128 + (j - 128)];
        else if (j < 320) v = chrE[(size_t)chridx[g] * 64 + (j - 256)];
        else return;
        gf[idx] = v;
    } else if (blk < 3076) {
        int idx = (blk - 3072) * 256 + tid;   // 1024
        int b = idx >> 7, k = idx & 127;
        cemb[idx] = pertE[(size_t)pidx[b] * 128 + k];
    } else {
        wf2[tid * 4 + 0] = 0.f; wf2[tid * 4 + 1] = 0.f;
        wf2[tid * 4 + 2] = 0.f; wf2[tid * 4 + 3] = 0.f;
        wb2[tid * 4 + 0] = 0.f; wb2[tid * 4 + 1] = 0.f;
        wb2[tid * 4 + 2] = 0.f; wb2[tid * 4 + 3] = 0.f;
    }
}

// wfold: split-m atomic partial sums. 128 blocks = dir(2) x dseg(4) x mseg(16)
__global__ void wfold_kernel(const float* __restrict__ headW,
                             const float* __restrict__ fOutW, const float* __restrict__ fNw,
                             const float* __restrict__ bOutW, const float* __restrict__ bNw,
                             float* __restrict__ wf2, float* __restrict__ wb2) {
    int blk = blockIdx.x;
    int dir = blk >> 6;
    int rem = blk & 63;
    int dseg = rem >> 4, mseg = rem & 15;
    int tid = threadIdx.x;
    int d = dseg * 256 + tid;
    const float* W = dir ? bOutW : fOutW;
    float s = 0.f;
#pragma unroll
    for (int m = mseg * 32; m < mseg * 32 + 32; ++m)
        s += headW[m] * W[(size_t)m * 1024 + d];
    const float* nw = dir ? bNw : fNw;
    atomicAdd(&(dir ? wb2 : wf2)[d], s * nw[d]);
}

// ---------------- fused bf16 conversions (weights + gf) ----------------

__global__ void tobf4_kernel(const float* __restrict__ inW, const float* __restrict__ fInW,
                             const float* __restrict__ bInW, const float* __restrict__ gf,
                             unsigned short* __restrict__ inW2, unsigned short* __restrict__ fInW2,
                             unsigned short* __restrict__ bInW2, unsigned short* __restrict__ gf2) {
    size_t idx = (size_t)blockIdx.x * 256 + threadIdx.x;
    const size_t A = 512UL * 384, B5 = 2432UL * 512;
    if (idx < A) {
        inW2[idx] = f2bf(inW[idx]);
    } else if (idx < A + B5) {
        size_t k = idx - A; int m = k / 512, kk = k % 512;
        fInW2[k] = f2bf(m < 2320 ? fInW[(size_t)m * 512 + kk] : 0.f);
    } else if (idx < A + 2 * B5) {
        size_t k = idx - A - B5; int m = k / 512, kk = k % 512;
        bInW2[k] = f2bf(m < 2320 ? bInW[(size_t)m * 512 + kk] : 0.f);
    } else {
        size_t k = idx - A - 2 * B5;   // 2048*384
        gf2[k] = f2bf(gf[k]);
    }
}

// ---------------- MFMA GEMM (bf16 out) for the ug projection ----------------

__global__ __launch_bounds__(256) void mfma_gemm_kernel(
    const unsigned short* __restrict__ A2, const unsigned short* __restrict__ W2,
    const float* __restrict__ bias, unsigned short* __restrict__ Cbf,
    int N, int K2, int ldc) {
    __shared__ __align__(16) unsigned short Al[128 * 40];
    __shared__ __align__(16) unsigned short Bl[128 * 40];
    const int tid = threadIdx.x;
    const int bm = blockIdx.y * 128, bn = blockIdx.x * 128;
    const int lane = tid & 63, wave = tid >> 6;
    const int wm = (wave >> 1) * 64, wn = (wave & 1) * 64;
    f32x4 acc[4][4];
#pragma unroll
    for (int i = 0; i < 4; ++i)
#pragma unroll
        for (int j = 0; j < 4; ++j) acc[i][j] = (f32x4){0.f, 0.f, 0.f, 0.f};

    for (int k0 = 0; k0 < K2; k0 += 32) {
        __syncthreads();
#pragma unroll
        for (int s = 0; s < 2; ++s) {
            int ch = tid + 256 * s;
            int row = ch >> 2, q = ch & 3;
            uint4 va = *(const uint4*)&A2[(size_t)(bm + row) * K2 + k0 + q * 8];
            *(uint4*)&Al[row * 40 + q * 8] = va;
            uint4 vb = *(const uint4*)&W2[(size_t)(bn + row) * K2 + k0 + q * 8];
            *(uint4*)&Bl[row * 40 + q * 8] = vb;
        }
        __syncthreads();
        bf16x8 af[4], bfr[4];
#pragma unroll
        for (int i = 0; i < 4; ++i)
            af[i] = *(const bf16x8*)&Al[(wm + i * 16 + (lane & 15)) * 40 + (lane >> 4) * 8];
#pragma unroll
        for (int j = 0; j < 4; ++j)
            bfr[j] = *(const bf16x8*)&Bl[(wn + j * 16 + (lane & 15)) * 40 + (lane >> 4) * 8];
#pragma unroll
        for (int i = 0; i < 4; ++i)
#pragma unroll
            for (int j = 0; j < 4; ++j)
                acc[i][j] = __builtin_amdgcn_mfma_f32_16x16x32_bf16(af[i], bfr[j], acc[i][j], 0, 0, 0);
    }
#pragma unroll
    for (int i = 0; i < 4; ++i) {
        int m = bm + wm + i * 16 + (lane >> 4) * 4;
#pragma unroll
        for (int j = 0; j < 4; ++j) {
            int n = bn + wn + j * 16 + (lane & 15);
            if (n < N) {
                float bv = bias ? bias[n] : 0.f;
#pragma unroll
                for (int r = 0; r < 4; ++r)
                    Cbf[(size_t)(m + r) * ldc + n] = f2bf(acc[i][j][r] + bv);
            }
        }
    }
}

// ---------------- merged fwd+bwd zx GEMM with scatter epilogue ----------------

__global__ __launch_bounds__(256) void zx_gemm_kernel(
    const unsigned short* __restrict__ A2,
    const unsigned short* __restrict__ fInW2, const unsigned short* __restrict__ bInW2,
    unsigned short* __restrict__ szF, unsigned short* __restrict__ xbcF, float* __restrict__ dtrF,
    unsigned short* __restrict__ szB, unsigned short* __restrict__ xbcB, float* __restrict__ dtrB) {
    __shared__ __align__(16) unsigned short Al[128 * 40];
    __shared__ __align__(16) unsigned short Bl[128 * 40];
    const int tid = threadIdx.x;
    const int bxx = blockIdx.x;
    const int d = (bxx >= 19);
    const int bn = (d ? bxx - 19 : bxx) * 128, bm = blockIdx.y * 128;
    const unsigned short* W2 = d ? bInW2 : fInW2;
    unsigned short* sz = d ? szB : szF;
    unsigned short* xbc = d ? xbcB : xbcF;
    float* dtr = d ? dtrB : dtrF;
    const int lane = tid & 63, wave = tid >> 6;
    const int wm = (wave >> 1) * 64, wn = (wave & 1) * 64;
    const int K2 = 512, N = 2320;
    f32x4 acc[4][4];
#pragma unroll
    for (int i = 0; i < 4; ++i)
#pragma unroll
        for (int j = 0; j < 4; ++j) acc[i][j] = (f32x4){0.f, 0.f, 0.f, 0.f};

    for (int k0 = 0; k0 < K2; k0 += 32) {
        __syncthreads();
#pragma unroll
        for (int s = 0; s < 2; ++s) {
            int ch = tid + 256 * s;
            int row = ch >> 2, q = ch & 3;
            uint4 va = *(const uint4*)&A2[(size_t)(bm + row) * K2 + k0 + q * 8];
            *(uint4*)&Al[row * 40 + q * 8] = va;
            uint4 vb = *(const uint4*)&W2[(size_t)(bn + row) * K2 + k0 + q * 8];
            *(uint4*)&Bl[row * 40 + q * 8] = vb;
        }
        __syncthreads();
        bf16x8 af[4], bfr[4];
#pragma unroll
        for (int i = 0; i < 4; ++i)
            af[i] = *(const bf16x8*)&Al[(wm + i * 16 + (lane & 15)) * 40 + (lane >> 4) * 8];
#pragma unroll
        for (int j = 0; j < 4; ++j)
            bfr[j] = *(const bf16x8*)&Bl[(wn + j * 16 + (lane & 15)) * 40 + (lane >> 4) * 8];
#pragma unroll
        for (int i = 0; i < 4; ++i)
#pragma unroll
            for (int j = 0; j < 4; ++j)
                acc[i][j] = __builtin_amdgcn_mfma_f32_16x16x32_bf16(af[i], bfr[j], acc[i][j], 0, 0, 0);
    }
#pragma unroll
    for (int i = 0; i < 4; ++i) {
        int m = bm + wm + i * 16 + (lane >> 4) * 4;
#pragma unroll
        for (int j = 0; j < 4; ++j) {
            int n = bn + wn + j * 16 + (lane & 15);
            if (n < N) {
#pragma unroll
                for (int r = 0; r < 4; ++r) {
                    float v = acc[i][j][r];
                    if (n < 1024)
                        sz[(size_t)(m + r) * 1024 + n] = f2h(siluf(v));
                    else if (n < 2304)
                        xbc[(size_t)(m + r) * 1280 + (n - 1024)] = f2bf(v);
                    else
                        dtr[(size_t)(m + r) * 16 + (n - 2304)] = v;
                }
            }
        }
    }
}

// ---------------- generic tiled fp32 GEMM (small shapes only) ----------------

__global__ __launch_bounds__(256) void gemm_kernel(
    const float* __restrict__ A, const float* __restrict__ W,
    const float* __restrict__ bias, float* __restrict__ C,
    int M, int N, int K, int ldc, int act) {
    __shared__ __align__(16) float As[16][68];
    __shared__ __align__(16) float Ws[16][68];
    const int tid = threadIdx.x;
    const int tx = tid & 15, ty = tid >> 4;
    const int bm = blockIdx.y * 64, bn = blockIdx.x * 64;
    const int lr = tid >> 2;
    const int lk = (tid & 3) * 4;
    float acc[4][4];
#pragma unroll
    for (int i = 0; i < 4; ++i)
#pragma unroll
        for (int j = 0; j < 4; ++j) acc[i][j] = 0.f;

    for (int k0 = 0; k0 < K; k0 += 16) {
        const int am = bm + lr;
        const int wn = bn + lr;
        float4 av = make_float4(0.f, 0.f, 0.f, 0.f), wv = make_float4(0.f, 0.f, 0.f, 0.f);
        if (am < M) av = *(const float4*)&A[(size_t)am * K + k0 + lk];
        if (wn < N) wv = *(const float4*)&W[(size_t)wn * K + k0 + lk];
        __syncthreads();
        As[lk + 0][lr] = av.x; As[lk + 1][lr] = av.y; As[lk + 2][lr] = av.z; As[lk + 3][lr] = av.w;
        Ws[lk + 0][lr] = wv.x; Ws[lk + 1][lr] = wv.y; Ws[lk + 2][lr] = wv.z; Ws[lk + 3][lr] = wv.w;
        __syncthreads();
#pragma unroll
        for (int kk = 0; kk < 16; ++kk) {
            float4 a = *(const float4*)&As[kk][ty * 4];
            float4 w = *(const float4*)&Ws[kk][tx * 4];
            float aa[4] = {a.x, a.y, a.z, a.w}, ww[4] = {w.x, w.y, w.z, w.w};
#pragma unroll
            for (int i = 0; i < 4; ++i)
#pragma unroll
                for (int j = 0; j < 4; ++j) acc[i][j] += aa[i] * ww[j];
        }
    }
#pragma unroll
    for (int i = 0; i < 4; ++i) {
        const int m = bm + ty * 4 + i;
        if (m >= M) continue;
#pragma unroll
        for (int j = 0; j < 4; ++j) {
            const int n = bn + tx * 4 + j;
            if (n >= N) continue;
            float v = acc[i][j] + (bias ? bias[n] : 0.f);
            if (act == 1) v = 0.5f * v * (1.f + erff(v * 0.70710678118654752f));
            C[(size_t)m * ldc + n] = v;
        }
    }
}

// ---------------- dt precompute (compact in, transposed out) ----------------

__global__ void dt_kernel(const float* __restrict__ dtrF, const float* __restrict__ dtrB,
                          const float* __restrict__ zxc,
                          const float* __restrict__ fDtB, const float* __restrict__ bDtB,
                          float* __restrict__ dtFsT, float* __restrict__ dtBsT,
                          float* __restrict__ dtFp) {
    int idx = blockIdx.x * 256 + threadIdx.x;   // 65664
    if (idx < 32768) {
        int r = idx >> 4, hh = idx & 15;
        float raw = dtrF[idx] + fDtB[hh];
        dtFsT[hh * 2048 + r] = (raw > 20.f) ? raw : log1pf(expf(raw));
    } else if (idx < 65536) {
        int k = idx - 32768;
        int r = k >> 4, hh = k & 15;
        float raw = dtrB[(size_t)(2047 - r) * 16 + hh] + bDtB[hh];
        dtBsT[hh * 2048 + r] = (raw > 20.f) ? raw : log1pf(expf(raw));
    } else if (idx < 65664) {
        int k = idx - 65536;
        int b = k >> 4, hh = k & 15;
        float raw = zxc[(size_t)b * DPROJ + 2304 + hh] + fDtB[hh];
        dtFp[k] = (raw > 20.f) ? raw : log1pf(expf(raw));
    }
}

// chunk-local inclusive cumsum of ldA = -dt*exp(A_log), transposed input
__global__ void cum_kernel(const float* __restrict__ dtFsT, const float* __restrict__ dtBsT,
                           const float* __restrict__ fAlog, const float* __restrict__ bAlog,
                           float* __restrict__ cumF, float* __restrict__ cumB) {
    int id = blockIdx.x * 256 + threadIdx.x;   // 1024
    int dir = id >> 9, k = id & 511, h = k >> 5, c = k & 31;
    const float* dtT = dir ? dtBsT : dtFsT;
    const float* Al = dir ? bAlog : fAlog;
    float* cum = dir ? cumB : cumF;
    float a = -expf(Al[h]);
    float acc = 0.f;
    for (int s4 = 0; s4 < 16; ++s4) {
        float4 v = *(const float4*)&dtT[h * 2048 + c * 64 + s4 * 4];
        float4 o;
        acc += v.x * a; o.x = acc;
        acc += v.y * a; o.y = acc;
        acc += v.z * a; o.z = acc;
        acc += v.w * a; o.w = acc;
        *(float4*)&cum[h * 2048 + c * 64 + s4 * 4] = o;
    }
}

// ---------------- fused causal depthwise conv (+SiLU), bf16 in/out ----------------

__global__ void conv_kernel(const unsigned short* __restrict__ xbcF,
                            const unsigned short* __restrict__ xbcB,
                            const float* __restrict__ zxc,
                            const float* __restrict__ fCw, const float* __restrict__ fCb,
                            const float* __restrict__ bCw, const float* __restrict__ bCb,
                            unsigned short* __restrict__ bcF, unsigned short* __restrict__ xF16,
                            unsigned short* __restrict__ bcB, unsigned short* __restrict__ xB16,
                            float* __restrict__ convFp, unsigned short* __restrict__ bcFp,
                            unsigned short* __restrict__ xFp16) {
    int blk = blockIdx.x, tid = threadIdx.x;
    if (blk < 10225) {
        int idx = blk * 256 + tid;
        if (idx >= 2045 * 1280) return;
        int t4 = idx / 1280, c = idx % 1280;
        float4 w4 = *(const float4*)&fCw[c * 4];
        float acc = fCb[c];
        acc += bfu(xbcF[(size_t)(t4 + 0) * 1280 + c]) * w4.x;
        acc += bfu(xbcF[(size_t)(t4 + 1) * 1280 + c]) * w4.y;
        acc += bfu(xbcF[(size_t)(t4 + 2) * 1280 + c]) * w4.z;
        acc += bfu(xbcF[(size_t)(t4 + 3) * 1280 + c]) * w4.w;
        float r = siluf(acc);
        if (c >= 1024) bcF[(size_t)t4 * 256 + (c - 1024)] = f2bf(r);
        else           xF16[(size_t)t4 * 1024 + c] = f2bf(r);
    } else if (blk < 20465) {
        int idx = (blk - 10225) * 256 + tid;   // 2048*1280
        int s = idx / 1280, c = idx % 1280;
        float4 w4 = *(const float4*)&bCw[c * 4];
        float w[4] = {w4.x, w4.y, w4.z, w4.w};
        float acc = bCb[c];
#pragma unroll
        for (int k = 0; k < 4; ++k) {
            int j = s - 3 + k;
            if (j >= 0) acc += bfu(xbcB[(size_t)(2047 - j) * 1280 + c]) * w[k];
        }
        float r = siluf(acc);
        if (c >= 1024) bcB[(size_t)s * 256 + (c - 1024)] = f2bf(r);
        else           xB16[(size_t)s * 1024 + c] = f2bf(r);
    } else {
        int idx = (blk - 20465) * 256 + tid;   // 8*4*1280
        int b = idx / 5120;
        int r = idx % 5120;
        int t = r / 1280, c = r % 1280;
        float4 w4 = *(const float4*)&fCw[c * 4];
        float w[4] = {w4.x, w4.y, w4.z, w4.w};
        float acc = fCb[c];
#pragma unroll
        for (int k = 0; k < 4; ++k) {
            int j = t - 3 + k;
            float x = 0.f;
            if (j == 0)      x = zxc[(size_t)b * DPROJ + 1024 + c];
            else if (j >= 1) x = bfu(xbcF[(size_t)(j - 1) * 1280 + c]);
            acc += x * w[k];
        }
        float rr = siluf(acc);
        convFp[idx] = rr;   // fp32 kept: x0v, cbm rank-1 path
        if (c >= 1024) bcFp[(size_t)(b * 4 + t) * 256 + (c - 1024)] = f2bf(rr);
        else           xFp16[(size_t)(b * 4 + t) * 1024 + c] = f2bf(rr);
    }
}

// ---------------- intra-chunk kernel (MFMA) ----------------

__global__ __launch_bounds__(256) void intra_kernel(
    const unsigned short* __restrict__ bcF, const unsigned short* __restrict__ bcFp,
    const unsigned short* __restrict__ bcB,
    const unsigned short* __restrict__ xF16, const unsigned short* __restrict__ xFp16,
    const unsigned short* __restrict__ xB16,
    const float* __restrict__ dtFsT, const float* __restrict__ dtBsT,
    const float* __restrict__ cumF, const float* __restrict__ cumB,
    unsigned short* __restrict__ YiF0, unsigned short* __restrict__ YiFs,
    unsigned short* __restrict__ YiB,
    unsigned short* __restrict__ UF0, unsigned short* __restrict__ UFs,
    unsigned short* __restrict__ UB) {
    __shared__ __align__(16) unsigned char smraw[63232];
    unsigned short* Bt = (unsigned short*)smraw;                    // 64 x 136  [s][n]
    unsigned short* Ct = (unsigned short*)(smraw + 17408);          // 64 x 136  [t][n]
    unsigned short* Sm = (unsigned short*)(smraw + 17408);          // 64 x 72   [t][s] (alias Ct)
    unsigned short* BT = (unsigned short*)(smraw + 34816);          // 128 x 72  [n][s]
    unsigned short* XT = (unsigned short*)(smraw + 53248);          // 64 x 72   [p][s]
    float* scum = (float*)(smraw + 62464);                          // 64
    float* sdt  = scum + 64;                                        // 64
    float* se   = scum + 128;                                       // 64

    const int iid = blockIdx.x;
    int dir, b = 0, h, c;
    unsigned short *Yout, *Uout;
    if (iid < 128)      { dir = 0; b = iid >> 4; h = iid & 15; c = 0;
                          Yout = YiF0 + (size_t)(b * 16 + h) * 4096; Uout = UF0 + (size_t)(b * 16 + h) * 8192; }
    else if (iid < 624) { int k = iid - 128; dir = 0; c = 1 + (k >> 4); h = k & 15;
                          Yout = YiFs + (size_t)(c * 16 + h) * 4096; Uout = UFs + (size_t)(c * 16 + h) * 8192; }
    else                { int k = iid - 624; dir = 1; c = k >> 4; h = k & 15;
                          Yout = YiB + (size_t)(c * 16 + h) * 4096;  Uout = UB + (size_t)(c * 16 + h) * 8192; }
    const float* dtAT = dir ? dtBsT : dtFsT;
    const float* cumA = dir ? cumB : cumF;

    const int tid = threadIdx.x;
    const int lane = tid & 63, wave = tid >> 6;
    const int quad = lane >> 4, l15 = lane & 15;

    {
        int r = tid >> 2, q = tid & 3;
        const unsigned short *bsrc, *xsrc;
        if (dir == 0) {
            int t = 64 * c + 1 + r;
            if (t < 4) { bsrc = bcFp + (size_t)(b * 4 + t) * 256; xsrc = xFp16 + (size_t)(b * 4 + t) * 1024; }
            else       { bsrc = bcF + (size_t)(t - 4) * 256;      xsrc = xF16 + (size_t)(t - 4) * 1024; }
        } else {
            int s = 64 * c + r;
            bsrc = bcB + (size_t)s * 256;
            xsrc = xB16 + (size_t)s * 1024;
        }
#pragma unroll
        for (int i = 0; i < 4; ++i) {
            int n0 = q * 32 + i * 8;
            uint4 v = *(const uint4*)&bsrc[n0];
            *(uint4*)&Bt[r * 136 + n0] = v;
            const unsigned short* pv = (const unsigned short*)&v;
#pragma unroll
            for (int jj = 0; jj < 8; ++jj) BT[(n0 + jj) * 72 + r] = pv[jj];
        }
#pragma unroll
        for (int i = 0; i < 4; ++i) {
            int n0 = q * 32 + i * 8;
            uint4 v = *(const uint4*)&bsrc[128 + n0];
            *(uint4*)&Ct[r * 136 + n0] = v;
        }
#pragma unroll
        for (int k = 0; k < 2; ++k) {
            uint4 v = *(const uint4*)&xsrc[h * 64 + q * 16 + k * 8];
            const unsigned short* pv = (const unsigned short*)&v;
#pragma unroll
            for (int jj = 0; jj < 8; ++jj) XT[(q * 16 + k * 8 + jj) * 72 + r] = pv[jj];
        }
        if (tid < 64) {
            int j = 64 * c + tid;
            scum[tid] = cumA[h * 2048 + j];
            sdt[tid] = dtAT[h * 2048 + j];
        }
    }
    __syncthreads();
    if (tid < 64) se[tid] = __expf(scum[63] - scum[tid]) * sdt[tid];

    // phase 1: G = C . B^T
    const int tm = (wave >> 1) * 32, sn = (wave & 1) * 32;
    f32x4 acc1[2][2];
#pragma unroll
    for (int i = 0; i < 2; ++i)
#pragma unroll
        for (int j = 0; j < 2; ++j) acc1[i][j] = (f32x4){0.f, 0.f, 0.f, 0.f};
#pragma unroll
    for (int ks = 0; ks < 4; ++ks) {
        bf16x8 af[2], bfr[2];
#pragma unroll
        for (int i = 0; i < 2; ++i)
            af[i] = *(const bf16x8*)&Ct[(tm + i * 16 + l15) * 136 + ks * 32 + quad * 8];
#pragma unroll
        for (int j = 0; j < 2; ++j)
            bfr[j] = *(const bf16x8*)&Bt[(sn + j * 16 + l15) * 136 + ks * 32 + quad * 8];
#pragma unroll
        for (int i = 0; i < 2; ++i)
#pragma unroll
            for (int j = 0; j < 2; ++j)
                acc1[i][j] = __builtin_amdgcn_mfma_f32_16x16x32_bf16(af[i], bfr[j], acc1[i][j], 0, 0, 0);
    }
    __syncthreads();

#pragma unroll
    for (int j = 0; j < 2; ++j) {
        int s = sn + j * 16 + l15;
        float cs = scum[s], ds = sdt[s];
#pragma unroll
        for (int i = 0; i < 2; ++i) {
#pragma unroll
            for (int r = 0; r < 4; ++r) {
                int t = tm + i * 16 + quad * 4 + r;
                float v = (s <= t) ? __expf(scum[t] - cs) * ds * acc1[i][j][r] : 0.f;
                Sm[t * 72 + s] = f2bf(v);
            }
        }
    }
    __syncthreads();

    // phase 2 (swapped): A = X^T rows p, B = Sm rows t -> D[p][t]
    const int pm = (wave >> 1) * 32, tn = (wave & 1) * 32;
    f32x4 acc2[2][2];
#pragma unroll
    for (int i = 0; i < 2; ++i)
#pragma unroll
        for (int j = 0; j < 2; ++j) acc2[i][j] = (f32x4){0.f, 0.f, 0.f, 0.f};
#pragma unroll
    for (int ks = 0; ks < 2; ++ks) {
        bf16x8 af[2], bfr[2];
#pragma unroll
        for (int i = 0; i < 2; ++i)
            af[i] = *(const bf16x8*)&XT[(pm + i * 16 + l15) * 72 + ks * 32 + quad * 8];
#pragma unroll
        for (int j = 0; j < 2; ++j)
            bfr[j] = *(const bf16x8*)&Sm[(tn + j * 16 + l15) * 72 + ks * 32 + quad * 8];
#pragma unroll
        for (int i = 0; i < 2; ++i)
#pragma unroll
            for (int j = 0; j < 2; ++j)
                acc2[i][j] = __builtin_amdgcn_mfma_f32_16x16x32_bf16(af[i], bfr[j], acc2[i][j], 0, 0, 0);
    }
#pragma unroll
    for (int i = 0; i < 2; ++i)
#pragma unroll
        for (int j = 0; j < 2; ++j) {
            int t = tn + j * 16 + l15;
            int p0 = pm + i * 16 + quad * 4;
            ushort4 o = make_ushort4(f2bf(acc2[i][j][0]), f2bf(acc2[i][j][1]),
                                     f2bf(acc2[i][j][2]), f2bf(acc2[i][j][3]));
            *(ushort4*)&Yout[t * 64 + p0] = o;
        }

    // phase 3: U = B^T . (e*X) -> write U[p][n]
    const int nm = wave * 32;
    f32x4 acc3[2][4];
#pragma unroll
    for (int i = 0; i < 2; ++i)
#pragma unroll
        for (int j = 0; j < 4; ++j) acc3[i][j] = (f32x4){0.f, 0.f, 0.f, 0.f};
#pragma unroll
    for (int ks = 0; ks < 2; ++ks) {
        float ev[8];
#pragma unroll
        for (int jj = 0; jj < 8; ++jj) ev[jj] = se[ks * 32 + quad * 8 + jj];
        bf16x8 bfx[4];
#pragma unroll
        for (int j = 0; j < 4; ++j) {
            bf16x8 xs = *(const bf16x8*)&XT[(j * 16 + l15) * 72 + ks * 32 + quad * 8];
#pragma unroll
            for (int jj = 0; jj < 8; ++jj)
                bfx[j][jj] = (short)f2bf(bfu((unsigned short)xs[jj]) * ev[jj]);
        }
        bf16x8 af[2];
#pragma unroll
        for (int i = 0; i < 2; ++i)
            af[i] = *(const bf16x8*)&BT[(nm + i * 16 + l15) * 72 + ks * 32 + quad * 8];
#pragma unroll
        for (int i = 0; i < 2; ++i)
#pragma unroll
            for (int j = 0; j < 4; ++j)
                acc3[i][j] = __builtin_amdgcn_mfma_f32_16x16x32_bf16(af[i], bfx[j], acc3[i][j], 0, 0, 0);
    }
#pragma unroll
    for (int i = 0; i < 2; ++i)
#pragma unroll
        for (int j = 0; j < 4; ++j) {
            int p = j * 16 + l15;
            int n0 = nm + i * 16 + quad * 4;
            ushort4 o = make_ushort4(f2bf(acc3[i][j][0]), f2bf(acc3[i][j][1]),
                                     f2bf(acc3[i][j][2]), f2bf(acc3[i][j][3]));
            *(ushort4*)&Uout[p * 128 + n0] = o;
        }
}

// ---------------- merged cb0 + M + tpsi ----------------

__global__ void mid_kernel(const float* __restrict__ convFp, const unsigned short* __restrict__ bcF,
                           const float* __restrict__ dtFp, const float* __restrict__ cumF,
                           const float* __restrict__ cumB,
                           const unsigned short* __restrict__ UF0,
                           const unsigned short* __restrict__ UFs, const unsigned short* __restrict__ UB,
                           float* __restrict__ cb0, unsigned short* __restrict__ Mb,
                           unsigned short* __restrict__ Tst, float* __restrict__ psiF) {
    int blk = blockIdx.x, tid = threadIdx.x;   // 416
    if (blk < 32) {
        int idx = blk * 256 + tid;   // 8192
        int b = idx >> 10, r = idx & 1023, h = r >> 6, tl = r & 63;
        int t = tl + 1;
        const float* b0 = convFp + (size_t)(b * 4) * CONVD;
        float s = 0.f;
        if (t < 4) {
            const float* crow = convFp + (size_t)(b * 4 + t) * CONVD;
            for (int n = 0; n < 128; ++n) s += crow[1152 + n] * b0[1024 + n];
        } else {
            const unsigned short* cr = bcF + (size_t)(t - 4) * 256 + 128;
            for (int n = 0; n < 128; ++n) s += bfu(cr[n]) * b0[1024 + n];
        }
        cb0[(b * 16 + h) * 64 + tl] = s * dtFp[b * 16 + h];
    } else if (blk < 160) {
        int bh = blk - 32;   // 128
        int b = bh >> 4, h = bh & 15;
        float D0 = __expf(cumF[h * 2048 + 63]);
        float dt0 = dtFp[b * 16 + h];
        const float* row0 = convFp + (size_t)(b * 4) * CONVD;
        const unsigned short* u = UF0 + (size_t)(b * 16 + h) * 8192;
        unsigned short* m = Mb + (size_t)(b * 16 + h) * 8192;
        for (int e4 = tid; e4 < 2048; e4 += 256) {
            int e = e4 * 4, p = e >> 7, n0 = e & 127;
            float s = D0 * dt0 * row0[h * 64 + p];
            float4 B4 = *(const float4*)&row0[1024 + n0];
            ushort4 uv = *(const ushort4*)&u[e];
            ushort4 o = make_ushort4(f2bf(s * B4.x + bfu(uv.x)), f2bf(s * B4.y + bfu(uv.y)),
                                     f2bf(s * B4.z + bfu(uv.z)), f2bf(s * B4.w + bfu(uv.w)));
            *(ushort4*)&m[e] = o;
        }
    } else {
        int blk2 = blk - 160;   // 256: dir*128 + h*8 + q8
        int dir = blk2 >> 7, h = (blk2 >> 3) & 15, q8 = blk2 & 7;
        const unsigned short* U = dir ? UB : UFs;
        const float* cum = dir ? cumB : cumF;
        unsigned short* T = Tst + (size_t)(dir * 16 + h) * 32 * 8192;
        if (dir == 0 && q8 == 0 && tid == 0) {
            float ps = 1.f;
            for (int c = 1; c < 32; ++c) {
                psiF[h * 32 + c] = ps;
                ps *= __expf(cumF[h * 2048 + c * 64 + 63]);
            }
        }
        const size_t e = (size_t)q8 * 1024 + 4 * tid;
        float4 st = make_float4(0.f, 0.f, 0.f, 0.f);
        const int c0 = dir ? 0 : 1;
        ushort4 u = *(const ushort4*)&U[((size_t)c0 * 16 + h) * 8192 + e];
        for (int c = c0; c < 32; ++c) {
            ushort4 un = make_ushort4(0, 0, 0, 0);
            if (c + 1 < 32) un = *(const ushort4*)&U[((size_t)(c + 1) * 16 + h) * 8192 + e];
            float Dc = __expf(cum[h * 2048 + c * 64 + 63]);
            ushort4 o = make_ushort4(f2bf(st.x), f2bf(st.y), f2bf(st.z), f2bf(st.w));
            *(ushort4*)&T[(size_t)c * 8192 + e] = o;
            st.x = Dc * st.x + bfu(u.x);
            st.y = Dc * st.y + bfu(u.y);
            st.z = Dc * st.z + bfu(u.z);
            st.w = Dc * st.w + bfu(u.w);
            u = un;
        }
    }
}

// ---------------- batch-shared Ys = Yi + et*(C . T^T) + Dh*x ----------------

__global__ __launch_bounds__(256) void yt_kernel(
    const unsigned short* __restrict__ bcF, const unsigned short* __restrict__ bcB,
    const unsigned short* __restrict__ Tst,
    const unsigned short* __restrict__ YiFs, const unsigned short* __restrict__ YiB,
    const unsigned short* __restrict__ xF16, const unsigned short* __restrict__ xB16,
    const float* __restrict__ cumF, const float* __restrict__ cumB,
    const float* __restrict__ fD, const float* __restrict__ bD,
    unsigned short* __restrict__ YsF, unsigned short* __restrict__ YsB) {
    const int iid = blockIdx.x;   // 1008
    int dir, h, c;
    if (iid < 496) { dir = 0; c = 1 + (iid >> 4); h = iid & 15; }
    else           { int k = iid - 496; dir = 1; c = k >> 4; h = k & 15; }
    const unsigned short* Cbase = (dir == 0)
        ? bcF + ((size_t)(64 * c - 3)) * 256 + 128
        : bcB + ((size_t)(64 * c)) * 256 + 128;
    const unsigned short* Tp = Tst + ((size_t)(dir * 16 + h) * 32 + c) * 8192;
    const unsigned short* Yi = (dir == 0 ? YiFs : YiB) + (size_t)(c * 16 + h) * 4096;
    const unsigned short* xbase = (dir == 0) ? xF16 + ((size_t)(64 * c - 3)) * 1024
                                             : xB16 + ((size_t)(64 * c)) * 1024;
    const float* cum = dir ? cumB : cumF;
    const float Dh = (dir ? bD : fD)[h];
    unsigned short* Ys = (dir == 0 ? YsF : YsB) + (size_t)(c * 16 + h) * 4096;
    const int tid = threadIdx.x;
    const int lane = tid & 63, wave = tid >> 6;
    const int quad = lane >> 4, l15 = lane & 15;
    const int pm = (wave >> 1) * 32, tb = (wave & 1) * 32;
    f32x4 acc[2][2];
#pragma unroll
    for (int i = 0; i < 2; ++i)
#pragma unroll
        for (int j = 0; j < 2; ++j) acc[i][j] = (f32x4){0.f, 0.f, 0.f, 0.f};
#pragma unroll
    for (int ks = 0; ks < 4; ++ks) {
        bf16x8 af[2], bfr[2];
#pragma unroll
        for (int i = 0; i < 2; ++i)
            af[i] = *(const bf16x8*)&Tp[(size_t)(pm + i * 16 + l15) * 128 + ks * 32 + quad * 8];
#pragma unroll
        for (int j = 0; j < 2; ++j)
            bfr[j] = *(const bf16x8*)&Cbase[(size_t)(tb + j * 16 + l15) * 256 + ks * 32 + quad * 8];
#pragma unroll
        for (int i = 0; i < 2; ++i)
#pragma unroll
            for (int j = 0; j < 2; ++j)
                acc[i][j] = __builtin_amdgcn_mfma_f32_16x16x32_bf16(af[i], bfr[j], acc[i][j], 0, 0, 0);
    }
#pragma unroll
    for (int i = 0; i < 2; ++i)
#pragma unroll
        for (int j = 0; j < 2; ++j) {
            int t = tb + j * 16 + l15;
            int p0 = pm + i * 16 + quad * 4;
            float et = __expf(cum[h * 2048 + 64 * c + t]);
            ushort4 yi = *(const ushort4*)&Yi[t * 64 + p0];
            ushort4 xv = *(const ushort4*)&xbase[(size_t)t * 1024 + h * 64 + p0];
            ushort4 o = make_ushort4(f2bf(bfu(yi.x) + et * acc[i][j][0] + Dh * bfu(xv.x)),
                                     f2bf(bfu(yi.y) + et * acc[i][j][1] + Dh * bfu(xv.y)),
                                     f2bf(bfu(yi.z) + et * acc[i][j][2] + Dh * bfu(xv.z)),
                                     f2bf(bfu(yi.w) + et * acc[i][j][3] + Dh * bfu(xv.w)));
            *(ushort4*)&Ys[t * 64 + p0] = o;
        }
}

// ---------------- gate kernel: 2 chunks/block, loads issued before GEMM ----------------

__global__ __launch_bounds__(256) void gate_kernel(
    const unsigned short* __restrict__ bcF,
    const unsigned short* __restrict__ Mb, const float* __restrict__ psiF,
    const unsigned short* __restrict__ YsF, const unsigned short* __restrict__ YsB,
    const unsigned short* __restrict__ xF16, const unsigned short* __restrict__ xFp16,
    const unsigned short* __restrict__ szF, const unsigned short* __restrict__ szB,
    const float* __restrict__ convFp,
    const float* __restrict__ cumF,
    const unsigned short* __restrict__ YiF0,
    const float* __restrict__ cb0,
    const float* __restrict__ fD,
    const float* __restrict__ wf2, const float* __restrict__ wb2,
    float* __restrict__ aF, float* __restrict__ aB) {
    __shared__ __align__(16) float Ysm[64 * 68];

    const int iid = blockIdx.x;   // 2304: fwd 2048 (b,h,cg), bwd 256 (h,cg)
    int dir, b = 0, h, cg;
    if (iid < 2048) { dir = 0; b = iid >> 8; int r = iid & 255; h = r >> 4; cg = r & 15; }
    else            { int k = iid - 2048; dir = 1; h = k >> 4; cg = k & 15; }
    const int tid = threadIdx.x, tx = tid & 15, ty = tid >> 4;
    const int lane = tid & 63, wave = tid >> 6;
    const int quad = lane >> 4, l15 = lane & 15;

    const float Dh = dir ? 0.f : fD[h];
    const float* wvp = dir ? wb2 : wf2;
    float4 wreg = *(const float4*)&wvp[h * 64 + tx * 4];

    const int pm = (wave >> 1) * 32, tb = (wave & 1) * 32;
    bf16x8 mfr[4][2];
    if (dir == 0) {
        const unsigned short* Mp = Mb + (size_t)(b * 16 + h) * 8192;
#pragma unroll
        for (int ks = 0; ks < 4; ++ks)
#pragma unroll
            for (int i = 0; i < 2; ++i)
                mfr[ks][i] = *(const bf16x8*)&Mp[(size_t)(pm + i * 16 + l15) * 128 + ks * 32 + quad * 8];
    }

    for (int cc = 0; cc < 2; ++cc) {
        const int c = cg * 2 + cc;
        const bool fwdG = (dir == 0 && c > 0);
        const bool c0 = (dir == 0 && c == 0);

        // ---- issue independent epilogue loads first ----
        float rawet[4];
        ushort4 y4a[4], z4a[4], x4a[4];
#pragma unroll
        for (int i = 0; i < 4; ++i) {
            int tl = ty + 16 * i;
            int j = 64 * c + tl;
            rawet[i] = (dir == 0) ? cumF[h * 2048 + j] : 0.f;
            const unsigned short *Yp, *zp;
            if (dir == 0) {
                Yp = c0 ? YiF0 + (size_t)(b * 16 + h) * 4096 : YsF + (size_t)(c * 16 + h) * 4096;
                zp = szF + (size_t)j * 1024;
            } else {
                Yp = YsB + (size_t)(c * 16 + h) * 4096;
                zp = szB + (size_t)(2047 - j) * 1024;
            }
            y4a[i] = *(const ushort4*)&Yp[tl * 64 + tx * 4];
            z4a[i] = *(const ushort4*)&zp[h * 64 + tx * 4];
            if (c0) {
                int t = j + 1;
                const unsigned short* xp = (t < 4) ? xFp16 + (size_t)(b * 4 + t) * 1024
                                                   : xF16 + (size_t)(t - 4) * 1024;
                x4a[i] = *(const ushort4*)&xp[h * 64 + tx * 4];
            } else {
                x4a[i] = make_ushort4(0, 0, 0, 0);
            }
        }
        float4 x0v = make_float4(0.f, 0.f, 0.f, 0.f);
        float cbv[4] = {0.f, 0.f, 0.f, 0.f};
        if (c0) {
            x0v = *(const float4*)&convFp[(size_t)(b * 4) * CONVD + h * 64 + tx * 4];
#pragma unroll
            for (int i = 0; i < 4; ++i) cbv[i] = cb0[(b * 16 + h) * 64 + (ty + 16 * i)];
        }

        // ---- per-batch cm GEMM overlaps the loads above ----
        if (fwdG) {
            if (cc > 0) __syncthreads();   // prior epilogue done reading Ysm
            const unsigned short* Cbase = bcF + ((size_t)(64 * c - 3)) * 256 + 128;
            f32x4 acc[2][2];
#pragma unroll
            for (int i = 0; i < 2; ++i)
#pragma unroll
                for (int j = 0; j < 2; ++j) acc[i][j] = (f32x4){0.f, 0.f, 0.f, 0.f};
#pragma unroll
            for (int ks = 0; ks < 4; ++ks) {
                bf16x8 bfr[2];
#pragma unroll
                for (int j = 0; j < 2; ++j)
                    bfr[j] = *(const bf16x8*)&Cbase[(size_t)(tb + j * 16 + l15) * 256 + ks * 32 + quad * 8];
#pragma unroll
                for (int i = 0; i < 2; ++i)
#pragma unroll
                    for (int j = 0; j < 2; ++j)
                        acc[i][j] = __builtin_amdgcn_mfma_f32_16x16x32_bf16(mfr[ks][i], bfr[j], acc[i][j], 0, 0, 0);
            }
#pragma unroll
            for (int i = 0; i < 2; ++i)
#pragma unroll
                for (int j = 0; j < 2; ++j)
                    *(f32x4*)&Ysm[(tb + j * 16 + l15) * 68 + pm + i * 16 + quad * 4] = acc[i][j];
            __syncthreads();
        }

        const float psi = fwdG ? psiF[h * 32 + c] : 0.f;

#pragma unroll
        for (int i = 0; i < 4; ++i) {
            int tl = ty + 16 * i;
            int j = 64 * c + tl;
            float k1 = 0.f;
            float cma[4] = {0.f, 0.f, 0.f, 0.f};
            if (fwdG) {
                float et = __expf(rawet[i]);
                k1 = et * psi;
                float4 cmv = *(const float4*)&Ysm[tl * 68 + tx * 4];
                cma[0] = cmv.x; cma[1] = cmv.y; cma[2] = cmv.z; cma[3] = cmv.w;
            } else if (c0) {
                float et = __expf(rawet[i]);
                k1 = et * cbv[i];
                cma[0] = x0v.x; cma[1] = x0v.y; cma[2] = x0v.z; cma[3] = x0v.w;
            }
            float yv[4] = {bfu(y4a[i].x), bfu(y4a[i].y), bfu(y4a[i].z), bfu(y4a[i].w)};
            float sza[4] = {h2f(z4a[i].x), h2f(z4a[i].y), h2f(z4a[i].z), h2f(z4a[i].w)};
            float xa[4] = {bfu(x4a[i].x), bfu(x4a[i].y), bfu(x4a[i].z), bfu(x4a[i].w)};
            float wa[4] = {wreg.x, wreg.y, wreg.z, wreg.w};
            float a1 = 0.f, a2 = 0.f;
#pragma unroll
            for (int w = 0; w < 4; ++w) {
                float tot = yv[w] + k1 * cma[w] + (c0 ? Dh * xa[w] : 0.f);
                float g = tot * sza[w];
                a1 += g * wa[w];
                a2 += g * g;
            }
#pragma unroll
            for (int m = 1; m < 16; m <<= 1) {
                a1 += __shfl_xor(a1, m);
                a2 += __shfl_xor(a2, m);
            }
            if (tx == 0) {
                if (dir == 0) {
                    size_t o = ((size_t)(b * 2048 + j) * 16 + h) * 2;
                    aF[o] = a1; aF[o + 1] = a2;
                } else {
                    int g = 2047 - j;
                    size_t o = ((size_t)g * 16 + h) * 2;
                    aB[o] = a1; aB[o + 1] = a2;
                }
            }
        }
    }
}

// ---------------- final combine ----------------

__global__ void final_kernel(const float* __restrict__ aF, const float* __restrict__ aB,
                             const float* __restrict__ headB, float* __restrict__ out) {
    int idx = blockIdx.x * 256 + threadIdx.x;   // 16384
    int b = idx >> 11, g = idx & 2047;
    const float* pf = aF + ((size_t)(b * 2048 + g)) * 32;
    const float* pb = aB + (size_t)g * 32;
    float f1 = 0.f, f2 = 0.f, b1 = 0.f, b2 = 0.f;
#pragma unroll
    for (int h = 0; h < 16; ++h) {
        f1 += pf[2 * h]; f2 += pf[2 * h + 1];
        b1 += pb[2 * h]; b2 += pb[2 * h + 1];
    }
    out[idx] = f1 * rsqrtf(f2 * (1.f / 1024.f) + 1e-5f) +
               b1 * rsqrtf(b2 * (1.f / 1024.f) + 1e-5f) + headB[0];
}

// ---------------- launch ----------------

extern "C" void kernel_launch(void* const* d_in, const int* in_sizes, int n_in,
                              void* d_out, int out_size, void* d_ws, size_t ws_size,
                              hipStream_t stream) {
    const int*   pidx   = (const int*)  d_in[0];
    const int*   chridx = (const int*)  d_in[1];
    const float* locusF = (const float*)d_in[2];
    const float* pathF  = (const float*)d_in[3];
    const float* pertE  = (const float*)d_in[4];
    const float* gidE   = (const float*)d_in[5];
    const float* chrE   = (const float*)d_in[6];
    const float* locusW = (const float*)d_in[7];
    const float* locusB = (const float*)d_in[8];
    const float* condW  = (const float*)d_in[9];
    const float* condB  = (const float*)d_in[10];
    const float* inW    = (const float*)d_in[11];
    const float* inB    = (const float*)d_in[12];
    const float* headW  = (const float*)d_in[13];
    const float* headB  = (const float*)d_in[14];
    const float* fInW   = (const float*)d_in[15];
    const float* fCw    = (const float*)d_in[16];
    const float* fCb    = (const float*)d_in[17];
    const float* fDtB   = (const float*)d_in[18];
    const float* fAlog  = (const float*)d_in[19];
    const float* fDp    = (const float*)d_in[20];
    const float* fNw    = (const float*)d_in[21];
    const float* fOutW  = (const float*)d_in[22];
    const float* bInW   = (const float*)d_in[23];
    const float* bCw    = (const float*)d_in[24];
    const float* bCb    = (const float*)d_in[25];
    const float* bDtB   = (const float*)d_in[26];
    const float* bAlog  = (const float*)d_in[27];
    const float* bDp    = (const float*)d_in[28];
    const float* bNw    = (const float*)d_in[29];
    const float* bOutW  = (const float*)d_in[30];
    float* out = (float*)d_out;
    (void)in_sizes; (void)n_in; (void)out_size; (void)ws_size;

    char* base = (char*)d_ws;
    size_t off = 0;
    auto allocf = [&](size_t n) -> float* {
        char* r = base + off; off += ((n * 4 + 63) & ~(size_t)63); return (float*)r; };
    auto allocu = [&](size_t n) -> unsigned short* {
        char* r = base + off; off += ((n * 2 + 63) & ~(size_t)63); return (unsigned short*)r; };

    float* gf     = allocf(2048UL * 384);
    float* cond   = allocf(8UL * 384);
    float* cemb   = allocf(8UL * 128);
    float* uc     = allocf(8UL * 512);
    float* zxc    = allocf(8UL * DPROJ);
    float* convFp = allocf(8UL * 4 * CONVD);
    float* dtrF   = allocf(2048UL * 16);
    float* dtrB   = allocf(2048UL * 16);
    float* dtFsT  = allocf(16UL * 2048);
    float* dtFp   = allocf(128);
    float* dtBsT  = allocf(16UL * 2048);
    float* cumF   = allocf(16UL * 2048);
    float* cumB   = allocf(16UL * 2048);
    float* wf2    = allocf(1024);
    float* wb2    = allocf(1024);
    float* cb0    = allocf(8UL * 16 * 64);
    float* psiF   = allocf(16UL * 32);
    float* aF     = allocf(8UL * 2048 * 16 * 2);
    float* aB     = allocf(2048UL * 16 * 2);
    unsigned short* xbcF = allocu(2048UL * 1280);
    unsigned short* xbcB = allocu(2048UL * 1280);
    unsigned short* YiF0 = allocu(8UL * 16 * 4096);
    unsigned short* YiFs = allocu(32UL * 16 * 4096);
    unsigned short* YiB  = allocu(32UL * 16 * 4096);
    unsigned short* UF0  = allocu(8UL * 16 * 8192);
    unsigned short* UFs  = allocu(32UL * 16 * 8192);
    unsigned short* UB   = allocu(32UL * 16 * 8192);
    unsigned short* Mb   = allocu(8UL * 16 * 8192);
    unsigned short* Tst  = allocu(2UL * 16 * 32 * 8192);
    unsigned short* bcF  = allocu(2045UL * 256);
    unsigned short* bcFp = allocu(32UL * 256);
    unsigned short* bcB  = allocu(2048UL * 256);
    unsigned short* YsF  = allocu(32UL * 16 * 4096);
    unsigned short* YsB  = allocu(32UL * 16 * 4096);
    unsigned short* xF16 = allocu(2045UL * 1024);
    unsigned short* xFp16= allocu(32UL * 1024);
    unsigned short* xB16 = allocu(2048UL * 1024);
    unsigned short* szF  = allocu(2048UL * 1024);
    unsigned short* szB  = allocu(2048UL * 1024);
    unsigned short* gf2   = allocu(2048UL * 384);
    unsigned short* inW2  = allocu(512UL * 384);
    unsigned short* ug2   = allocu(2048UL * 512);
    unsigned short* fInW2 = allocu(2432UL * 512);
    unsigned short* bInW2 = allocu(2432UL * 512);

    gg_kernel<<<3077, 256, 0, stream>>>(chridx, gidE, pathF, chrE, pidx, pertE, gf, cemb, wf2, wb2);
    wfold_kernel<<<128, 256, 0, stream>>>(headW, fOutW, fNw, bOutW, bNw, wf2, wb2);
    gemm_kernel<<<dim3(1, 32), 256, 0, stream>>>(locusF, locusW, locusB, gf + 320, 2048, 64, 64, 384, 1);
    gemm_kernel<<<dim3(6, 1), 256, 0, stream>>>(cemb, condW, condB, cond, 8, 384, 128, 384, 0);

    tobf4_kernel<<<13568, 256, 0, stream>>>(inW, fInW, bInW, gf, inW2, fInW2, bInW2, gf2);

    mfma_gemm_kernel<<<dim3(4, 16), 256, 0, stream>>>(gf2, inW2, inB, ug2, 512, 384, 512);
    gemm_kernel<<<dim3(8, 1), 256, 0, stream>>>(cond, inW, inB, uc, 8, 512, 384, 512, 0);

    zx_gemm_kernel<<<dim3(38, 16), 256, 0, stream>>>(ug2, fInW2, bInW2,
                                                     szF, xbcF, dtrF, szB, xbcB, dtrB);
    gemm_kernel<<<dim3(37, 1), 256, 0, stream>>>(uc, fInW, nullptr, zxc, 8, DPROJ, 512, DPROJ, 0);

    dt_kernel<<<257, 256, 0, stream>>>(dtrF, dtrB, zxc, fDtB, bDtB, dtFsT, dtBsT, dtFp);
    cum_kernel<<<4, 256, 0, stream>>>(dtFsT, dtBsT, fAlog, bAlog, cumF, cumB);
    conv_kernel<<<20625, 256, 0, stream>>>(xbcF, xbcB, zxc, fCw, fCb, bCw, bCb,
                                           bcF, xF16, bcB, xB16, convFp, bcFp, xFp16);
    intra_kernel<<<1136, 256, 0, stream>>>(bcF, bcFp, bcB, xF16, xFp16, xB16,
                                           dtFsT, dtBsT, cumF, cumB,
                                           YiF0, YiFs, YiB, UF0, UFs, UB);
    mid_kernel<<<416, 256, 0, stream>>>(convFp, bcF, dtFp, cumF, cumB, UF0, UFs, UB,
                                        cb0, Mb, Tst, psiF);
    yt_kernel<<<1008, 256, 0, stream>>>(bcF, bcB, Tst, YiFs, YiB, xF16, xB16,
                                        cumF, cumB, fDp, bDp, YsF, YsB);
    gate_kernel<<<2304, 256, 0, stream>>>(bcF, Mb, psiF, YsF, YsB, xF16, xFp16,
                                          szF, szB, convFp, cumF,
                                          YiF0, cb0, fDp, wf2, wb2, aF, aB);
    final_kernel<<<64, 256, 0, stream>>>(aF, aB, headB, out);
}